// Round 11
// baseline (846.635 us; speedup 1.0000x reference)
//
#include <hip/hip_runtime.h>

#define OUT_ZQ   0
#define OUT_DIFF 2097152
#define OUT_IND  2097153

// ws layout (bytes) — total 528,464 <= proven 565,248
#define WS_AMIN   0        // u64[8192]
#define WS_A      65536    // f32[8192]
#define WS_N      98304    // f32[8192]
#define WS_EMAX   131072   // u32 (+pad)
#define WS_BMIN   131136   // f32[4][8192]
#define WS_BSEC   262208   // f32[4][8192]
#define WS_BARGK  393280   // u16[4][8192]
#define WS_DLIST  458816   // u16[4][8192]
#define WS_DCNT   524352   // i32[4]
#define WS_PART   524368   // f32[1024]

typedef unsigned long long u64t;
typedef __attribute__((ext_vector_type(8))) short bf16x8;
typedef __attribute__((ext_vector_type(4))) float f32x4;

__device__ inline unsigned short bf16rn(float f) {
    unsigned u = __float_as_uint(f);
    return (unsigned short)((u + 0x7fffu + ((u >> 16) & 1u)) >> 16);
}
__device__ inline float bf16tof(unsigned short h) { return __uint_as_float(((unsigned)h) << 16); }

// ---------------------------------------------------------------- init
__global__ __launch_bounds__(256) void k_init(u64t* __restrict__ amin,
                                              int* __restrict__ dcnt,
                                              unsigned* __restrict__ e2) {
    const int i = blockIdx.x * 256 + threadIdx.x;
    amin[i] = ~0ULL;
    if (i < 4) dcnt[i] = 0;
    if (i == 4) *e2 = 0u;
}

// ---------------------------------------------------------------- z_e: bit-exact np.einsum replica (verified r5-r10)
__global__ __launch_bounds__(256) void k_ze_np(const float* __restrict__ z,
                                               const float* __restrict__ pw,
                                               const float* __restrict__ pb,
                                               float* __restrict__ ze) {
    __shared__ float lz[32][16];
    __shared__ float lw[256][33];
    const int t   = threadIdx.x;
    const int b   = blockIdx.x >> 6;
    const int hw0 = (blockIdx.x & 63) * 16;

    float acc[16];
#pragma unroll
    for (int p = 0; p < 16; ++p) acc[p] = 0.0f;

    for (int cc = 0; cc < 256; cc += 32) {
        float4 wv[8];
        const float4* wsrc = reinterpret_cast<const float4*>(pw + (size_t)t * 256 + cc);
#pragma unroll
        for (int i = 0; i < 8; ++i) wv[i] = wsrc[i];
        float zv[2];
#pragma unroll
        for (int i = 0; i < 2; ++i) {
            const int f = t + i * 256;
            zv[i] = z[(size_t)(b * 256 + cc + (f >> 4)) * 1024 + hw0 + (f & 15)];
        }
        __syncthreads();
#pragma unroll
        for (int i = 0; i < 8; ++i) {
            lw[t][i * 4 + 0] = wv[i].x;
            lw[t][i * 4 + 1] = wv[i].y;
            lw[t][i * 4 + 2] = wv[i].z;
            lw[t][i * 4 + 3] = wv[i].w;
        }
#pragma unroll
        for (int i = 0; i < 2; ++i) {
            const int f = t + i * 256;
            lz[f >> 4][f & 15] = zv[i];
        }
        __syncthreads();
#pragma unroll 8
        for (int cl = 0; cl < 32; ++cl) {
            const float wl = lw[t][cl];
#pragma unroll
            for (int p = 0; p < 16; ++p)
                acc[p] = __fadd_rn(acc[p], __fmul_rn(lz[cl][p], wl));
        }
    }
    const float bb = pb[t];
#pragma unroll
    for (int p = 0; p < 16; ++p)
        ze[(size_t)(b * 1024 + hw0 + p) * 256 + t] = __fadd_rn(acc[p], bb);
}

// ---------------------------------------------------------------- np pairwise row-norms + embed-norm max
__global__ __launch_bounds__(256) void k_rowstats(const float* __restrict__ ze,
                                                  const float* __restrict__ embed,
                                                  float* __restrict__ A,
                                                  float* __restrict__ Nf,
                                                  unsigned* __restrict__ e2) {
    const int gid = blockIdx.x * 256 + threadIdx.x;
    const float* row = (gid < 8192) ? (ze + (size_t)gid * 256)
                                    : (embed + (size_t)(gid - 8192) * 256);
    float blk[2];
#pragma unroll
    for (int half = 0; half < 2; ++half) {
        const float4* r4 = reinterpret_cast<const float4*>(row + half * 128);
        float r[8];
#pragma unroll
        for (int i = 0; i < 16; ++i) {
            const float4 a = r4[i * 2], b = r4[i * 2 + 1];
            const float s[8] = {__fmul_rn(a.x, a.x), __fmul_rn(a.y, a.y),
                                __fmul_rn(a.z, a.z), __fmul_rn(a.w, a.w),
                                __fmul_rn(b.x, b.x), __fmul_rn(b.y, b.y),
                                __fmul_rn(b.z, b.z), __fmul_rn(b.w, b.w)};
            if (i == 0) {
#pragma unroll
                for (int j = 0; j < 8; ++j) r[j] = s[j];
            } else {
#pragma unroll
                for (int j = 0; j < 8; ++j) r[j] = __fadd_rn(r[j], s[j]);
            }
        }
        blk[half] = __fadd_rn(__fadd_rn(__fadd_rn(r[0], r[1]), __fadd_rn(r[2], r[3])),
                              __fadd_rn(__fadd_rn(r[4], r[5]), __fadd_rn(r[6], r[7])));
    }
    const float res = __fadd_rn(blk[0], blk[1]);
    if (gid < 8192) A[gid] = res;
    else {
        Nf[gid - 8192] = res;
        float mx = res;
        for (int off = 32; off; off >>= 1) mx = fmaxf(mx, __shfl_down(mx, off, 64));
        if ((threadIdx.x & 63) == 0) atomicMax(e2, __float_as_uint(mx));
    }
}

// ---------------------------------------------------------------- MFMA screening pass (bf16 3-product split)
// grid 512 = 128 px-tiles(64) x 4 k-splits(2048). 4 waves: wave w covers k-sub w*64 within 256-k subtile.
// Per px per split: tracks (min, second, argk) of vhat = f64(A - Mtilde + N), f32-RN-packed u64 with k.
__global__ __launch_bounds__(256, 2) void k_mfma(const float* __restrict__ ze,
                                                 const float* __restrict__ embed,
                                                 const float* __restrict__ A,
                                                 const float* __restrict__ Nf,
                                                 float* __restrict__ bmin,
                                                 float* __restrict__ bsec,
                                                 unsigned short* __restrict__ bargk) {
    __shared__ __align__(16) char smem[59392];
    short (*zh)[72]  = reinterpret_cast<short(*)[72]>(smem);            // [64 px][72]  (64 c + pad)
    short (*zl)[72]  = reinterpret_cast<short(*)[72]>(smem + 9216);
    short (*ehi)[40] = reinterpret_cast<short(*)[40]>(smem + 18432);    // [256 k][40] (32 c + pad)
    short (*elo)[40] = reinterpret_cast<short(*)[40]>(smem + 38912);

    const int t = threadIdx.x;
    const int ks = blockIdx.x & 3, pt = blockIdx.x >> 2;
    const int pix0 = pt * 64, k0 = ks * 2048;
    const int w = t >> 6, l = t & 63;
    const int lg = l >> 4, lr = l & 15;

    float a_reg[4][4];
#pragma unroll
    for (int ti = 0; ti < 4; ++ti)
#pragma unroll
        for (int r = 0; r < 4; ++r)
            a_reg[ti][r] = A[pix0 + ti * 16 + lg * 4 + r];

    u64t bb[4][4], ss[4][4];
#pragma unroll
    for (int ti = 0; ti < 4; ++ti)
#pragma unroll
        for (int r = 0; r < 4; ++r) { bb[ti][r] = ~0ULL; ss[ti][r] = ~0ULL; }

    for (int ksub = 0; ksub < 8; ++ksub) {
        f32x4 acc[4][4];
#pragma unroll
        for (int ti = 0; ti < 4; ++ti)
#pragma unroll
            for (int tj = 0; tj < 4; ++tj) acc[ti][tj] = (f32x4)(0.0f);

        for (int cq = 0; cq < 4; ++cq) {
            {   // stage z quarter: 2*z_e -> bf16 hi/lo
                const int row = t >> 2, c0 = (t & 3) * 16;
                const float4* src = reinterpret_cast<const float4*>(
                    ze + (size_t)(pix0 + row) * 256 + cq * 64 + c0);
                float4 v4[4];
#pragma unroll
                for (int m = 0; m < 4; ++m) v4[m] = src[m];
                float xv[16] = {v4[0].x, v4[0].y, v4[0].z, v4[0].w, v4[1].x, v4[1].y, v4[1].z, v4[1].w,
                                v4[2].x, v4[2].y, v4[2].z, v4[2].w, v4[3].x, v4[3].y, v4[3].z, v4[3].w};
                __syncthreads();
                bf16x8 ph0, ph1, pl0, pl1;
#pragma unroll
                for (int i = 0; i < 16; ++i) {
                    const float x = __fmul_rn(2.0f, xv[i]);
                    const unsigned short h = bf16rn(x);
                    const unsigned short lo = bf16rn(__fsub_rn(x, bf16tof(h)));
                    if (i < 8) { ph0[i] = (short)h; pl0[i] = (short)lo; }
                    else       { ph1[i - 8] = (short)h; pl1[i - 8] = (short)lo; }
                }
                *reinterpret_cast<bf16x8*>(&zh[row][c0])     = ph0;
                *reinterpret_cast<bf16x8*>(&zh[row][c0 + 8]) = ph1;
                *reinterpret_cast<bf16x8*>(&zl[row][c0])     = pl0;
                *reinterpret_cast<bf16x8*>(&zl[row][c0 + 8]) = pl1;
                __syncthreads();
            }
            for (int cc = 0; cc < 2; ++cc) {
                {   // stage e chunk: [256 k][32 c] -> bf16 hi/lo
                    const float4* esrc = reinterpret_cast<const float4*>(
                        embed + (size_t)(k0 + ksub * 256 + t) * 256 + cq * 64 + cc * 32);
                    float4 e4[8];
#pragma unroll
                    for (int m = 0; m < 8; ++m) e4[m] = esrc[m];
                    __syncthreads();
#pragma unroll
                    for (int m = 0; m < 8; m += 2) {
                        const float ev[8] = {e4[m].x, e4[m].y, e4[m].z, e4[m].w,
                                             e4[m + 1].x, e4[m + 1].y, e4[m + 1].z, e4[m + 1].w};
                        bf16x8 phh, pll;
#pragma unroll
                        for (int i = 0; i < 8; ++i) {
                            const unsigned short h = bf16rn(ev[i]);
                            phh[i] = (short)h;
                            pll[i] = (short)bf16rn(__fsub_rn(ev[i], bf16tof(h)));
                        }
                        *reinterpret_cast<bf16x8*>(&ehi[t][m * 4]) = phh;
                        *reinterpret_cast<bf16x8*>(&elo[t][m * 4]) = pll;
                    }
                    __syncthreads();
                }
                bf16x8 ahz[4], alz[4];
                const int acol = cc * 32 + lg * 8;
#pragma unroll
                for (int ti = 0; ti < 4; ++ti) {
                    ahz[ti] = *reinterpret_cast<const bf16x8*>(&zh[ti * 16 + lr][acol]);
                    alz[ti] = *reinterpret_cast<const bf16x8*>(&zl[ti * 16 + lr][acol]);
                }
#pragma unroll
                for (int tj = 0; tj < 4; ++tj) {
                    const bf16x8 bhe = *reinterpret_cast<const bf16x8*>(&ehi[w * 64 + tj * 16 + lr][lg * 8]);
                    const bf16x8 ble = *reinterpret_cast<const bf16x8*>(&elo[w * 64 + tj * 16 + lr][lg * 8]);
#pragma unroll
                    for (int ti = 0; ti < 4; ++ti) {
                        acc[ti][tj] = __builtin_amdgcn_mfma_f32_16x16x32_bf16(ahz[ti], bhe, acc[ti][tj], 0, 0, 0);
                        acc[ti][tj] = __builtin_amdgcn_mfma_f32_16x16x32_bf16(ahz[ti], ble, acc[ti][tj], 0, 0, 0);
                        acc[ti][tj] = __builtin_amdgcn_mfma_f32_16x16x32_bf16(alz[ti], bhe, acc[ti][tj], 0, 0, 0);
                    }
                }
            }
        }
        // epilogue: vhat' = f64(A - M + N), pack f32-RN + k, track (best, second)
#pragma unroll
        for (int tj = 0; tj < 4; ++tj) {
            const int kk = k0 + ksub * 256 + w * 64 + tj * 16 + lr;
            const double nk = (double)Nf[kk];
#pragma unroll
            for (int ti = 0; ti < 4; ++ti) {
#pragma unroll
                for (int r = 0; r < 4; ++r) {
                    const float vv = (float)((double)a_reg[ti][r] - (double)acc[ti][tj][r] + nk);
                    const u64t key = ((u64t)__float_as_uint(vv) << 32) | (unsigned)kk;
                    if (key < bb[ti][r]) { ss[ti][r] = bb[ti][r]; bb[ti][r] = key; }
                    else if (key < ss[ti][r]) ss[ti][r] = key;
                }
            }
        }
    }
    // cross-lane tournament within each 16-lane group (exact 2-smallest)
#pragma unroll
    for (int ti = 0; ti < 4; ++ti)
#pragma unroll
        for (int r = 0; r < 4; ++r) {
            u64t b = bb[ti][r], s2 = ss[ti][r];
#pragma unroll
            for (int m = 1; m <= 8; m <<= 1) {
                const u64t ob = __shfl_xor(b, m, 64);
                const u64t os = __shfl_xor(s2, m, 64);
                const u64t nb = (b < ob) ? b : ob;
                const u64t mx = (b < ob) ? ob : b;
                u64t ns = (os < s2) ? os : s2;
                ns = (mx < ns) ? mx : ns;
                b = nb; s2 = ns;
            }
            bb[ti][r] = b; ss[ti][r] = s2;
        }
    __syncthreads();
    u64t (*mrg)[4][2] = reinterpret_cast<u64t(*)[4][2]>(smem + 18432);  // overlay on e-bufs
    if (lr == 0) {
#pragma unroll
        for (int ti = 0; ti < 4; ++ti)
#pragma unroll
            for (int r = 0; r < 4; ++r) {
                mrg[ti * 16 + lg * 4 + r][w][0] = bb[ti][r];
                mrg[ti * 16 + lg * 4 + r][w][1] = ss[ti][r];
            }
    }
    __syncthreads();
    if (t < 64) {
        u64t B = ~0ULL, S = ~0ULL;
#pragma unroll
        for (int w4 = 0; w4 < 4; ++w4) {
            const u64t b = mrg[t][w4][0], s2 = mrg[t][w4][1];
            const u64t nb = (B < b) ? B : b;
            const u64t mx = (B < b) ? b : B;
            u64t ns = (S < s2) ? S : s2;
            ns = (mx < ns) ? mx : ns;
            B = nb; S = ns;
        }
        bmin[ks * 8192 + pix0 + t]  = __uint_as_float((unsigned)(B >> 32));
        bsec[ks * 8192 + pix0 + t]  = __uint_as_float((unsigned)(S >> 32));
        bargk[ks * 8192 + pix0 + t] = (unsigned short)(B & 0xffffu);
    }
}

// ---------------------------------------------------------------- select: candidates exact np rescore + deep flags
__global__ __launch_bounds__(256) void k_sel(const float* __restrict__ ze,
                                             const float* __restrict__ embed,
                                             const float* __restrict__ A,
                                             const float* __restrict__ Nf,
                                             const unsigned* __restrict__ e2,
                                             const float* __restrict__ bmin,
                                             const float* __restrict__ bsec,
                                             const unsigned short* __restrict__ bargk,
                                             u64t* __restrict__ amin,
                                             unsigned short* __restrict__ dlist,
                                             int* __restrict__ dcnt) {
    const int px = blockIdx.x * 256 + threadIdx.x;
    const float a = A[px];
    float m = bmin[px];
#pragma unroll
    for (int s = 1; s < 4; ++s) m = fminf(m, bmin[s * 8192 + px]);
    const float Em = sqrtf(__uint_as_float(*e2));
    const float S = __fmul_rn(2.0f, sqrtf(a)) * Em;           // CS bound on |M2|
    const unsigned eb = (__float_as_uint(a + 0.125f) >> 23) & 255u;
    const float up = __uint_as_float((eb - 23u) << 23);        // ulp at A's binade
    const float thresh = m + 2.0f * (1.5e-4f * S + 1.6f * up + 1.0e-6f);
#pragma unroll
    for (int s = 0; s < 4; ++s) {
        if (bmin[s * 8192 + px] <= thresh) {
            const int k = bargk[s * 8192 + px];
            const float4* zr = reinterpret_cast<const float4*>(ze + (size_t)px * 256);
            const float4* er = reinterpret_cast<const float4*>(embed + (size_t)k * 256);
            float acc = 0.0f;
            for (int i = 0; i < 64; ++i) {
                const float4 z4 = zr[i], e4 = er[i];
                acc = fmaf(__fmul_rn(2.0f, z4.x), e4.x, acc);
                acc = fmaf(__fmul_rn(2.0f, z4.y), e4.y, acc);
                acc = fmaf(__fmul_rn(2.0f, z4.z), e4.z, acc);
                acc = fmaf(__fmul_rn(2.0f, z4.w), e4.w, acc);
            }
            const float v = __fadd_rn(__fsub_rn(a, acc), Nf[k]);
            atomicMin(&amin[px], ((u64t)__float_as_uint(v) << 32) | (unsigned)k);
        }
        if (bsec[s * 8192 + px] <= thresh) {
            const int pos = atomicAdd(&dcnt[s], 1);
            dlist[s * 8192 + pos] = (unsigned short)px;
        }
    }
}

// ---------------------------------------------------------------- deep: exact np rescore of a whole 2048-k split
// grid 4096 = 4 splits x 1024 buckets of 8 px. Most blocks exit immediately.
__global__ __launch_bounds__(256) void k_deep(const float* __restrict__ ze,
                                              const float* __restrict__ embed,
                                              const float* __restrict__ A,
                                              const float* __restrict__ Nf,
                                              const unsigned short* __restrict__ dlist,
                                              const int* __restrict__ dcnt,
                                              u64t* __restrict__ amin) {
    const int s = blockIdx.x >> 10;
    const int bkt = blockIdx.x & 1023;
    int n = dcnt[s]; if (n > 8192) n = 8192;
    const int i0 = bkt * 8;
    if (i0 >= n) return;
    __shared__ int spx[8];
    __shared__ float sA[8];
    __shared__ __align__(16) float lz2[8][264];
    __shared__ __align__(16) float echA[128][36];   // even k rows
    __shared__ __align__(16) float echB[128][36];   // odd k rows
    const int t = threadIdx.x;
    if (t < 8) {
        const int v = (i0 + t < n) ? (int)dlist[s * 8192 + i0 + t] : -1;
        spx[t] = v;
        sA[t] = (v >= 0) ? A[v] : 0.0f;
    }
    __syncthreads();
    {   // stage 2*z_e rows
        const int row = t >> 5, c0 = (t & 31) * 8;
        float4 v0 = make_float4(0.f, 0.f, 0.f, 0.f), v1 = v0;
        const int px = spx[row];
        if (px >= 0) {
            const float4* zr = reinterpret_cast<const float4*>(ze + (size_t)px * 256 + c0);
            v0 = zr[0]; v1 = zr[1];
        }
        lz2[row][c0 + 0] = __fmul_rn(2.0f, v0.x);
        lz2[row][c0 + 1] = __fmul_rn(2.0f, v0.y);
        lz2[row][c0 + 2] = __fmul_rn(2.0f, v0.z);
        lz2[row][c0 + 3] = __fmul_rn(2.0f, v0.w);
        lz2[row][c0 + 4] = __fmul_rn(2.0f, v1.x);
        lz2[row][c0 + 5] = __fmul_rn(2.0f, v1.y);
        lz2[row][c0 + 6] = __fmul_rn(2.0f, v1.z);
        lz2[row][c0 + 7] = __fmul_rn(2.0f, v1.w);
    }
    __syncthreads();
    const int pxg = t >> 7, kg = t & 127;
    for (int kc = 0; kc < 8; ++kc) {
        float acc[4][2];
#pragma unroll
        for (int p = 0; p < 4; ++p) { acc[p][0] = 0.0f; acc[p][1] = 0.0f; }
        for (int cc = 0; cc < 8; ++cc) {
            const float4* esrc = reinterpret_cast<const float4*>(
                embed + (size_t)(s * 2048 + kc * 256 + t) * 256 + cc * 32);
            float4 ev[8];
#pragma unroll
            for (int m = 0; m < 8; ++m) ev[m] = esrc[m];
            __syncthreads();
            {
                float* dst = (t & 1) ? &echB[t >> 1][0] : &echA[t >> 1][0];
#pragma unroll
                for (int m = 0; m < 8; ++m) {
                    dst[m * 4 + 0] = ev[m].x; dst[m * 4 + 1] = ev[m].y;
                    dst[m * 4 + 2] = ev[m].z; dst[m * 4 + 3] = ev[m].w;
                }
            }
            __syncthreads();
#pragma unroll
            for (int c4 = 0; c4 < 8; ++c4) {
                const float4 e0 = *reinterpret_cast<const float4*>(&echA[kg][c4 * 4]);
                const float4 e1 = *reinterpret_cast<const float4*>(&echB[kg][c4 * 4]);
#pragma unroll
                for (int p = 0; p < 4; ++p) {
                    const float4 zq = *reinterpret_cast<const float4*>(&lz2[pxg * 4 + p][cc * 32 + c4 * 4]);
                    acc[p][0] = fmaf(zq.x, e0.x, acc[p][0]);
                    acc[p][0] = fmaf(zq.y, e0.y, acc[p][0]);
                    acc[p][0] = fmaf(zq.z, e0.z, acc[p][0]);
                    acc[p][0] = fmaf(zq.w, e0.w, acc[p][0]);
                    acc[p][1] = fmaf(zq.x, e1.x, acc[p][1]);
                    acc[p][1] = fmaf(zq.y, e1.y, acc[p][1]);
                    acc[p][1] = fmaf(zq.z, e1.z, acc[p][1]);
                    acc[p][1] = fmaf(zq.w, e1.w, acc[p][1]);
                }
            }
        }
#pragma unroll
        for (int p = 0; p < 4; ++p) {
            const int px = spx[pxg * 4 + p];
            if (px >= 0) {
#pragma unroll
                for (int j = 0; j < 2; ++j) {
                    const int k = s * 2048 + kc * 256 + kg * 2 + j;
                    const float v = __fadd_rn(__fsub_rn(sA[pxg * 4 + p], acc[p][j]), Nf[k]);
                    atomicMin(&amin[px], ((u64t)__float_as_uint(v) << 32) | (unsigned)k);
                }
            }
        }
        __syncthreads();
    }
}

// ---------------------------------------------------------------- unpack argmin
__global__ __launch_bounds__(256) void k_combine(const u64t* __restrict__ amin,
                                                 float* __restrict__ out_ind) {
    const int nn = blockIdx.x * 256 + threadIdx.x;
    out_ind[nn] = (float)(unsigned)(amin[nn] & 0xffffffffULL);
}

// ---------------------------------------------------------------- gather z_q (overwrite z_e) + partial MSE (f64)
__global__ __launch_bounds__(256) void k_gather(const float* __restrict__ embed,
                                                float* __restrict__ out,
                                                const float* __restrict__ out_ind,
                                                float* __restrict__ part) {
    __shared__ double wsum[4];
    const int t = threadIdx.x;
    const int g = t >> 5, ll = t & 31;
    const int nn = blockIdx.x * 8 + g;
    const int idx = (int)(out_ind[nn] + 0.5f);
    const float4* ev4 = reinterpret_cast<const float4*>(embed + (size_t)idx * 256);
    float4* zp = reinterpret_cast<float4*>(out + (size_t)nn * 256);
    double sm = 0.0;
#pragma unroll
    for (int r = 0; r < 2; ++r) {
        const float4 ev = ev4[ll + r * 32];
        const float4 zv = zp[ll + r * 32];
        const double dx = (double)ev.x - zv.x, dy = (double)ev.y - zv.y;
        const double dz = (double)ev.z - zv.z, dw = (double)ev.w - zv.w;
        sm += dx * dx + dy * dy + dz * dz + dw * dw;
        zp[ll + r * 32] = ev;
    }
    for (int off = 32; off; off >>= 1) sm += __shfl_down(sm, off, 64);
    const int wid = t >> 6, lane = t & 63;
    if (lane == 0) wsum[wid] = sm;
    __syncthreads();
    if (t == 0) part[blockIdx.x] = (float)(wsum[0] + wsum[1] + wsum[2] + wsum[3]);
}

// ---------------------------------------------------------------- final diff reduction (f64)
__global__ __launch_bounds__(256) void k_final(const float* __restrict__ part,
                                               float* __restrict__ out_diff) {
    __shared__ double wsum[4];
    double sm = 0.0;
#pragma unroll
    for (int i = 0; i < 4; ++i) sm += (double)part[threadIdx.x + i * 256];
    for (int off = 32; off; off >>= 1) sm += __shfl_down(sm, off, 64);
    const int wid = threadIdx.x >> 6, lane = threadIdx.x & 63;
    if (lane == 0) wsum[wid] = sm;
    __syncthreads();
    if (threadIdx.x == 0)
        out_diff[0] = (float)(2.0 * (wsum[0] + wsum[1] + wsum[2] + wsum[3]) / 2097152.0);
}

extern "C" void kernel_launch(void* const* d_in, const int* in_sizes, int n_in,
                              void* d_out, int out_size, void* d_ws, size_t ws_size,
                              hipStream_t stream) {
    const float* z     = (const float*)d_in[0];
    const float* pw    = (const float*)d_in[1];
    const float* pb    = (const float*)d_in[2];
    const float* embed = (const float*)d_in[3];
    float* out = (float*)d_out;
    char*  ws  = (char*)d_ws;

    u64t*           amin  = (u64t*)(ws + WS_AMIN);
    float*          A     = (float*)(ws + WS_A);
    float*          Nf    = (float*)(ws + WS_N);
    unsigned*       e2    = (unsigned*)(ws + WS_EMAX);
    float*          bmin  = (float*)(ws + WS_BMIN);
    float*          bsec  = (float*)(ws + WS_BSEC);
    unsigned short* bargk = (unsigned short*)(ws + WS_BARGK);
    unsigned short* dlist = (unsigned short*)(ws + WS_DLIST);
    int*            dcnt  = (int*)(ws + WS_DCNT);
    float*          part  = (float*)(ws + WS_PART);

    float* ze       = out + OUT_ZQ;      // z_e lives in z_q slot, overwritten by gather
    float* out_diff = out + OUT_DIFF;
    float* out_ind  = out + OUT_IND;

    k_init    <<<32,   256, 0, stream>>>(amin, dcnt, e2);
    k_ze_np   <<<512,  256, 0, stream>>>(z, pw, pb, ze);
    k_rowstats<<<64,   256, 0, stream>>>(ze, embed, A, Nf, e2);
    k_mfma    <<<512,  256, 0, stream>>>(ze, embed, A, Nf, bmin, bsec, bargk);
    k_sel     <<<32,   256, 0, stream>>>(ze, embed, A, Nf, e2, bmin, bsec, bargk, amin, dlist, dcnt);
    k_deep    <<<4096, 256, 0, stream>>>(ze, embed, A, Nf, dlist, dcnt, amin);
    k_combine <<<32,   256, 0, stream>>>(amin, out_ind);
    k_gather  <<<1024, 256, 0, stream>>>(embed, out + OUT_ZQ, out_ind, part);
    k_final   <<<1,    256, 0, stream>>>(part, out_diff);
}

// Round 12
// 486.076 us; speedup vs baseline: 1.7418x; 1.7418x over previous
//
#include <hip/hip_runtime.h>

#define OUT_ZQ   0
#define OUT_DIFF 2097152
#define OUT_IND  2097153

// ws layout (bytes) — total 528,464 <= proven 565,248
#define WS_AMIN   0        // u64[8192]
#define WS_A      65536    // f32[8192]
#define WS_N      98304    // f32[8192]
#define WS_EMAX   131072   // u32 (+pad)
#define WS_BMIN   131136   // f32[4][8192]
#define WS_BSEC   262208   // f32[4][8192]
#define WS_BARGK  393280   // u16[4][8192]
#define WS_DLIST  458816   // u16[4][8192]
#define WS_DCNT   524352   // i32[4]
#define WS_PART   524368   // f32[1024]

typedef unsigned long long u64t;
typedef __attribute__((ext_vector_type(8))) short bf16x8;
typedef __attribute__((ext_vector_type(4))) float f32x4;

__device__ inline unsigned short bf16rn(float f) {
    unsigned u = __float_as_uint(f);
    return (unsigned short)((u + 0x7fffu + ((u >> 16) & 1u)) >> 16);
}
__device__ inline float bf16tof(unsigned short h) { return __uint_as_float(((unsigned)h) << 16); }

// ---------------------------------------------------------------- init
__global__ __launch_bounds__(256) void k_init(u64t* __restrict__ amin,
                                              int* __restrict__ dcnt,
                                              unsigned* __restrict__ e2) {
    const int i = blockIdx.x * 256 + threadIdx.x;
    amin[i] = ~0ULL;
    if (i < 4) dcnt[i] = 0;
    if (i == 4) *e2 = 0u;
}

// ---------------------------------------------------------------- z_e: bit-exact np.einsum replica (verified r5-r11)
__global__ __launch_bounds__(256) void k_ze_np(const float* __restrict__ z,
                                               const float* __restrict__ pw,
                                               const float* __restrict__ pb,
                                               float* __restrict__ ze) {
    __shared__ float lz[32][16];
    __shared__ float lw[256][33];
    const int t   = threadIdx.x;
    const int b   = blockIdx.x >> 6;
    const int hw0 = (blockIdx.x & 63) * 16;

    float acc[16];
#pragma unroll
    for (int p = 0; p < 16; ++p) acc[p] = 0.0f;

    for (int cc = 0; cc < 256; cc += 32) {
        float4 wv[8];
        const float4* wsrc = reinterpret_cast<const float4*>(pw + (size_t)t * 256 + cc);
#pragma unroll
        for (int i = 0; i < 8; ++i) wv[i] = wsrc[i];
        float zv[2];
#pragma unroll
        for (int i = 0; i < 2; ++i) {
            const int f = t + i * 256;
            zv[i] = z[(size_t)(b * 256 + cc + (f >> 4)) * 1024 + hw0 + (f & 15)];
        }
        __syncthreads();
#pragma unroll
        for (int i = 0; i < 8; ++i) {
            lw[t][i * 4 + 0] = wv[i].x;
            lw[t][i * 4 + 1] = wv[i].y;
            lw[t][i * 4 + 2] = wv[i].z;
            lw[t][i * 4 + 3] = wv[i].w;
        }
#pragma unroll
        for (int i = 0; i < 2; ++i) {
            const int f = t + i * 256;
            lz[f >> 4][f & 15] = zv[i];
        }
        __syncthreads();
#pragma unroll 8
        for (int cl = 0; cl < 32; ++cl) {
            const float wl = lw[t][cl];
#pragma unroll
            for (int p = 0; p < 16; ++p)
                acc[p] = __fadd_rn(acc[p], __fmul_rn(lz[cl][p], wl));
        }
    }
    const float bb = pb[t];
#pragma unroll
    for (int p = 0; p < 16; ++p)
        ze[(size_t)(b * 1024 + hw0 + p) * 256 + t] = __fadd_rn(acc[p], bb);
}

// ---------------------------------------------------------------- np pairwise row-norms + embed-norm max
__global__ __launch_bounds__(256) void k_rowstats(const float* __restrict__ ze,
                                                  const float* __restrict__ embed,
                                                  float* __restrict__ A,
                                                  float* __restrict__ Nf,
                                                  unsigned* __restrict__ e2) {
    const int gid = blockIdx.x * 256 + threadIdx.x;
    const float* row = (gid < 8192) ? (ze + (size_t)gid * 256)
                                    : (embed + (size_t)(gid - 8192) * 256);
    float blk[2];
#pragma unroll
    for (int half = 0; half < 2; ++half) {
        const float4* r4 = reinterpret_cast<const float4*>(row + half * 128);
        float r[8];
#pragma unroll
        for (int i = 0; i < 16; ++i) {
            const float4 a = r4[i * 2], b = r4[i * 2 + 1];
            const float s[8] = {__fmul_rn(a.x, a.x), __fmul_rn(a.y, a.y),
                                __fmul_rn(a.z, a.z), __fmul_rn(a.w, a.w),
                                __fmul_rn(b.x, b.x), __fmul_rn(b.y, b.y),
                                __fmul_rn(b.z, b.z), __fmul_rn(b.w, b.w)};
            if (i == 0) {
#pragma unroll
                for (int j = 0; j < 8; ++j) r[j] = s[j];
            } else {
#pragma unroll
                for (int j = 0; j < 8; ++j) r[j] = __fadd_rn(r[j], s[j]);
            }
        }
        blk[half] = __fadd_rn(__fadd_rn(__fadd_rn(r[0], r[1]), __fadd_rn(r[2], r[3])),
                              __fadd_rn(__fadd_rn(r[4], r[5]), __fadd_rn(r[6], r[7])));
    }
    const float res = __fadd_rn(blk[0], blk[1]);
    if (gid < 8192) A[gid] = res;
    else {
        Nf[gid - 8192] = res;
        float mx = res;
        for (int off = 32; off; off >>= 1) mx = fmaxf(mx, __shfl_down(mx, off, 64));
        if ((threadIdx.x & 63) == 0) atomicMax(e2, __float_as_uint(mx));
    }
}

// ---------------------------------------------------------------- MFMA screening pass (bf16 3-product split)
__global__ __launch_bounds__(256, 2) void k_mfma(const float* __restrict__ ze,
                                                 const float* __restrict__ embed,
                                                 const float* __restrict__ A,
                                                 const float* __restrict__ Nf,
                                                 float* __restrict__ bmin,
                                                 float* __restrict__ bsec,
                                                 unsigned short* __restrict__ bargk) {
    __shared__ __align__(16) char smem[59392];
    short (*zh)[72]  = reinterpret_cast<short(*)[72]>(smem);            // [64 px][72]
    short (*zl)[72]  = reinterpret_cast<short(*)[72]>(smem + 9216);
    short (*ehi)[40] = reinterpret_cast<short(*)[40]>(smem + 18432);    // [256 k][40]
    short (*elo)[40] = reinterpret_cast<short(*)[40]>(smem + 38912);

    const int t = threadIdx.x;
    const int ks = blockIdx.x & 3, pt = blockIdx.x >> 2;
    const int pix0 = pt * 64, k0 = ks * 2048;
    const int w = t >> 6, l = t & 63;
    const int lg = l >> 4, lr = l & 15;

    float a_reg[4][4];
#pragma unroll
    for (int ti = 0; ti < 4; ++ti)
#pragma unroll
        for (int r = 0; r < 4; ++r)
            a_reg[ti][r] = A[pix0 + ti * 16 + lg * 4 + r];

    u64t bb[4][4], ss[4][4];
#pragma unroll
    for (int ti = 0; ti < 4; ++ti)
#pragma unroll
        for (int r = 0; r < 4; ++r) { bb[ti][r] = ~0ULL; ss[ti][r] = ~0ULL; }

    for (int ksub = 0; ksub < 8; ++ksub) {
        f32x4 acc[4][4];
#pragma unroll
        for (int ti = 0; ti < 4; ++ti)
#pragma unroll
            for (int tj = 0; tj < 4; ++tj) acc[ti][tj] = (f32x4)(0.0f);

        for (int cq = 0; cq < 4; ++cq) {
            {   // stage z quarter: 2*z_e -> bf16 hi/lo
                const int row = t >> 2, c0 = (t & 3) * 16;
                const float4* src = reinterpret_cast<const float4*>(
                    ze + (size_t)(pix0 + row) * 256 + cq * 64 + c0);
                float4 v4[4];
#pragma unroll
                for (int m = 0; m < 4; ++m) v4[m] = src[m];
                float xv[16] = {v4[0].x, v4[0].y, v4[0].z, v4[0].w, v4[1].x, v4[1].y, v4[1].z, v4[1].w,
                                v4[2].x, v4[2].y, v4[2].z, v4[2].w, v4[3].x, v4[3].y, v4[3].z, v4[3].w};
                __syncthreads();
                bf16x8 ph0, ph1, pl0, pl1;
#pragma unroll
                for (int i = 0; i < 16; ++i) {
                    const float x = __fmul_rn(2.0f, xv[i]);
                    const unsigned short h = bf16rn(x);
                    const unsigned short lo = bf16rn(__fsub_rn(x, bf16tof(h)));
                    if (i < 8) { ph0[i] = (short)h; pl0[i] = (short)lo; }
                    else       { ph1[i - 8] = (short)h; pl1[i - 8] = (short)lo; }
                }
                *reinterpret_cast<bf16x8*>(&zh[row][c0])     = ph0;
                *reinterpret_cast<bf16x8*>(&zh[row][c0 + 8]) = ph1;
                *reinterpret_cast<bf16x8*>(&zl[row][c0])     = pl0;
                *reinterpret_cast<bf16x8*>(&zl[row][c0 + 8]) = pl1;
                __syncthreads();
            }
            for (int cc = 0; cc < 2; ++cc) {
                {   // stage e chunk: [256 k][32 c] -> bf16 hi/lo
                    const float4* esrc = reinterpret_cast<const float4*>(
                        embed + (size_t)(k0 + ksub * 256 + t) * 256 + cq * 64 + cc * 32);
                    float4 e4[8];
#pragma unroll
                    for (int m = 0; m < 8; ++m) e4[m] = esrc[m];
                    __syncthreads();
#pragma unroll
                    for (int m = 0; m < 8; m += 2) {
                        const float ev[8] = {e4[m].x, e4[m].y, e4[m].z, e4[m].w,
                                             e4[m + 1].x, e4[m + 1].y, e4[m + 1].z, e4[m + 1].w};
                        bf16x8 phh, pll;
#pragma unroll
                        for (int i = 0; i < 8; ++i) {
                            const unsigned short h = bf16rn(ev[i]);
                            phh[i] = (short)h;
                            pll[i] = (short)bf16rn(__fsub_rn(ev[i], bf16tof(h)));
                        }
                        *reinterpret_cast<bf16x8*>(&ehi[t][m * 4]) = phh;
                        *reinterpret_cast<bf16x8*>(&elo[t][m * 4]) = pll;
                    }
                    __syncthreads();
                }
                bf16x8 ahz[4], alz[4];
                const int acol = cc * 32 + lg * 8;
#pragma unroll
                for (int ti = 0; ti < 4; ++ti) {
                    ahz[ti] = *reinterpret_cast<const bf16x8*>(&zh[ti * 16 + lr][acol]);
                    alz[ti] = *reinterpret_cast<const bf16x8*>(&zl[ti * 16 + lr][acol]);
                }
#pragma unroll
                for (int tj = 0; tj < 4; ++tj) {
                    const bf16x8 bhe = *reinterpret_cast<const bf16x8*>(&ehi[w * 64 + tj * 16 + lr][lg * 8]);
                    const bf16x8 ble = *reinterpret_cast<const bf16x8*>(&elo[w * 64 + tj * 16 + lr][lg * 8]);
#pragma unroll
                    for (int ti = 0; ti < 4; ++ti) {
                        acc[ti][tj] = __builtin_amdgcn_mfma_f32_16x16x32_bf16(ahz[ti], bhe, acc[ti][tj], 0, 0, 0);
                        acc[ti][tj] = __builtin_amdgcn_mfma_f32_16x16x32_bf16(ahz[ti], ble, acc[ti][tj], 0, 0, 0);
                        acc[ti][tj] = __builtin_amdgcn_mfma_f32_16x16x32_bf16(alz[ti], bhe, acc[ti][tj], 0, 0, 0);
                    }
                }
            }
        }
        // epilogue: vhat = f32(f64(A - M + N)), pack with k, track (best, second)
#pragma unroll
        for (int tj = 0; tj < 4; ++tj) {
            const int kk = k0 + ksub * 256 + w * 64 + tj * 16 + lr;
            const double nk = (double)Nf[kk];
#pragma unroll
            for (int ti = 0; ti < 4; ++ti) {
#pragma unroll
                for (int r = 0; r < 4; ++r) {
                    const float vv = (float)((double)a_reg[ti][r] - (double)acc[ti][tj][r] + nk);
                    const u64t key = ((u64t)__float_as_uint(vv) << 32) | (unsigned)kk;
                    if (key < bb[ti][r]) { ss[ti][r] = bb[ti][r]; bb[ti][r] = key; }
                    else if (key < ss[ti][r]) ss[ti][r] = key;
                }
            }
        }
    }
    // cross-lane tournament within each 16-lane group (exact 2-smallest)
#pragma unroll
    for (int ti = 0; ti < 4; ++ti)
#pragma unroll
        for (int r = 0; r < 4; ++r) {
            u64t b = bb[ti][r], s2 = ss[ti][r];
#pragma unroll
            for (int m = 1; m <= 8; m <<= 1) {
                const u64t ob = __shfl_xor(b, m, 64);
                const u64t os = __shfl_xor(s2, m, 64);
                const u64t nb = (b < ob) ? b : ob;
                const u64t mx = (b < ob) ? ob : b;
                u64t ns = (os < s2) ? os : s2;
                ns = (mx < ns) ? mx : ns;
                b = nb; s2 = ns;
            }
            bb[ti][r] = b; ss[ti][r] = s2;
        }
    __syncthreads();
    u64t (*mrg)[4][2] = reinterpret_cast<u64t(*)[4][2]>(smem + 18432);  // overlay on e-bufs
    if (lr == 0) {
#pragma unroll
        for (int ti = 0; ti < 4; ++ti)
#pragma unroll
            for (int r = 0; r < 4; ++r) {
                mrg[ti * 16 + lg * 4 + r][w][0] = bb[ti][r];
                mrg[ti * 16 + lg * 4 + r][w][1] = ss[ti][r];
            }
    }
    __syncthreads();
    if (t < 64) {
        u64t B = ~0ULL, S = ~0ULL;
#pragma unroll
        for (int w4 = 0; w4 < 4; ++w4) {
            const u64t b = mrg[t][w4][0], s2 = mrg[t][w4][1];
            const u64t nb = (B < b) ? B : b;
            const u64t mx = (B < b) ? b : B;
            u64t ns = (S < s2) ? S : s2;
            ns = (mx < ns) ? mx : ns;
            B = nb; S = ns;
        }
        bmin[ks * 8192 + pix0 + t]  = __uint_as_float((unsigned)(B >> 32));
        bsec[ks * 8192 + pix0 + t]  = __uint_as_float((unsigned)(S >> 32));
        bargk[ks * 8192 + pix0 + t] = (unsigned short)(B & 0xffffu);
    }
}

// ---------------------------------------------------------------- select: candidates exact np rescore + deep flags
__global__ __launch_bounds__(256) void k_sel(const float* __restrict__ ze,
                                             const float* __restrict__ embed,
                                             const float* __restrict__ A,
                                             const float* __restrict__ Nf,
                                             const unsigned* __restrict__ e2,
                                             const float* __restrict__ bmin,
                                             const float* __restrict__ bsec,
                                             const unsigned short* __restrict__ bargk,
                                             u64t* __restrict__ amin,
                                             unsigned short* __restrict__ dlist,
                                             int* __restrict__ dcnt) {
    const int px = blockIdx.x * 256 + threadIdx.x;
    const float a = A[px];
    float m = bmin[px];
#pragma unroll
    for (int s = 1; s < 4; ++s) m = fminf(m, bmin[s * 8192 + px]);
    const float Em = sqrtf(__uint_as_float(*e2));
    const float S = __fmul_rn(2.0f, sqrtf(a)) * Em;           // CS bound on |M2|
    const unsigned eb = (__float_as_uint(a + 0.125f) >> 23) & 255u;
    const float up = __uint_as_float((eb - 23u) << 23);        // ulp at A's binade
    const float thresh = m + 2.0f * (1.5e-4f * S + 1.6f * up + 1.0e-6f);
#pragma unroll
    for (int s = 0; s < 4; ++s) {
        if (bmin[s * 8192 + px] <= thresh) {
            const int k = bargk[s * 8192 + px];
            const float4* zr = reinterpret_cast<const float4*>(ze + (size_t)px * 256);
            const float4* er = reinterpret_cast<const float4*>(embed + (size_t)k * 256);
            float acc = 0.0f;
            for (int i = 0; i < 64; ++i) {
                const float4 z4 = zr[i], e4 = er[i];
                acc = fmaf(__fmul_rn(2.0f, z4.x), e4.x, acc);
                acc = fmaf(__fmul_rn(2.0f, z4.y), e4.y, acc);
                acc = fmaf(__fmul_rn(2.0f, z4.z), e4.z, acc);
                acc = fmaf(__fmul_rn(2.0f, z4.w), e4.w, acc);
            }
            const float v = __fadd_rn(__fsub_rn(a, acc), Nf[k]);
            atomicMin(&amin[px], ((u64t)__float_as_uint(v) << 32) | (unsigned)k);
        }
        if (bsec[s * 8192 + px] <= thresh) {
            const int pos = atomicAdd(&dcnt[s], 1);
            dlist[s * 8192 + pos] = (unsigned short)px;
        }
    }
}

// ---------------------------------------------------------------- deep: exact np rescore of a whole 2048-k split
// v2: per-thread register min, block-level LDS reduction, ONE atomicMin per pixel per block.
__global__ __launch_bounds__(256) void k_deep(const float* __restrict__ ze,
                                              const float* __restrict__ embed,
                                              const float* __restrict__ A,
                                              const float* __restrict__ Nf,
                                              const unsigned short* __restrict__ dlist,
                                              const int* __restrict__ dcnt,
                                              u64t* __restrict__ amin) {
    const int s = blockIdx.x >> 10;
    const int bkt = blockIdx.x & 1023;
    int n = dcnt[s]; if (n > 8192) n = 8192;
    const int i0 = bkt * 8;
    if (i0 >= n) return;
    __shared__ int spx[8];
    __shared__ float sA[8];
    __shared__ __align__(16) float lz2[8][264];
    __shared__ __align__(16) float echA[128][36];   // even k rows
    __shared__ __align__(16) float echB[128][36];   // odd k rows
    __shared__ u64t redm[8][128];
    const int t = threadIdx.x;
    if (t < 8) {
        const int v = (i0 + t < n) ? (int)dlist[s * 8192 + i0 + t] : -1;
        spx[t] = v;
        sA[t] = (v >= 0) ? A[v] : 0.0f;
    }
    __syncthreads();
    {   // stage 2*z_e rows
        const int row = t >> 5, c0 = (t & 31) * 8;
        float4 v0 = make_float4(0.f, 0.f, 0.f, 0.f), v1 = v0;
        const int px = spx[row];
        if (px >= 0) {
            const float4* zr = reinterpret_cast<const float4*>(ze + (size_t)px * 256 + c0);
            v0 = zr[0]; v1 = zr[1];
        }
        lz2[row][c0 + 0] = __fmul_rn(2.0f, v0.x);
        lz2[row][c0 + 1] = __fmul_rn(2.0f, v0.y);
        lz2[row][c0 + 2] = __fmul_rn(2.0f, v0.z);
        lz2[row][c0 + 3] = __fmul_rn(2.0f, v0.w);
        lz2[row][c0 + 4] = __fmul_rn(2.0f, v1.x);
        lz2[row][c0 + 5] = __fmul_rn(2.0f, v1.y);
        lz2[row][c0 + 6] = __fmul_rn(2.0f, v1.z);
        lz2[row][c0 + 7] = __fmul_rn(2.0f, v1.w);
    }
    __syncthreads();
    const int pxg = t >> 7, kg = t & 127;
    u64t pbest[4];
#pragma unroll
    for (int p = 0; p < 4; ++p) pbest[p] = ~0ULL;
    for (int kc = 0; kc < 8; ++kc) {
        float acc[4][2];
#pragma unroll
        for (int p = 0; p < 4; ++p) { acc[p][0] = 0.0f; acc[p][1] = 0.0f; }
        for (int cc = 0; cc < 8; ++cc) {
            const float4* esrc = reinterpret_cast<const float4*>(
                embed + (size_t)(s * 2048 + kc * 256 + t) * 256 + cc * 32);
            float4 ev[8];
#pragma unroll
            for (int m = 0; m < 8; ++m) ev[m] = esrc[m];
            __syncthreads();
            {
                float* dst = (t & 1) ? &echB[t >> 1][0] : &echA[t >> 1][0];
#pragma unroll
                for (int m = 0; m < 8; ++m) {
                    dst[m * 4 + 0] = ev[m].x; dst[m * 4 + 1] = ev[m].y;
                    dst[m * 4 + 2] = ev[m].z; dst[m * 4 + 3] = ev[m].w;
                }
            }
            __syncthreads();
#pragma unroll
            for (int c4 = 0; c4 < 8; ++c4) {
                const float4 e0 = *reinterpret_cast<const float4*>(&echA[kg][c4 * 4]);
                const float4 e1 = *reinterpret_cast<const float4*>(&echB[kg][c4 * 4]);
#pragma unroll
                for (int p = 0; p < 4; ++p) {
                    const float4 zq = *reinterpret_cast<const float4*>(&lz2[pxg * 4 + p][cc * 32 + c4 * 4]);
                    acc[p][0] = fmaf(zq.x, e0.x, acc[p][0]);
                    acc[p][0] = fmaf(zq.y, e0.y, acc[p][0]);
                    acc[p][0] = fmaf(zq.z, e0.z, acc[p][0]);
                    acc[p][0] = fmaf(zq.w, e0.w, acc[p][0]);
                    acc[p][1] = fmaf(zq.x, e1.x, acc[p][1]);
                    acc[p][1] = fmaf(zq.y, e1.y, acc[p][1]);
                    acc[p][1] = fmaf(zq.z, e1.z, acc[p][1]);
                    acc[p][1] = fmaf(zq.w, e1.w, acc[p][1]);
                }
            }
        }
        // fold this kc-chunk into per-thread register mins (k ascending; packed key = lexicographic)
#pragma unroll
        for (int p = 0; p < 4; ++p) {
#pragma unroll
            for (int j = 0; j < 2; ++j) {
                const int k = s * 2048 + kc * 256 + kg * 2 + j;
                const float v = __fadd_rn(__fsub_rn(sA[pxg * 4 + p], acc[p][j]), Nf[k]);
                const u64t key = ((u64t)__float_as_uint(v) << 32) | (unsigned)k;
                pbest[p] = (key < pbest[p]) ? key : pbest[p];
            }
        }
    }
    // block reduction: 8 px x 128 contributors -> 8 atomics
#pragma unroll
    for (int p = 0; p < 4; ++p) redm[pxg * 4 + p][kg] = pbest[p];
    __syncthreads();
    if (t < 8) {
        u64t bv = ~0ULL;
        for (int q = 0; q < 128; ++q) {
            const u64t v = redm[t][q];
            bv = (v < bv) ? v : bv;
        }
        if (spx[t] >= 0) atomicMin(&amin[spx[t]], bv);
    }
}

// ---------------------------------------------------------------- unpack argmin
__global__ __launch_bounds__(256) void k_combine(const u64t* __restrict__ amin,
                                                 float* __restrict__ out_ind) {
    const int nn = blockIdx.x * 256 + threadIdx.x;
    out_ind[nn] = (float)(unsigned)(amin[nn] & 0xffffffffULL);
}

// ---------------------------------------------------------------- gather z_q (overwrite z_e) + partial MSE (f64)
__global__ __launch_bounds__(256) void k_gather(const float* __restrict__ embed,
                                                float* __restrict__ out,
                                                const float* __restrict__ out_ind,
                                                float* __restrict__ part) {
    __shared__ double wsum[4];
    const int t = threadIdx.x;
    const int g = t >> 5, ll = t & 31;
    const int nn = blockIdx.x * 8 + g;
    const int idx = (int)(out_ind[nn] + 0.5f);
    const float4* ev4 = reinterpret_cast<const float4*>(embed + (size_t)idx * 256);
    float4* zp = reinterpret_cast<float4*>(out + (size_t)nn * 256);
    double sm = 0.0;
#pragma unroll
    for (int r = 0; r < 2; ++r) {
        const float4 ev = ev4[ll + r * 32];
        const float4 zv = zp[ll + r * 32];
        const double dx = (double)ev.x - zv.x, dy = (double)ev.y - zv.y;
        const double dz = (double)ev.z - zv.z, dw = (double)ev.w - zv.w;
        sm += dx * dx + dy * dy + dz * dz + dw * dw;
        zp[ll + r * 32] = ev;
    }
    for (int off = 32; off; off >>= 1) sm += __shfl_down(sm, off, 64);
    const int wid = t >> 6, lane = t & 63;
    if (lane == 0) wsum[wid] = sm;
    __syncthreads();
    if (t == 0) part[blockIdx.x] = (float)(wsum[0] + wsum[1] + wsum[2] + wsum[3]);
}

// ---------------------------------------------------------------- final diff reduction (f64)
__global__ __launch_bounds__(256) void k_final(const float* __restrict__ part,
                                               float* __restrict__ out_diff) {
    __shared__ double wsum[4];
    double sm = 0.0;
#pragma unroll
    for (int i = 0; i < 4; ++i) sm += (double)part[threadIdx.x + i * 256];
    for (int off = 32; off; off >>= 1) sm += __shfl_down(sm, off, 64);
    const int wid = threadIdx.x >> 6, lane = threadIdx.x & 63;
    if (lane == 0) wsum[wid] = sm;
    __syncthreads();
    if (threadIdx.x == 0)
        out_diff[0] = (float)(2.0 * (wsum[0] + wsum[1] + wsum[2] + wsum[3]) / 2097152.0);
}

extern "C" void kernel_launch(void* const* d_in, const int* in_sizes, int n_in,
                              void* d_out, int out_size, void* d_ws, size_t ws_size,
                              hipStream_t stream) {
    const float* z     = (const float*)d_in[0];
    const float* pw    = (const float*)d_in[1];
    const float* pb    = (const float*)d_in[2];
    const float* embed = (const float*)d_in[3];
    float* out = (float*)d_out;
    char*  ws  = (char*)d_ws;

    u64t*           amin  = (u64t*)(ws + WS_AMIN);
    float*          A     = (float*)(ws + WS_A);
    float*          Nf    = (float*)(ws + WS_N);
    unsigned*       e2    = (unsigned*)(ws + WS_EMAX);
    float*          bmin  = (float*)(ws + WS_BMIN);
    float*          bsec  = (float*)(ws + WS_BSEC);
    unsigned short* bargk = (unsigned short*)(ws + WS_BARGK);
    unsigned short* dlist = (unsigned short*)(ws + WS_DLIST);
    int*            dcnt  = (int*)(ws + WS_DCNT);
    float*          part  = (float*)(ws + WS_PART);

    float* ze       = out + OUT_ZQ;      // z_e lives in z_q slot, overwritten by gather
    float* out_diff = out + OUT_DIFF;
    float* out_ind  = out + OUT_IND;

    k_init    <<<32,   256, 0, stream>>>(amin, dcnt, e2);
    k_ze_np   <<<512,  256, 0, stream>>>(z, pw, pb, ze);
    k_rowstats<<<64,   256, 0, stream>>>(ze, embed, A, Nf, e2);
    k_mfma    <<<512,  256, 0, stream>>>(ze, embed, A, Nf, bmin, bsec, bargk);
    k_sel     <<<32,   256, 0, stream>>>(ze, embed, A, Nf, e2, bmin, bsec, bargk, amin, dlist, dcnt);
    k_deep    <<<4096, 256, 0, stream>>>(ze, embed, A, Nf, dlist, dcnt, amin);
    k_combine <<<32,   256, 0, stream>>>(amin, out_ind);
    k_gather  <<<1024, 256, 0, stream>>>(embed, out + OUT_ZQ, out_ind, part);
    k_final   <<<1,    256, 0, stream>>>(part, out_diff);
}

// Round 13
// 445.837 us; speedup vs baseline: 1.8990x; 1.0903x over previous
//
#include <hip/hip_runtime.h>

#define OUT_ZQ   0
#define OUT_DIFF 2097152
#define OUT_IND  2097153

// ws layout (bytes) — base total 528,464 <= proven 565,248
#define WS_AMIN   0        // u64[8192]
#define WS_A      65536    // f32[8192]
#define WS_N      98304    // f32[8192]
#define WS_EMAX   131072   // u32 (+pad)
#define WS_BMIN   131136   // f32[4][8192]
#define WS_BSEC   262208   // f32[4][8192]
#define WS_BARGK  393280   // u16[4][8192]
#define WS_DLIST  458816   // u16[4][8192]
#define WS_DCNT   524352   // i32[4]
#define WS_PART   524368   // f32[1024]
// optional big region (only if ws_size allows): precomputed bf16 hi/lo
#define WS_ZH     532480   // u16[8192*256] = 4 MB   (hi of 2*z_e)
#define WS_ZL     4726784  // u16[8192*256]          (lo of 2*z_e)
#define WS_EH     8921088  // u16[8192*256]          (hi of embed)
#define WS_EL     13115392 // u16[8192*256]          (lo of embed)
#define WS_BIG_END 17309696ULL

typedef unsigned long long u64t;
typedef __attribute__((ext_vector_type(8))) short bf16x8;
typedef __attribute__((ext_vector_type(4))) float f32x4;

__device__ inline unsigned short bf16rn(float f) {
    unsigned u = __float_as_uint(f);
    return (unsigned short)((u + 0x7fffu + ((u >> 16) & 1u)) >> 16);
}
__device__ inline float bf16tof(unsigned short h) { return __uint_as_float(((unsigned)h) << 16); }

// ---------------------------------------------------------------- init
__global__ __launch_bounds__(256) void k_init(u64t* __restrict__ amin,
                                              int* __restrict__ dcnt,
                                              unsigned* __restrict__ e2) {
    const int i = blockIdx.x * 256 + threadIdx.x;
    amin[i] = ~0ULL;
    if (i < 4) dcnt[i] = 0;
    if (i == 4) *e2 = 0u;
}

// ---------------------------------------------------------------- z_e: bit-exact np.einsum replica (verified r5-r12)
__global__ __launch_bounds__(256) void k_ze_np(const float* __restrict__ z,
                                               const float* __restrict__ pw,
                                               const float* __restrict__ pb,
                                               float* __restrict__ ze) {
    __shared__ float lz[32][16];
    __shared__ float lw[256][33];
    const int t   = threadIdx.x;
    const int b   = blockIdx.x >> 6;
    const int hw0 = (blockIdx.x & 63) * 16;

    float acc[16];
#pragma unroll
    for (int p = 0; p < 16; ++p) acc[p] = 0.0f;

    for (int cc = 0; cc < 256; cc += 32) {
        float4 wv[8];
        const float4* wsrc = reinterpret_cast<const float4*>(pw + (size_t)t * 256 + cc);
#pragma unroll
        for (int i = 0; i < 8; ++i) wv[i] = wsrc[i];
        float zv[2];
#pragma unroll
        for (int i = 0; i < 2; ++i) {
            const int f = t + i * 256;
            zv[i] = z[(size_t)(b * 256 + cc + (f >> 4)) * 1024 + hw0 + (f & 15)];
        }
        __syncthreads();
#pragma unroll
        for (int i = 0; i < 8; ++i) {
            lw[t][i * 4 + 0] = wv[i].x;
            lw[t][i * 4 + 1] = wv[i].y;
            lw[t][i * 4 + 2] = wv[i].z;
            lw[t][i * 4 + 3] = wv[i].w;
        }
#pragma unroll
        for (int i = 0; i < 2; ++i) {
            const int f = t + i * 256;
            lz[f >> 4][f & 15] = zv[i];
        }
        __syncthreads();
#pragma unroll 8
        for (int cl = 0; cl < 32; ++cl) {
            const float wl = lw[t][cl];
#pragma unroll
            for (int p = 0; p < 16; ++p)
                acc[p] = __fadd_rn(acc[p], __fmul_rn(lz[cl][p], wl));
        }
    }
    const float bb = pb[t];
#pragma unroll
    for (int p = 0; p < 16; ++p)
        ze[(size_t)(b * 1024 + hw0 + p) * 256 + t] = __fadd_rn(acc[p], bb);
}

// ---------------------------------------------------------------- np pairwise row-norms (+unused e2 kept)
__global__ __launch_bounds__(256) void k_rowstats(const float* __restrict__ ze,
                                                  const float* __restrict__ embed,
                                                  float* __restrict__ A,
                                                  float* __restrict__ Nf,
                                                  unsigned* __restrict__ e2) {
    const int gid = blockIdx.x * 256 + threadIdx.x;
    const float* row = (gid < 8192) ? (ze + (size_t)gid * 256)
                                    : (embed + (size_t)(gid - 8192) * 256);
    float blk[2];
#pragma unroll
    for (int half = 0; half < 2; ++half) {
        const float4* r4 = reinterpret_cast<const float4*>(row + half * 128);
        float r[8];
#pragma unroll
        for (int i = 0; i < 16; ++i) {
            const float4 a = r4[i * 2], b = r4[i * 2 + 1];
            const float s[8] = {__fmul_rn(a.x, a.x), __fmul_rn(a.y, a.y),
                                __fmul_rn(a.z, a.z), __fmul_rn(a.w, a.w),
                                __fmul_rn(b.x, b.x), __fmul_rn(b.y, b.y),
                                __fmul_rn(b.z, b.z), __fmul_rn(b.w, b.w)};
            if (i == 0) {
#pragma unroll
                for (int j = 0; j < 8; ++j) r[j] = s[j];
            } else {
#pragma unroll
                for (int j = 0; j < 8; ++j) r[j] = __fadd_rn(r[j], s[j]);
            }
        }
        blk[half] = __fadd_rn(__fadd_rn(__fadd_rn(r[0], r[1]), __fadd_rn(r[2], r[3])),
                              __fadd_rn(__fadd_rn(r[4], r[5]), __fadd_rn(r[6], r[7])));
    }
    const float res = __fadd_rn(blk[0], blk[1]);
    if (gid < 8192) A[gid] = res;
    else {
        Nf[gid - 8192] = res;
        float mx = res;
        for (int off = 32; off; off >>= 1) mx = fmaxf(mx, __shfl_down(mx, off, 64));
        if ((threadIdx.x & 63) == 0) atomicMax(e2, __float_as_uint(mx));
    }
}

// ---------------------------------------------------------------- one-time bf16 hi/lo precompute (big-ws path)
// rows 0..8191: 2*z_e (exact prescale) -> zh/zl.  rows 8192..16383: embed -> eh/el.
// Formulas bit-identical to the in-kernel conversion used in rounds 11-12.
__global__ __launch_bounds__(256) void k_cvt(const float* __restrict__ ze,
                                             const float* __restrict__ embed,
                                             unsigned short* __restrict__ zh,
                                             unsigned short* __restrict__ zl,
                                             unsigned short* __restrict__ eh,
                                             unsigned short* __restrict__ el) {
    const int t   = threadIdx.x;
    const int row = blockIdx.x * 4 + (t >> 6);
    const int c0  = (t & 63) * 4;
    if (row < 8192) {
        const float4 v = *reinterpret_cast<const float4*>(ze + (size_t)row * 256 + c0);
        const float x[4] = {__fmul_rn(2.0f, v.x), __fmul_rn(2.0f, v.y),
                            __fmul_rn(2.0f, v.z), __fmul_rn(2.0f, v.w)};
        ushort4 h, l;
        unsigned short hv[4], lv[4];
#pragma unroll
        for (int i = 0; i < 4; ++i) {
            hv[i] = bf16rn(x[i]);
            lv[i] = bf16rn(__fsub_rn(x[i], bf16tof(hv[i])));
        }
        h = make_ushort4(hv[0], hv[1], hv[2], hv[3]);
        l = make_ushort4(lv[0], lv[1], lv[2], lv[3]);
        *reinterpret_cast<ushort4*>(zh + (size_t)row * 256 + c0) = h;
        *reinterpret_cast<ushort4*>(zl + (size_t)row * 256 + c0) = l;
    } else {
        const int r2 = row - 8192;
        const float4 v = *reinterpret_cast<const float4*>(embed + (size_t)r2 * 256 + c0);
        const float x[4] = {v.x, v.y, v.z, v.w};
        unsigned short hv[4], lv[4];
#pragma unroll
        for (int i = 0; i < 4; ++i) {
            hv[i] = bf16rn(x[i]);
            lv[i] = bf16rn(__fsub_rn(x[i], bf16tof(hv[i])));
        }
        *reinterpret_cast<ushort4*>(eh + (size_t)r2 * 256 + c0) = make_ushort4(hv[0], hv[1], hv[2], hv[3]);
        *reinterpret_cast<ushort4*>(el + (size_t)r2 * 256 + c0) = make_ushort4(lv[0], lv[1], lv[2], lv[3]);
    }
}

// ---------------------------------------------------------------- MFMA screening pass (bf16 3-product split)
// PRE=1: staged from precomputed u16 arrays (no VALU conversion). PRE=0: inline conversion (r12 path).
// Epilogue: f32 np-style vv = fl(fl(A - Mtilde) + N); capture window 4u handled in k_sel.
template <int PRE>
__global__ __launch_bounds__(256, 2) void k_mfma(const float* __restrict__ ze,
                                                 const float* __restrict__ embed,
                                                 const float* __restrict__ A,
                                                 const float* __restrict__ Nf,
                                                 const unsigned short* __restrict__ zh_g,
                                                 const unsigned short* __restrict__ zl_g,
                                                 const unsigned short* __restrict__ eh_g,
                                                 const unsigned short* __restrict__ el_g,
                                                 float* __restrict__ bmin,
                                                 float* __restrict__ bsec,
                                                 unsigned short* __restrict__ bargk) {
    __shared__ __align__(16) char smem[59392];
    short (*zh)[72]  = reinterpret_cast<short(*)[72]>(smem);            // [64 px][72]
    short (*zl)[72]  = reinterpret_cast<short(*)[72]>(smem + 9216);
    short (*ehi)[40] = reinterpret_cast<short(*)[40]>(smem + 18432);    // [256 k][40]
    short (*elo)[40] = reinterpret_cast<short(*)[40]>(smem + 38912);

    const int t = threadIdx.x;
    const int ks = blockIdx.x & 3, pt = blockIdx.x >> 2;
    const int pix0 = pt * 64, k0 = ks * 2048;
    const int w = t >> 6, l = t & 63;
    const int lg = l >> 4, lr = l & 15;

    float a_reg[4][4];
#pragma unroll
    for (int ti = 0; ti < 4; ++ti)
#pragma unroll
        for (int r = 0; r < 4; ++r)
            a_reg[ti][r] = A[pix0 + ti * 16 + lg * 4 + r];

    u64t bb[4][4], ss[4][4];
#pragma unroll
    for (int ti = 0; ti < 4; ++ti)
#pragma unroll
        for (int r = 0; r < 4; ++r) { bb[ti][r] = ~0ULL; ss[ti][r] = ~0ULL; }

    for (int ksub = 0; ksub < 8; ++ksub) {
        f32x4 acc[4][4];
#pragma unroll
        for (int ti = 0; ti < 4; ++ti)
#pragma unroll
            for (int tj = 0; tj < 4; ++tj) acc[ti][tj] = (f32x4)(0.0f);

        for (int cq = 0; cq < 4; ++cq) {
            if constexpr (PRE) {   // stage z quarter from precomputed u16
                const int row = t >> 2, c0 = (t & 3) * 16;
                const size_t off = (size_t)(pix0 + row) * 256 + cq * 64 + c0;
                const bf16x8* sh = reinterpret_cast<const bf16x8*>(zh_g + off);
                const bf16x8* sl = reinterpret_cast<const bf16x8*>(zl_g + off);
                const bf16x8 h0 = sh[0], h1 = sh[1], l0 = sl[0], l1 = sl[1];
                __syncthreads();
                *reinterpret_cast<bf16x8*>(&zh[row][c0])     = h0;
                *reinterpret_cast<bf16x8*>(&zh[row][c0 + 8]) = h1;
                *reinterpret_cast<bf16x8*>(&zl[row][c0])     = l0;
                *reinterpret_cast<bf16x8*>(&zl[row][c0 + 8]) = l1;
                __syncthreads();
            } else {               // stage z quarter: 2*z_e -> bf16 hi/lo (inline)
                const int row = t >> 2, c0 = (t & 3) * 16;
                const float4* src = reinterpret_cast<const float4*>(
                    ze + (size_t)(pix0 + row) * 256 + cq * 64 + c0);
                float4 v4[4];
#pragma unroll
                for (int m = 0; m < 4; ++m) v4[m] = src[m];
                float xv[16] = {v4[0].x, v4[0].y, v4[0].z, v4[0].w, v4[1].x, v4[1].y, v4[1].z, v4[1].w,
                                v4[2].x, v4[2].y, v4[2].z, v4[2].w, v4[3].x, v4[3].y, v4[3].z, v4[3].w};
                __syncthreads();
                bf16x8 ph0, ph1, pl0, pl1;
#pragma unroll
                for (int i = 0; i < 16; ++i) {
                    const float x = __fmul_rn(2.0f, xv[i]);
                    const unsigned short h = bf16rn(x);
                    const unsigned short lo = bf16rn(__fsub_rn(x, bf16tof(h)));
                    if (i < 8) { ph0[i] = (short)h; pl0[i] = (short)lo; }
                    else       { ph1[i - 8] = (short)h; pl1[i - 8] = (short)lo; }
                }
                *reinterpret_cast<bf16x8*>(&zh[row][c0])     = ph0;
                *reinterpret_cast<bf16x8*>(&zh[row][c0 + 8]) = ph1;
                *reinterpret_cast<bf16x8*>(&zl[row][c0])     = pl0;
                *reinterpret_cast<bf16x8*>(&zl[row][c0 + 8]) = pl1;
                __syncthreads();
            }
            for (int cc = 0; cc < 2; ++cc) {
                if constexpr (PRE) {   // stage e chunk from precomputed u16
                    const size_t off = (size_t)(k0 + ksub * 256 + t) * 256 + cq * 64 + cc * 32;
                    const bf16x8* sh = reinterpret_cast<const bf16x8*>(eh_g + off);
                    const bf16x8* sl = reinterpret_cast<const bf16x8*>(el_g + off);
                    const bf16x8 h0 = sh[0], h1 = sh[1], h2 = sh[2], h3 = sh[3];
                    const bf16x8 l0 = sl[0], l1 = sl[1], l2 = sl[2], l3 = sl[3];
                    __syncthreads();
                    *reinterpret_cast<bf16x8*>(&ehi[t][0])  = h0;
                    *reinterpret_cast<bf16x8*>(&ehi[t][8])  = h1;
                    *reinterpret_cast<bf16x8*>(&ehi[t][16]) = h2;
                    *reinterpret_cast<bf16x8*>(&ehi[t][24]) = h3;
                    *reinterpret_cast<bf16x8*>(&elo[t][0])  = l0;
                    *reinterpret_cast<bf16x8*>(&elo[t][8])  = l1;
                    *reinterpret_cast<bf16x8*>(&elo[t][16]) = l2;
                    *reinterpret_cast<bf16x8*>(&elo[t][24]) = l3;
                    __syncthreads();
                } else {               // stage e chunk: [256 k][32 c] -> bf16 hi/lo (inline)
                    const float4* esrc = reinterpret_cast<const float4*>(
                        embed + (size_t)(k0 + ksub * 256 + t) * 256 + cq * 64 + cc * 32);
                    float4 e4[8];
#pragma unroll
                    for (int m = 0; m < 8; ++m) e4[m] = esrc[m];
                    __syncthreads();
#pragma unroll
                    for (int m = 0; m < 8; m += 2) {
                        const float ev[8] = {e4[m].x, e4[m].y, e4[m].z, e4[m].w,
                                             e4[m + 1].x, e4[m + 1].y, e4[m + 1].z, e4[m + 1].w};
                        bf16x8 phh, pll;
#pragma unroll
                        for (int i = 0; i < 8; ++i) {
                            const unsigned short h = bf16rn(ev[i]);
                            phh[i] = (short)h;
                            pll[i] = (short)bf16rn(__fsub_rn(ev[i], bf16tof(h)));
                        }
                        *reinterpret_cast<bf16x8*>(&ehi[t][m * 4]) = phh;
                        *reinterpret_cast<bf16x8*>(&elo[t][m * 4]) = pll;
                    }
                    __syncthreads();
                }
                bf16x8 ahz[4], alz[4];
                const int acol = cc * 32 + lg * 8;
#pragma unroll
                for (int ti = 0; ti < 4; ++ti) {
                    ahz[ti] = *reinterpret_cast<const bf16x8*>(&zh[ti * 16 + lr][acol]);
                    alz[ti] = *reinterpret_cast<const bf16x8*>(&zl[ti * 16 + lr][acol]);
                }
#pragma unroll
                for (int tj = 0; tj < 4; ++tj) {
                    const bf16x8 bhe = *reinterpret_cast<const bf16x8*>(&ehi[w * 64 + tj * 16 + lr][lg * 8]);
                    const bf16x8 ble = *reinterpret_cast<const bf16x8*>(&elo[w * 64 + tj * 16 + lr][lg * 8]);
#pragma unroll
                    for (int ti = 0; ti < 4; ++ti) {
                        acc[ti][tj] = __builtin_amdgcn_mfma_f32_16x16x32_bf16(ahz[ti], bhe, acc[ti][tj], 0, 0, 0);
                        acc[ti][tj] = __builtin_amdgcn_mfma_f32_16x16x32_bf16(ahz[ti], ble, acc[ti][tj], 0, 0, 0);
                        acc[ti][tj] = __builtin_amdgcn_mfma_f32_16x16x32_bf16(alz[ti], bhe, acc[ti][tj], 0, 0, 0);
                    }
                }
            }
        }
        // epilogue: vhat = fl(fl(A - Mtilde) + N) in f32 (np-style), pack with k, track (best, second)
#pragma unroll
        for (int tj = 0; tj < 4; ++tj) {
            const int kk = k0 + ksub * 256 + w * 64 + tj * 16 + lr;
            const float nk = Nf[kk];
#pragma unroll
            for (int ti = 0; ti < 4; ++ti) {
#pragma unroll
                for (int r = 0; r < 4; ++r) {
                    const float vv = __fadd_rn(__fsub_rn(a_reg[ti][r], acc[ti][tj][r]), nk);
                    const u64t key = ((u64t)__float_as_uint(vv) << 32) | (unsigned)kk;
                    if (key < bb[ti][r]) { ss[ti][r] = bb[ti][r]; bb[ti][r] = key; }
                    else if (key < ss[ti][r]) ss[ti][r] = key;
                }
            }
        }
    }
    // cross-lane tournament within each 16-lane group (exact 2-smallest)
#pragma unroll
    for (int ti = 0; ti < 4; ++ti)
#pragma unroll
        for (int r = 0; r < 4; ++r) {
            u64t b = bb[ti][r], s2 = ss[ti][r];
#pragma unroll
            for (int m = 1; m <= 8; m <<= 1) {
                const u64t ob = __shfl_xor(b, m, 64);
                const u64t os = __shfl_xor(s2, m, 64);
                const u64t nb = (b < ob) ? b : ob;
                const u64t mx = (b < ob) ? ob : b;
                u64t ns = (os < s2) ? os : s2;
                ns = (mx < ns) ? mx : ns;
                b = nb; s2 = ns;
            }
            bb[ti][r] = b; ss[ti][r] = s2;
        }
    __syncthreads();
    u64t (*mrg)[4][2] = reinterpret_cast<u64t(*)[4][2]>(smem + 18432);  // overlay on e-bufs
    if (lr == 0) {
#pragma unroll
        for (int ti = 0; ti < 4; ++ti)
#pragma unroll
            for (int r = 0; r < 4; ++r) {
                mrg[ti * 16 + lg * 4 + r][w][0] = bb[ti][r];
                mrg[ti * 16 + lg * 4 + r][w][1] = ss[ti][r];
            }
    }
    __syncthreads();
    if (t < 64) {
        u64t B = ~0ULL, S = ~0ULL;
#pragma unroll
        for (int w4 = 0; w4 < 4; ++w4) {
            const u64t b = mrg[t][w4][0], s2 = mrg[t][w4][1];
            const u64t nb = (B < b) ? B : b;
            const u64t mx = (B < b) ? b : B;
            u64t ns = (S < s2) ? S : s2;
            ns = (mx < ns) ? mx : ns;
            B = nb; S = ns;
        }
        bmin[ks * 8192 + pix0 + t]  = __uint_as_float((unsigned)(B >> 32));
        bsec[ks * 8192 + pix0 + t]  = __uint_as_float((unsigned)(S >> 32));
        bargk[ks * 8192 + pix0 + t] = (unsigned short)(B & 0xffffu);
    }
}

// ---------------------------------------------------------------- select: candidates exact np rescore + deep flags
// Window: |vhat - v_np| <= 2u + eps each (double-rounding, monotone) -> thresh = m + 4.5u + 1e-5.
__global__ __launch_bounds__(256) void k_sel(const float* __restrict__ ze,
                                             const float* __restrict__ embed,
                                             const float* __restrict__ A,
                                             const float* __restrict__ Nf,
                                             const float* __restrict__ bmin,
                                             const float* __restrict__ bsec,
                                             const unsigned short* __restrict__ bargk,
                                             u64t* __restrict__ amin,
                                             unsigned short* __restrict__ dlist,
                                             int* __restrict__ dcnt) {
    const int px = blockIdx.x * 256 + threadIdx.x;
    const float a = A[px];
    float m = bmin[px];
#pragma unroll
    for (int s = 1; s < 4; ++s) m = fminf(m, bmin[s * 8192 + px]);
    const unsigned eb = (__float_as_uint(a + 0.125f) >> 23) & 255u;
    const float up = __uint_as_float((eb - 23u) << 23);        // ulp at A's binade (conservative)
    const float thresh = m + 4.5f * up + 1.0e-5f;
#pragma unroll
    for (int s = 0; s < 4; ++s) {
        if (bmin[s * 8192 + px] <= thresh) {
            const int k = bargk[s * 8192 + px];
            const float4* zr = reinterpret_cast<const float4*>(ze + (size_t)px * 256);
            const float4* er = reinterpret_cast<const float4*>(embed + (size_t)k * 256);
            float acc = 0.0f;
            for (int i = 0; i < 64; ++i) {
                const float4 z4 = zr[i], e4 = er[i];
                acc = fmaf(__fmul_rn(2.0f, z4.x), e4.x, acc);
                acc = fmaf(__fmul_rn(2.0f, z4.y), e4.y, acc);
                acc = fmaf(__fmul_rn(2.0f, z4.z), e4.z, acc);
                acc = fmaf(__fmul_rn(2.0f, z4.w), e4.w, acc);
            }
            const float v = __fadd_rn(__fsub_rn(a, acc), Nf[k]);
            atomicMin(&amin[px], ((u64t)__float_as_uint(v) << 32) | (unsigned)k);
        }
        if (bsec[s * 8192 + px] <= thresh) {
            const int pos = atomicAdd(&dcnt[s], 1);
            if (pos < 8192) dlist[s * 8192 + pos] = (unsigned short)px;
        }
    }
}

// ---------------------------------------------------------------- deep: exact np rescore of a whole 2048-k split
// per-thread register min, block-level LDS reduction, ONE atomicMin per pixel per block (r12-verified)
__global__ __launch_bounds__(256) void k_deep(const float* __restrict__ ze,
                                              const float* __restrict__ embed,
                                              const float* __restrict__ A,
                                              const float* __restrict__ Nf,
                                              const unsigned short* __restrict__ dlist,
                                              const int* __restrict__ dcnt,
                                              u64t* __restrict__ amin) {
    const int s = blockIdx.x >> 10;
    const int bkt = blockIdx.x & 1023;
    int n = dcnt[s]; if (n > 8192) n = 8192;
    const int i0 = bkt * 8;
    if (i0 >= n) return;
    __shared__ int spx[8];
    __shared__ float sA[8];
    __shared__ __align__(16) float lz2[8][264];
    __shared__ __align__(16) float echA[128][36];
    __shared__ __align__(16) float echB[128][36];
    __shared__ u64t redm[8][128];
    const int t = threadIdx.x;
    if (t < 8) {
        const int v = (i0 + t < n) ? (int)dlist[s * 8192 + i0 + t] : -1;
        spx[t] = v;
        sA[t] = (v >= 0) ? A[v] : 0.0f;
    }
    __syncthreads();
    {
        const int row = t >> 5, c0 = (t & 31) * 8;
        float4 v0 = make_float4(0.f, 0.f, 0.f, 0.f), v1 = v0;
        const int px = spx[row];
        if (px >= 0) {
            const float4* zr = reinterpret_cast<const float4*>(ze + (size_t)px * 256 + c0);
            v0 = zr[0]; v1 = zr[1];
        }
        lz2[row][c0 + 0] = __fmul_rn(2.0f, v0.x);
        lz2[row][c0 + 1] = __fmul_rn(2.0f, v0.y);
        lz2[row][c0 + 2] = __fmul_rn(2.0f, v0.z);
        lz2[row][c0 + 3] = __fmul_rn(2.0f, v0.w);
        lz2[row][c0 + 4] = __fmul_rn(2.0f, v1.x);
        lz2[row][c0 + 5] = __fmul_rn(2.0f, v1.y);
        lz2[row][c0 + 6] = __fmul_rn(2.0f, v1.z);
        lz2[row][c0 + 7] = __fmul_rn(2.0f, v1.w);
    }
    __syncthreads();
    const int pxg = t >> 7, kg = t & 127;
    u64t pbest[4];
#pragma unroll
    for (int p = 0; p < 4; ++p) pbest[p] = ~0ULL;
    for (int kc = 0; kc < 8; ++kc) {
        float acc[4][2];
#pragma unroll
        for (int p = 0; p < 4; ++p) { acc[p][0] = 0.0f; acc[p][1] = 0.0f; }
        for (int cc = 0; cc < 8; ++cc) {
            const float4* esrc = reinterpret_cast<const float4*>(
                embed + (size_t)(s * 2048 + kc * 256 + t) * 256 + cc * 32);
            float4 ev[8];
#pragma unroll
            for (int m = 0; m < 8; ++m) ev[m] = esrc[m];
            __syncthreads();
            {
                float* dst = (t & 1) ? &echB[t >> 1][0] : &echA[t >> 1][0];
#pragma unroll
                for (int m = 0; m < 8; ++m) {
                    dst[m * 4 + 0] = ev[m].x; dst[m * 4 + 1] = ev[m].y;
                    dst[m * 4 + 2] = ev[m].z; dst[m * 4 + 3] = ev[m].w;
                }
            }
            __syncthreads();
#pragma unroll
            for (int c4 = 0; c4 < 8; ++c4) {
                const float4 e0 = *reinterpret_cast<const float4*>(&echA[kg][c4 * 4]);
                const float4 e1 = *reinterpret_cast<const float4*>(&echB[kg][c4 * 4]);
#pragma unroll
                for (int p = 0; p < 4; ++p) {
                    const float4 zq = *reinterpret_cast<const float4*>(&lz2[pxg * 4 + p][cc * 32 + c4 * 4]);
                    acc[p][0] = fmaf(zq.x, e0.x, acc[p][0]);
                    acc[p][0] = fmaf(zq.y, e0.y, acc[p][0]);
                    acc[p][0] = fmaf(zq.z, e0.z, acc[p][0]);
                    acc[p][0] = fmaf(zq.w, e0.w, acc[p][0]);
                    acc[p][1] = fmaf(zq.x, e1.x, acc[p][1]);
                    acc[p][1] = fmaf(zq.y, e1.y, acc[p][1]);
                    acc[p][1] = fmaf(zq.z, e1.z, acc[p][1]);
                    acc[p][1] = fmaf(zq.w, e1.w, acc[p][1]);
                }
            }
        }
#pragma unroll
        for (int p = 0; p < 4; ++p) {
#pragma unroll
            for (int j = 0; j < 2; ++j) {
                const int k = s * 2048 + kc * 256 + kg * 2 + j;
                const float v = __fadd_rn(__fsub_rn(sA[pxg * 4 + p], acc[p][j]), Nf[k]);
                const u64t key = ((u64t)__float_as_uint(v) << 32) | (unsigned)k;
                pbest[p] = (key < pbest[p]) ? key : pbest[p];
            }
        }
    }
#pragma unroll
    for (int p = 0; p < 4; ++p) redm[pxg * 4 + p][kg] = pbest[p];
    __syncthreads();
    if (t < 8) {
        u64t bv = ~0ULL;
        for (int q = 0; q < 128; ++q) {
            const u64t v = redm[t][q];
            bv = (v < bv) ? v : bv;
        }
        if (spx[t] >= 0) atomicMin(&amin[spx[t]], bv);
    }
}

// ---------------------------------------------------------------- unpack argmin
__global__ __launch_bounds__(256) void k_combine(const u64t* __restrict__ amin,
                                                 float* __restrict__ out_ind) {
    const int nn = blockIdx.x * 256 + threadIdx.x;
    out_ind[nn] = (float)(unsigned)(amin[nn] & 0xffffffffULL);
}

// ---------------------------------------------------------------- gather z_q (overwrite z_e) + partial MSE (f64)
__global__ __launch_bounds__(256) void k_gather(const float* __restrict__ embed,
                                                float* __restrict__ out,
                                                const float* __restrict__ out_ind,
                                                float* __restrict__ part) {
    __shared__ double wsum[4];
    const int t = threadIdx.x;
    const int g = t >> 5, ll = t & 31;
    const int nn = blockIdx.x * 8 + g;
    const int idx = (int)(out_ind[nn] + 0.5f);
    const float4* ev4 = reinterpret_cast<const float4*>(embed + (size_t)idx * 256);
    float4* zp = reinterpret_cast<float4*>(out + (size_t)nn * 256);
    double sm = 0.0;
#pragma unroll
    for (int r = 0; r < 2; ++r) {
        const float4 ev = ev4[ll + r * 32];
        const float4 zv = zp[ll + r * 32];
        const double dx = (double)ev.x - zv.x, dy = (double)ev.y - zv.y;
        const double dz = (double)ev.z - zv.z, dw = (double)ev.w - zv.w;
        sm += dx * dx + dy * dy + dz * dz + dw * dw;
        zp[ll + r * 32] = ev;
    }
    for (int off = 32; off; off >>= 1) sm += __shfl_down(sm, off, 64);
    const int wid = t >> 6, lane = t & 63;
    if (lane == 0) wsum[wid] = sm;
    __syncthreads();
    if (t == 0) part[blockIdx.x] = (float)(wsum[0] + wsum[1] + wsum[2] + wsum[3]);
}

// ---------------------------------------------------------------- final diff reduction (f64)
__global__ __launch_bounds__(256) void k_final(const float* __restrict__ part,
                                               float* __restrict__ out_diff) {
    __shared__ double wsum[4];
    double sm = 0.0;
#pragma unroll
    for (int i = 0; i < 4; ++i) sm += (double)part[threadIdx.x + i * 256];
    for (int off = 32; off; off >>= 1) sm += __shfl_down(sm, off, 64);
    const int wid = threadIdx.x >> 6, lane = threadIdx.x & 63;
    if (lane == 0) wsum[wid] = sm;
    __syncthreads();
    if (threadIdx.x == 0)
        out_diff[0] = (float)(2.0 * (wsum[0] + wsum[1] + wsum[2] + wsum[3]) / 2097152.0);
}

extern "C" void kernel_launch(void* const* d_in, const int* in_sizes, int n_in,
                              void* d_out, int out_size, void* d_ws, size_t ws_size,
                              hipStream_t stream) {
    const float* z     = (const float*)d_in[0];
    const float* pw    = (const float*)d_in[1];
    const float* pb    = (const float*)d_in[2];
    const float* embed = (const float*)d_in[3];
    float* out = (float*)d_out;
    char*  ws  = (char*)d_ws;

    u64t*           amin  = (u64t*)(ws + WS_AMIN);
    float*          A     = (float*)(ws + WS_A);
    float*          Nf    = (float*)(ws + WS_N);
    unsigned*       e2    = (unsigned*)(ws + WS_EMAX);
    float*          bmin  = (float*)(ws + WS_BMIN);
    float*          bsec  = (float*)(ws + WS_BSEC);
    unsigned short* bargk = (unsigned short*)(ws + WS_BARGK);
    unsigned short* dlist = (unsigned short*)(ws + WS_DLIST);
    int*            dcnt  = (int*)(ws + WS_DCNT);
    float*          part  = (float*)(ws + WS_PART);

    float* ze       = out + OUT_ZQ;      // z_e lives in z_q slot, overwritten by gather
    float* out_diff = out + OUT_DIFF;
    float* out_ind  = out + OUT_IND;

    const bool big = (ws_size >= WS_BIG_END);

    k_init    <<<32,   256, 0, stream>>>(amin, dcnt, e2);
    k_ze_np   <<<512,  256, 0, stream>>>(z, pw, pb, ze);
    k_rowstats<<<64,   256, 0, stream>>>(ze, embed, A, Nf, e2);
    if (big) {
        unsigned short* zh = (unsigned short*)(ws + WS_ZH);
        unsigned short* zl = (unsigned short*)(ws + WS_ZL);
        unsigned short* eh = (unsigned short*)(ws + WS_EH);
        unsigned short* el = (unsigned short*)(ws + WS_EL);
        k_cvt     <<<4096, 256, 0, stream>>>(ze, embed, zh, zl, eh, el);
        k_mfma<1> <<<512,  256, 0, stream>>>(ze, embed, A, Nf, zh, zl, eh, el, bmin, bsec, bargk);
    } else {
        k_mfma<0> <<<512,  256, 0, stream>>>(ze, embed, A, Nf, nullptr, nullptr, nullptr, nullptr,
                                             bmin, bsec, bargk);
    }
    k_sel     <<<32,   256, 0, stream>>>(ze, embed, A, Nf, bmin, bsec, bargk, amin, dlist, dcnt);
    k_deep    <<<4096, 256, 0, stream>>>(ze, embed, A, Nf, dlist, dcnt, amin);
    k_combine <<<32,   256, 0, stream>>>(amin, out_ind);
    k_gather  <<<1024, 256, 0, stream>>>(embed, out + OUT_ZQ, out_ind, part);
    k_final   <<<1,    256, 0, stream>>>(part, out_diff);
}

// Round 14
// 425.476 us; speedup vs baseline: 1.9899x; 1.0479x over previous
//
#include <hip/hip_runtime.h>

#define OUT_ZQ   0
#define OUT_DIFF 2097152
#define OUT_IND  2097153

// ws base layout (bytes) — total 528,464 <= proven 565,248
#define WS_AMIN   0        // u64[8192]
#define WS_A      65536    // f32[8192]
#define WS_N      98304    // f32[8192]
#define WS_EMAX   131072   // u32
#define WS_DLIST  458816   // u16[4][8192]
#define WS_DCNT   524352   // i32[4]
#define WS_PART   524368   // f32[1024]
// big region (gated on ws_size): top-3 keys, candidate list, chunk-major bf16 hi/lo
#define WS_BQ     532480   // u64[4][3][8192] = 786,432
#define WS_CCNT   1318912  // i32 (+pad)
#define WS_CND    1318976  // u32[98304] = 393,216
#define WS_ZH2    1712384  // u16[4][8192][64] = 4 MB   (hi of 2*z_e, quarter-major)
#define WS_ZL2    5906688  // u16[4][8192][64]          (lo)
#define WS_EH2    10100992 // u16[8][8192][32]          (hi of embed, chunk-major)
#define WS_EL2    14295296 // u16[8][8192][32]          (lo)
#define WS_BIG_END 18489600ULL
#define CAND_CAP  98304

typedef unsigned long long u64t;
typedef __attribute__((ext_vector_type(8))) short bf16x8;
typedef __attribute__((ext_vector_type(4))) float f32x4;

__device__ inline unsigned short bf16rn(float f) {
    unsigned u = __float_as_uint(f);
    return (unsigned short)((u + 0x7fffu + ((u >> 16) & 1u)) >> 16);
}
__device__ inline float bf16tof(unsigned short h) { return __uint_as_float(((unsigned)h) << 16); }

// merged top-3 of two sorted triples (verified comparator network)
__device__ inline void merge3(u64t& a1, u64t& a2, u64t& a3, u64t o1, u64t o2, u64t o3) {
    const u64t x1 = (a1 < o1) ? a1 : o1, X1 = (a1 < o1) ? o1 : a1;
    const u64t y2 = (a2 < o2) ? a2 : o2, Y2 = (a2 < o2) ? o2 : a2;
    const u64t y3 = (a3 < o3) ? a3 : o3;
    a1 = x1;
    a2 = (X1 < y2) ? X1 : y2;
    const u64t c1 = (X1 < y2) ? y2 : X1;
    const u64t c2 = (Y2 < y3) ? Y2 : y3;
    a3 = (c1 < c2) ? c1 : c2;
}

// ---------------------------------------------------------------- init
__global__ __launch_bounds__(256) void k_init(u64t* __restrict__ amin,
                                              int* __restrict__ dcnt,
                                              unsigned* __restrict__ e2) {
    const int i = blockIdx.x * 256 + threadIdx.x;
    amin[i] = ~0ULL;
    if (i < 4) dcnt[i] = 0;
    if (i == 4) *e2 = 0u;
}

// ---------------------------------------------------------------- z_e: bit-exact np.einsum replica (verified r5-r13)
__global__ __launch_bounds__(256) void k_ze_np(const float* __restrict__ z,
                                               const float* __restrict__ pw,
                                               const float* __restrict__ pb,
                                               float* __restrict__ ze) {
    __shared__ float lz[32][16];
    __shared__ float lw[256][33];
    const int t   = threadIdx.x;
    const int b   = blockIdx.x >> 6;
    const int hw0 = (blockIdx.x & 63) * 16;

    float acc[16];
#pragma unroll
    for (int p = 0; p < 16; ++p) acc[p] = 0.0f;

    for (int cc = 0; cc < 256; cc += 32) {
        float4 wv[8];
        const float4* wsrc = reinterpret_cast<const float4*>(pw + (size_t)t * 256 + cc);
#pragma unroll
        for (int i = 0; i < 8; ++i) wv[i] = wsrc[i];
        float zv[2];
#pragma unroll
        for (int i = 0; i < 2; ++i) {
            const int f = t + i * 256;
            zv[i] = z[(size_t)(b * 256 + cc + (f >> 4)) * 1024 + hw0 + (f & 15)];
        }
        __syncthreads();
#pragma unroll
        for (int i = 0; i < 8; ++i) {
            lw[t][i * 4 + 0] = wv[i].x;
            lw[t][i * 4 + 1] = wv[i].y;
            lw[t][i * 4 + 2] = wv[i].z;
            lw[t][i * 4 + 3] = wv[i].w;
        }
#pragma unroll
        for (int i = 0; i < 2; ++i) {
            const int f = t + i * 256;
            lz[f >> 4][f & 15] = zv[i];
        }
        __syncthreads();
#pragma unroll 8
        for (int cl = 0; cl < 32; ++cl) {
            const float wl = lw[t][cl];
#pragma unroll
            for (int p = 0; p < 16; ++p)
                acc[p] = __fadd_rn(acc[p], __fmul_rn(lz[cl][p], wl));
        }
    }
    const float bb = pb[t];
#pragma unroll
    for (int p = 0; p < 16; ++p)
        ze[(size_t)(b * 1024 + hw0 + p) * 256 + t] = __fadd_rn(acc[p], bb);
}

// ---------------------------------------------------------------- np pairwise row-norms
__global__ __launch_bounds__(256) void k_rowstats(const float* __restrict__ ze,
                                                  const float* __restrict__ embed,
                                                  float* __restrict__ A,
                                                  float* __restrict__ Nf,
                                                  unsigned* __restrict__ e2) {
    const int gid = blockIdx.x * 256 + threadIdx.x;
    const float* row = (gid < 8192) ? (ze + (size_t)gid * 256)
                                    : (embed + (size_t)(gid - 8192) * 256);
    float blk[2];
#pragma unroll
    for (int half = 0; half < 2; ++half) {
        const float4* r4 = reinterpret_cast<const float4*>(row + half * 128);
        float r[8];
#pragma unroll
        for (int i = 0; i < 16; ++i) {
            const float4 a = r4[i * 2], b = r4[i * 2 + 1];
            const float s[8] = {__fmul_rn(a.x, a.x), __fmul_rn(a.y, a.y),
                                __fmul_rn(a.z, a.z), __fmul_rn(a.w, a.w),
                                __fmul_rn(b.x, b.x), __fmul_rn(b.y, b.y),
                                __fmul_rn(b.z, b.z), __fmul_rn(b.w, b.w)};
            if (i == 0) {
#pragma unroll
                for (int j = 0; j < 8; ++j) r[j] = s[j];
            } else {
#pragma unroll
                for (int j = 0; j < 8; ++j) r[j] = __fadd_rn(r[j], s[j]);
            }
        }
        blk[half] = __fadd_rn(__fadd_rn(__fadd_rn(r[0], r[1]), __fadd_rn(r[2], r[3])),
                              __fadd_rn(__fadd_rn(r[4], r[5]), __fadd_rn(r[6], r[7])));
    }
    const float res = __fadd_rn(blk[0], blk[1]);
    if (gid < 8192) A[gid] = res;
    else {
        Nf[gid - 8192] = res;
        float mx = res;
        for (int off = 32; off; off >>= 1) mx = fmaxf(mx, __shfl_down(mx, off, 64));
        if ((threadIdx.x & 63) == 0) atomicMax(e2, __float_as_uint(mx));
    }
}

// ---------------------------------------------------------------- bf16 hi/lo precompute into CHUNK-MAJOR layouts
// zh2/zl2: [cq4][px][64c]; eh2/el2: [ch8][k][32c]. Formulas bit-identical to r11-13.
__global__ __launch_bounds__(256) void k_cvt(const float* __restrict__ ze,
                                             const float* __restrict__ embed,
                                             unsigned short* __restrict__ zh2,
                                             unsigned short* __restrict__ zl2,
                                             unsigned short* __restrict__ eh2,
                                             unsigned short* __restrict__ el2,
                                             int* __restrict__ ccnt) {
    const int t   = threadIdx.x;
    if (blockIdx.x == 0 && t == 0) *ccnt = 0;
    const int row = blockIdx.x * 4 + (t >> 6);
    const int c   = (t & 63) * 4;
    if (row < 8192) {
        const float4 v = *reinterpret_cast<const float4*>(ze + (size_t)row * 256 + c);
        const float x[4] = {__fmul_rn(2.0f, v.x), __fmul_rn(2.0f, v.y),
                            __fmul_rn(2.0f, v.z), __fmul_rn(2.0f, v.w)};
        unsigned short hv[4], lv[4];
#pragma unroll
        for (int i = 0; i < 4; ++i) {
            hv[i] = bf16rn(x[i]);
            lv[i] = bf16rn(__fsub_rn(x[i], bf16tof(hv[i])));
        }
        const int cq = c >> 6, cr = c & 63;
        const size_t off = ((size_t)cq * 8192 + row) * 64 + cr;
        *reinterpret_cast<ushort4*>(zh2 + off) = make_ushort4(hv[0], hv[1], hv[2], hv[3]);
        *reinterpret_cast<ushort4*>(zl2 + off) = make_ushort4(lv[0], lv[1], lv[2], lv[3]);
    } else {
        const int r2 = row - 8192;
        const float4 v = *reinterpret_cast<const float4*>(embed + (size_t)r2 * 256 + c);
        const float x[4] = {v.x, v.y, v.z, v.w};
        unsigned short hv[4], lv[4];
#pragma unroll
        for (int i = 0; i < 4; ++i) {
            hv[i] = bf16rn(x[i]);
            lv[i] = bf16rn(__fsub_rn(x[i], bf16tof(hv[i])));
        }
        const int ch = c >> 5, cr2 = c & 31;
        const size_t off = ((size_t)ch * 8192 + r2) * 32 + cr2;
        *reinterpret_cast<ushort4*>(eh2 + off) = make_ushort4(hv[0], hv[1], hv[2], hv[3]);
        *reinterpret_cast<ushort4*>(el2 + off) = make_ushort4(lv[0], lv[1], lv[2], lv[3]);
    }
}

// ---------------------------------------------------------------- MFMA screen, coalesced staging, top-3 epilogue
// grid 512 = 128 px-tiles(64) x 4 k-splits(2048). Per (px,split): 3 smallest vhat keys (sorted).
__global__ __launch_bounds__(256, 2) void k_mfma(const float* __restrict__ A,
                                                 const float* __restrict__ Nf,
                                                 const unsigned short* __restrict__ zh_g,
                                                 const unsigned short* __restrict__ zl_g,
                                                 const unsigned short* __restrict__ eh_g,
                                                 const unsigned short* __restrict__ el_g,
                                                 u64t* __restrict__ bq) {
    __shared__ __align__(16) char smem[59392];
    short (*zh)[72]  = reinterpret_cast<short(*)[72]>(smem);            // [64 px][64c+8]
    short (*zl)[72]  = reinterpret_cast<short(*)[72]>(smem + 9216);
    short (*ehi)[40] = reinterpret_cast<short(*)[40]>(smem + 18432);    // [256 k][32c+8]
    short (*elo)[40] = reinterpret_cast<short(*)[40]>(smem + 38912);

    const int t = threadIdx.x;
    const int ks = blockIdx.x & 3, pt = blockIdx.x >> 2;
    const int pix0 = pt * 64, k0 = ks * 2048;
    const int w = t >> 6, l = t & 63;
    const int lg = l >> 4, lr = l & 15;

    float a_reg[4][4];
#pragma unroll
    for (int ti = 0; ti < 4; ++ti)
#pragma unroll
        for (int r = 0; r < 4; ++r)
            a_reg[ti][r] = A[pix0 + ti * 16 + lg * 4 + r];

    u64t b1[4][4], b2[4][4], b3[4][4];
#pragma unroll
    for (int ti = 0; ti < 4; ++ti)
#pragma unroll
        for (int r = 0; r < 4; ++r) { b1[ti][r] = ~0ULL; b2[ti][r] = ~0ULL; b3[ti][r] = ~0ULL; }

    for (int ksub = 0; ksub < 8; ++ksub) {
        f32x4 acc[4][4];
#pragma unroll
        for (int ti = 0; ti < 4; ++ti)
#pragma unroll
            for (int tj = 0; tj < 4; ++tj) acc[ti][tj] = (f32x4)(0.0f);

        for (int cq = 0; cq < 4; ++cq) {
            {   // z-quarter stage: contiguous 8 KB (thread t -> 32 B at t*32)
                const bf16x8* sh = reinterpret_cast<const bf16x8*>(
                    zh_g + ((size_t)cq * 8192 + pix0) * 64) + t * 2;
                const bf16x8* sl = reinterpret_cast<const bf16x8*>(
                    zl_g + ((size_t)cq * 8192 + pix0) * 64) + t * 2;
                const bf16x8 h0 = sh[0], h1 = sh[1], l0 = sl[0], l1 = sl[1];
                const int row = t >> 2, c0 = (t & 3) * 16;
                __syncthreads();
                *reinterpret_cast<bf16x8*>(&zh[row][c0])     = h0;
                *reinterpret_cast<bf16x8*>(&zh[row][c0 + 8]) = h1;
                *reinterpret_cast<bf16x8*>(&zl[row][c0])     = l0;
                *reinterpret_cast<bf16x8*>(&zl[row][c0 + 8]) = l1;
                __syncthreads();
            }
            for (int cc = 0; cc < 2; ++cc) {
                {   // e-chunk stage: contiguous 16 KB (thread t -> 64 B at t*64)
                    const int ch = cq * 2 + cc;
                    const bf16x8* sh = reinterpret_cast<const bf16x8*>(
                        eh_g + ((size_t)ch * 8192 + k0 + ksub * 256) * 32) + t * 4;
                    const bf16x8* sl = reinterpret_cast<const bf16x8*>(
                        el_g + ((size_t)ch * 8192 + k0 + ksub * 256) * 32) + t * 4;
                    const bf16x8 h0 = sh[0], h1 = sh[1], h2 = sh[2], h3 = sh[3];
                    const bf16x8 l0 = sl[0], l1 = sl[1], l2 = sl[2], l3 = sl[3];
                    __syncthreads();
                    *reinterpret_cast<bf16x8*>(&ehi[t][0])  = h0;
                    *reinterpret_cast<bf16x8*>(&ehi[t][8])  = h1;
                    *reinterpret_cast<bf16x8*>(&ehi[t][16]) = h2;
                    *reinterpret_cast<bf16x8*>(&ehi[t][24]) = h3;
                    *reinterpret_cast<bf16x8*>(&elo[t][0])  = l0;
                    *reinterpret_cast<bf16x8*>(&elo[t][8])  = l1;
                    *reinterpret_cast<bf16x8*>(&elo[t][16]) = l2;
                    *reinterpret_cast<bf16x8*>(&elo[t][24]) = l3;
                    __syncthreads();
                }
                bf16x8 ahz[4], alz[4];
                const int acol = cc * 32 + lg * 8;
#pragma unroll
                for (int ti = 0; ti < 4; ++ti) {
                    ahz[ti] = *reinterpret_cast<const bf16x8*>(&zh[ti * 16 + lr][acol]);
                    alz[ti] = *reinterpret_cast<const bf16x8*>(&zl[ti * 16 + lr][acol]);
                }
#pragma unroll
                for (int tj = 0; tj < 4; ++tj) {
                    const bf16x8 bhe = *reinterpret_cast<const bf16x8*>(&ehi[w * 64 + tj * 16 + lr][lg * 8]);
                    const bf16x8 ble = *reinterpret_cast<const bf16x8*>(&elo[w * 64 + tj * 16 + lr][lg * 8]);
#pragma unroll
                    for (int ti = 0; ti < 4; ++ti) {
                        acc[ti][tj] = __builtin_amdgcn_mfma_f32_16x16x32_bf16(ahz[ti], bhe, acc[ti][tj], 0, 0, 0);
                        acc[ti][tj] = __builtin_amdgcn_mfma_f32_16x16x32_bf16(ahz[ti], ble, acc[ti][tj], 0, 0, 0);
                        acc[ti][tj] = __builtin_amdgcn_mfma_f32_16x16x32_bf16(alz[ti], bhe, acc[ti][tj], 0, 0, 0);
                    }
                }
            }
        }
        // epilogue: vhat = fl(fl(A - M~) + N), track sorted top-3 per element
#pragma unroll
        for (int tj = 0; tj < 4; ++tj) {
            const int kk = k0 + ksub * 256 + w * 64 + tj * 16 + lr;
            const float nk = Nf[kk];
#pragma unroll
            for (int ti = 0; ti < 4; ++ti) {
#pragma unroll
                for (int r = 0; r < 4; ++r) {
                    const float vv = __fadd_rn(__fsub_rn(a_reg[ti][r], acc[ti][tj][r]), nk);
                    const u64t key = ((u64t)__float_as_uint(vv) << 32) | (unsigned)kk;
                    if (key < b3[ti][r]) {
                        if (key < b1[ti][r])      { b3[ti][r] = b2[ti][r]; b2[ti][r] = b1[ti][r]; b1[ti][r] = key; }
                        else if (key < b2[ti][r]) { b3[ti][r] = b2[ti][r]; b2[ti][r] = key; }
                        else                      { b3[ti][r] = key; }
                    }
                }
            }
        }
    }
    // butterfly top-3 merge within each 16-lane group
#pragma unroll
    for (int ti = 0; ti < 4; ++ti)
#pragma unroll
        for (int r = 0; r < 4; ++r) {
            u64t a1 = b1[ti][r], a2 = b2[ti][r], a3 = b3[ti][r];
#pragma unroll
            for (int m = 1; m <= 8; m <<= 1) {
                const u64t o1 = __shfl_xor(a1, m, 64);
                const u64t o2 = __shfl_xor(a2, m, 64);
                const u64t o3 = __shfl_xor(a3, m, 64);
                merge3(a1, a2, a3, o1, o2, o3);
            }
            b1[ti][r] = a1; b2[ti][r] = a2; b3[ti][r] = a3;
        }
    __syncthreads();
    u64t (*mrg)[4][3] = reinterpret_cast<u64t(*)[4][3]>(smem + 18432);  // overlay on e-bufs
    if (lr == 0) {
#pragma unroll
        for (int ti = 0; ti < 4; ++ti)
#pragma unroll
            for (int r = 0; r < 4; ++r) {
                const int pxl = ti * 16 + lg * 4 + r;
                mrg[pxl][w][0] = b1[ti][r];
                mrg[pxl][w][1] = b2[ti][r];
                mrg[pxl][w][2] = b3[ti][r];
            }
    }
    __syncthreads();
    if (t < 64) {
        u64t B1 = ~0ULL, B2 = ~0ULL, B3 = ~0ULL;
#pragma unroll
        for (int w4 = 0; w4 < 4; ++w4)
            merge3(B1, B2, B3, mrg[t][w4][0], mrg[t][w4][1], mrg[t][w4][2]);
        bq[((size_t)(ks * 3 + 0)) * 8192 + pix0 + t] = B1;
        bq[((size_t)(ks * 3 + 1)) * 8192 + pix0 + t] = B2;
        bq[((size_t)(ks * 3 + 2)) * 8192 + pix0 + t] = B3;
    }
}

// ---------------------------------------------------------------- select: emit candidates + deep flags (b3-gated)
__global__ __launch_bounds__(256) void k_sel(const float* __restrict__ A,
                                             const u64t* __restrict__ bq,
                                             unsigned short* __restrict__ dlist,
                                             int* __restrict__ dcnt,
                                             int* __restrict__ ccnt,
                                             unsigned* __restrict__ cnd) {
    const int px = blockIdx.x * 256 + threadIdx.x;
    const int lane = threadIdx.x & 63;
    u64t k1[4], k2[4], k3[4];
#pragma unroll
    for (int s = 0; s < 4; ++s) {
        k1[s] = bq[((size_t)(s * 3 + 0)) * 8192 + px];
        k2[s] = bq[((size_t)(s * 3 + 1)) * 8192 + px];
        k3[s] = bq[((size_t)(s * 3 + 2)) * 8192 + px];
    }
    float m = __uint_as_float((unsigned)(k1[0] >> 32));
#pragma unroll
    for (int s = 1; s < 4; ++s) m = fminf(m, __uint_as_float((unsigned)(k1[s] >> 32)));
    const float a = A[px];
    const unsigned eb = (__float_as_uint(a + 0.125f) >> 23) & 255u;
    const float up = __uint_as_float((eb - 23u) << 23);
    const float thresh = m + 4.5f * up + 1.0e-5f;

    unsigned cand[12];
    int nc = 0;
#pragma unroll
    for (int s = 0; s < 4; ++s) {
        if (__uint_as_float((unsigned)(k1[s] >> 32)) <= thresh)
            cand[nc++] = ((unsigned)px << 16) | (unsigned)(k1[s] & 0xffffu);
        if (__uint_as_float((unsigned)(k2[s] >> 32)) <= thresh)
            cand[nc++] = ((unsigned)px << 16) | (unsigned)(k2[s] & 0xffffu);
        if (__uint_as_float((unsigned)(k3[s] >> 32)) <= thresh) {
            cand[nc++] = ((unsigned)px << 16) | (unsigned)(k3[s] & 0xffffu);
            const int pos = atomicAdd(&dcnt[s], 1);          // possibly >3 in window -> deep
            if (pos < 8192) dlist[s * 8192 + pos] = (unsigned short)px;
        }
    }
    // wave-aggregated append (1 global atomic per wave)
    int sc = nc;
#pragma unroll
    for (int o = 1; o < 64; o <<= 1) {
        const int n = __shfl_up(sc, o, 64);
        if (lane >= o) sc += n;
    }
    int base = 0;
    if (lane == 63) base = atomicAdd(ccnt, sc);
    base = __shfl(base, 63, 64);
    const int off = base + sc - nc;
    for (int j = 0; j < nc; ++j)
        if (off + j < CAND_CAP) cnd[off + j] = cand[j];
}

// ---------------------------------------------------------------- candidate np-exact rescore (sequential fmaf chain)
__global__ __launch_bounds__(256) void k_cand(const float* __restrict__ ze,
                                              const float* __restrict__ embed,
                                              const float* __restrict__ A,
                                              const float* __restrict__ Nf,
                                              const int* __restrict__ ccnt,
                                              const unsigned* __restrict__ cnd,
                                              u64t* __restrict__ amin) {
    int cnt = *ccnt; if (cnt > CAND_CAP) cnt = CAND_CAP;
    for (int i = blockIdx.x * 256 + threadIdx.x; i < cnt; i += 32768) {
        const unsigned pk = cnd[i];
        const int px = pk >> 16, k = pk & 0xffffu;
        const float4* zr = reinterpret_cast<const float4*>(ze + (size_t)px * 256);
        const float4* er = reinterpret_cast<const float4*>(embed + (size_t)k * 256);
        float acc = 0.0f;
        for (int c4 = 0; c4 < 64; ++c4) {
            const float4 z4 = zr[c4], e4 = er[c4];
            acc = fmaf(__fmul_rn(2.0f, z4.x), e4.x, acc);
            acc = fmaf(__fmul_rn(2.0f, z4.y), e4.y, acc);
            acc = fmaf(__fmul_rn(2.0f, z4.z), e4.z, acc);
            acc = fmaf(__fmul_rn(2.0f, z4.w), e4.w, acc);
        }
        const float v = __fadd_rn(__fsub_rn(A[px], acc), Nf[k]);
        atomicMin(&amin[px], ((u64t)__float_as_uint(v) << 32) | (unsigned)k);
    }
}

// ---------------------------------------------------------------- deep: exact np rescore of a whole 2048-k split (r12/13-proven)
__global__ __launch_bounds__(256) void k_deep(const float* __restrict__ ze,
                                              const float* __restrict__ embed,
                                              const float* __restrict__ A,
                                              const float* __restrict__ Nf,
                                              const unsigned short* __restrict__ dlist,
                                              const int* __restrict__ dcnt,
                                              u64t* __restrict__ amin) {
    const int s = blockIdx.x >> 10;
    const int bkt = blockIdx.x & 1023;
    int n = dcnt[s]; if (n > 8192) n = 8192;
    const int i0 = bkt * 8;
    if (i0 >= n) return;
    __shared__ int spx[8];
    __shared__ float sA[8];
    __shared__ __align__(16) float lz2[8][264];
    __shared__ __align__(16) float echA[128][36];
    __shared__ __align__(16) float echB[128][36];
    __shared__ u64t redm[8][128];
    const int t = threadIdx.x;
    if (t < 8) {
        const int v = (i0 + t < n) ? (int)dlist[s * 8192 + i0 + t] : -1;
        spx[t] = v;
        sA[t] = (v >= 0) ? A[v] : 0.0f;
    }
    __syncthreads();
    {
        const int row = t >> 5, c0 = (t & 31) * 8;
        float4 v0 = make_float4(0.f, 0.f, 0.f, 0.f), v1 = v0;
        const int px = spx[row];
        if (px >= 0) {
            const float4* zr = reinterpret_cast<const float4*>(ze + (size_t)px * 256 + c0);
            v0 = zr[0]; v1 = zr[1];
        }
        lz2[row][c0 + 0] = __fmul_rn(2.0f, v0.x);
        lz2[row][c0 + 1] = __fmul_rn(2.0f, v0.y);
        lz2[row][c0 + 2] = __fmul_rn(2.0f, v0.z);
        lz2[row][c0 + 3] = __fmul_rn(2.0f, v0.w);
        lz2[row][c0 + 4] = __fmul_rn(2.0f, v1.x);
        lz2[row][c0 + 5] = __fmul_rn(2.0f, v1.y);
        lz2[row][c0 + 6] = __fmul_rn(2.0f, v1.z);
        lz2[row][c0 + 7] = __fmul_rn(2.0f, v1.w);
    }
    __syncthreads();
    const int pxg = t >> 7, kg = t & 127;
    u64t pbest[4];
#pragma unroll
    for (int p = 0; p < 4; ++p) pbest[p] = ~0ULL;
    for (int kc = 0; kc < 8; ++kc) {
        float acc[4][2];
#pragma unroll
        for (int p = 0; p < 4; ++p) { acc[p][0] = 0.0f; acc[p][1] = 0.0f; }
        for (int cc = 0; cc < 8; ++cc) {
            const float4* esrc = reinterpret_cast<const float4*>(
                embed + (size_t)(s * 2048 + kc * 256 + t) * 256 + cc * 32);
            float4 ev[8];
#pragma unroll
            for (int m = 0; m < 8; ++m) ev[m] = esrc[m];
            __syncthreads();
            {
                float* dst = (t & 1) ? &echB[t >> 1][0] : &echA[t >> 1][0];
#pragma unroll
                for (int m = 0; m < 8; ++m) {
                    dst[m * 4 + 0] = ev[m].x; dst[m * 4 + 1] = ev[m].y;
                    dst[m * 4 + 2] = ev[m].z; dst[m * 4 + 3] = ev[m].w;
                }
            }
            __syncthreads();
#pragma unroll
            for (int c4 = 0; c4 < 8; ++c4) {
                const float4 e0 = *reinterpret_cast<const float4*>(&echA[kg][c4 * 4]);
                const float4 e1 = *reinterpret_cast<const float4*>(&echB[kg][c4 * 4]);
#pragma unroll
                for (int p = 0; p < 4; ++p) {
                    const float4 zq = *reinterpret_cast<const float4*>(&lz2[pxg * 4 + p][cc * 32 + c4 * 4]);
                    acc[p][0] = fmaf(zq.x, e0.x, acc[p][0]);
                    acc[p][0] = fmaf(zq.y, e0.y, acc[p][0]);
                    acc[p][0] = fmaf(zq.z, e0.z, acc[p][0]);
                    acc[p][0] = fmaf(zq.w, e0.w, acc[p][0]);
                    acc[p][1] = fmaf(zq.x, e1.x, acc[p][1]);
                    acc[p][1] = fmaf(zq.y, e1.y, acc[p][1]);
                    acc[p][1] = fmaf(zq.z, e1.z, acc[p][1]);
                    acc[p][1] = fmaf(zq.w, e1.w, acc[p][1]);
                }
            }
        }
#pragma unroll
        for (int p = 0; p < 4; ++p) {
#pragma unroll
            for (int j = 0; j < 2; ++j) {
                const int k = s * 2048 + kc * 256 + kg * 2 + j;
                const float v = __fadd_rn(__fsub_rn(sA[pxg * 4 + p], acc[p][j]), Nf[k]);
                const u64t key = ((u64t)__float_as_uint(v) << 32) | (unsigned)k;
                pbest[p] = (key < pbest[p]) ? key : pbest[p];
            }
        }
    }
#pragma unroll
    for (int p = 0; p < 4; ++p) redm[pxg * 4 + p][kg] = pbest[p];
    __syncthreads();
    if (t < 8) {
        u64t bv = ~0ULL;
        for (int q = 0; q < 128; ++q) {
            const u64t v = redm[t][q];
            bv = (v < bv) ? v : bv;
        }
        if (spx[t] >= 0) atomicMin(&amin[spx[t]], bv);
    }
}

// ---------------------------------------------------------------- fallback (ws too small): r10 VALU distance kernel
__global__ __launch_bounds__(256, 2) void k_dist_r10(const float* __restrict__ ze,
                                                     const float* __restrict__ embed,
                                                     const float* __restrict__ A,
                                                     const float* __restrict__ Nf,
                                                     u64t* __restrict__ amin) {
    __shared__ __align__(16) char smem[49152];
    float (*le)[128] = reinterpret_cast<float (*)[128]>(smem);
    float (*z2)[256] = reinterpret_cast<float (*)[256]>(smem + 16384);
    u64t* red = reinterpret_cast<u64t*>(smem);

    const int t    = threadIdx.x;
    const int ks   = blockIdx.x & 31;
    const int pt   = blockIdx.x >> 5;
    const int pix0 = pt * 256;
    const int k0   = ks * 256;
    const int tp   = t & 15, tk = t >> 4;
    const int er   = t >> 1, eh2 = (t & 1) * 16;

    float best[16];
    int   bidx[16];
#pragma unroll
    for (int i = 0; i < 16; ++i) { best[i] = 3.402823466e+38f; bidx[i] = 0x7fffffff; }

    float Ai[16];
#pragma unroll
    for (int q = 0; q < 4; ++q)
#pragma unroll
        for (int m = 0; m < 4; ++m)
            Ai[q * 4 + m] = A[pix0 + (q * 16 + tp) * 4 + m];

    for (int kc = 0; kc < 256; kc += 128) {
        float acc[16][8];
#pragma unroll
        for (int i = 0; i < 16; ++i)
#pragma unroll
            for (int j = 0; j < 8; ++j) acc[i][j] = 0.0f;
        const int kbase = k0 + kc + tk * 8;
        for (int cc = 0; cc < 256; cc += 32) {
            float4 se[4], sz[8];
            const float4* esrc = reinterpret_cast<const float4*>(
                embed + (size_t)(k0 + kc + er) * 256 + cc + eh2);
#pragma unroll
            for (int m = 0; m < 4; ++m) se[m] = esrc[m];
            const float4* zsrc = reinterpret_cast<const float4*>(
                ze + (size_t)(pix0 + t) * 256 + cc);
#pragma unroll
            for (int m = 0; m < 8; ++m) sz[m] = zsrc[m];
            __syncthreads();
#pragma unroll
            for (int m = 0; m < 4; ++m) {
                le[eh2 + m * 4 + 0][er] = se[m].x;
                le[eh2 + m * 4 + 1][er] = se[m].y;
                le[eh2 + m * 4 + 2][er] = se[m].z;
                le[eh2 + m * 4 + 3][er] = se[m].w;
            }
#pragma unroll
            for (int m = 0; m < 8; ++m) {
                z2[m * 4 + 0][t] = __fmul_rn(2.0f, sz[m].x);
                z2[m * 4 + 1][t] = __fmul_rn(2.0f, sz[m].y);
                z2[m * 4 + 2][t] = __fmul_rn(2.0f, sz[m].z);
                z2[m * 4 + 3][t] = __fmul_rn(2.0f, sz[m].w);
            }
            __syncthreads();
#pragma unroll 2
            for (int c = 0; c < 32; ++c) {
                const float4 e0 = *reinterpret_cast<const float4*>(&le[c][tk * 8]);
                const float4 e1 = *reinterpret_cast<const float4*>(&le[c][tk * 8 + 4]);
                float4 zq[4];
#pragma unroll
                for (int q = 0; q < 4; ++q)
                    zq[q] = *reinterpret_cast<const float4*>(&z2[c][(q * 16 + tp) * 4]);
#define FMA8(i, zv)                                          \
    acc[i][0] = fmaf(zv, e0.x, acc[i][0]);                   \
    acc[i][1] = fmaf(zv, e0.y, acc[i][1]);                   \
    acc[i][2] = fmaf(zv, e0.z, acc[i][2]);                   \
    acc[i][3] = fmaf(zv, e0.w, acc[i][3]);                   \
    acc[i][4] = fmaf(zv, e1.x, acc[i][4]);                   \
    acc[i][5] = fmaf(zv, e1.y, acc[i][5]);                   \
    acc[i][6] = fmaf(zv, e1.z, acc[i][6]);                   \
    acc[i][7] = fmaf(zv, e1.w, acc[i][7]);
#pragma unroll
                for (int q = 0; q < 4; ++q) {
                    FMA8(q * 4 + 0, zq[q].x)
                    FMA8(q * 4 + 1, zq[q].y)
                    FMA8(q * 4 + 2, zq[q].z)
                    FMA8(q * 4 + 3, zq[q].w)
                }
#undef FMA8
            }
        }
        const float4 n0 = *reinterpret_cast<const float4*>(&Nf[kbase]);
        const float4 n1 = *reinterpret_cast<const float4*>(&Nf[kbase + 4]);
        const float nk[8] = {n0.x, n0.y, n0.z, n0.w, n1.x, n1.y, n1.z, n1.w};
#pragma unroll
        for (int j = 0; j < 8; ++j) {
            const int k = kbase + j;
#pragma unroll
            for (int i = 0; i < 16; ++i) {
                const float v = __fadd_rn(__fsub_rn(Ai[i], acc[i][j]), nk[j]);
                if (v < best[i]) { best[i] = v; bidx[i] = k; }
            }
        }
    }
    __syncthreads();
#pragma unroll
    for (int i = 0; i < 16; ++i) {
        const int px = ((i >> 2) * 16 + tp) * 4 + (i & 3);
        const unsigned u = __float_as_uint(best[i]);
        red[px * 17 + tk] = ((u64t)u << 32) | (unsigned)bidx[i];
    }
    __syncthreads();
    {
        u64t bv = ~0ULL;
#pragma unroll 4
        for (int q2 = 0; q2 < 16; ++q2) {
            const u64t v = red[t * 17 + q2];
            bv = (v < bv) ? v : bv;
        }
        atomicMin(&amin[pix0 + t], bv);
    }
}

// ---------------------------------------------------------------- unpack argmin
__global__ __launch_bounds__(256) void k_combine(const u64t* __restrict__ amin,
                                                 float* __restrict__ out_ind) {
    const int nn = blockIdx.x * 256 + threadIdx.x;
    out_ind[nn] = (float)(unsigned)(amin[nn] & 0xffffffffULL);
}

// ---------------------------------------------------------------- gather z_q (overwrite z_e) + partial MSE (f64)
__global__ __launch_bounds__(256) void k_gather(const float* __restrict__ embed,
                                                float* __restrict__ out,
                                                const float* __restrict__ out_ind,
                                                float* __restrict__ part) {
    __shared__ double wsum[4];
    const int t = threadIdx.x;
    const int g = t >> 5, ll = t & 31;
    const int nn = blockIdx.x * 8 + g;
    const int idx = (int)(out_ind[nn] + 0.5f);
    const float4* ev4 = reinterpret_cast<const float4*>(embed + (size_t)idx * 256);
    float4* zp = reinterpret_cast<float4*>(out + (size_t)nn * 256);
    double sm = 0.0;
#pragma unroll
    for (int r = 0; r < 2; ++r) {
        const float4 ev = ev4[ll + r * 32];
        const float4 zv = zp[ll + r * 32];
        const double dx = (double)ev.x - zv.x, dy = (double)ev.y - zv.y;
        const double dz = (double)ev.z - zv.z, dw = (double)ev.w - zv.w;
        sm += dx * dx + dy * dy + dz * dz + dw * dw;
        zp[ll + r * 32] = ev;
    }
    for (int off = 32; off; off >>= 1) sm += __shfl_down(sm, off, 64);
    const int wid = t >> 6, lane = t & 63;
    if (lane == 0) wsum[wid] = sm;
    __syncthreads();
    if (t == 0) part[blockIdx.x] = (float)(wsum[0] + wsum[1] + wsum[2] + wsum[3]);
}

// ---------------------------------------------------------------- final diff reduction (f64)
__global__ __launch_bounds__(256) void k_final(const float* __restrict__ part,
                                               float* __restrict__ out_diff) {
    __shared__ double wsum[4];
    double sm = 0.0;
#pragma unroll
    for (int i = 0; i < 4; ++i) sm += (double)part[threadIdx.x + i * 256];
    for (int off = 32; off; off >>= 1) sm += __shfl_down(sm, off, 64);
    const int wid = threadIdx.x >> 6, lane = threadIdx.x & 63;
    if (lane == 0) wsum[wid] = sm;
    __syncthreads();
    if (threadIdx.x == 0)
        out_diff[0] = (float)(2.0 * (wsum[0] + wsum[1] + wsum[2] + wsum[3]) / 2097152.0);
}

extern "C" void kernel_launch(void* const* d_in, const int* in_sizes, int n_in,
                              void* d_out, int out_size, void* d_ws, size_t ws_size,
                              hipStream_t stream) {
    const float* z     = (const float*)d_in[0];
    const float* pw    = (const float*)d_in[1];
    const float* pb    = (const float*)d_in[2];
    const float* embed = (const float*)d_in[3];
    float* out = (float*)d_out;
    char*  ws  = (char*)d_ws;

    u64t*           amin  = (u64t*)(ws + WS_AMIN);
    float*          A     = (float*)(ws + WS_A);
    float*          Nf    = (float*)(ws + WS_N);
    unsigned*       e2    = (unsigned*)(ws + WS_EMAX);
    unsigned short* dlist = (unsigned short*)(ws + WS_DLIST);
    int*            dcnt  = (int*)(ws + WS_DCNT);
    float*          part  = (float*)(ws + WS_PART);

    float* ze       = out + OUT_ZQ;      // z_e lives in z_q slot, overwritten by gather
    float* out_diff = out + OUT_DIFF;
    float* out_ind  = out + OUT_IND;

    const bool big = (ws_size >= WS_BIG_END);

    k_init    <<<32,   256, 0, stream>>>(amin, dcnt, e2);
    k_ze_np   <<<512,  256, 0, stream>>>(z, pw, pb, ze);
    k_rowstats<<<64,   256, 0, stream>>>(ze, embed, A, Nf, e2);
    if (big) {
        u64t*           bq   = (u64t*)(ws + WS_BQ);
        int*            ccnt = (int*)(ws + WS_CCNT);
        unsigned*       cnd  = (unsigned*)(ws + WS_CND);
        unsigned short* zh2  = (unsigned short*)(ws + WS_ZH2);
        unsigned short* zl2  = (unsigned short*)(ws + WS_ZL2);
        unsigned short* eh2  = (unsigned short*)(ws + WS_EH2);
        unsigned short* el2  = (unsigned short*)(ws + WS_EL2);
        k_cvt  <<<4096, 256, 0, stream>>>(ze, embed, zh2, zl2, eh2, el2, ccnt);
        k_mfma <<<512,  256, 0, stream>>>(A, Nf, zh2, zl2, eh2, el2, bq);
        k_sel  <<<32,   256, 0, stream>>>(A, bq, dlist, dcnt, ccnt, cnd);
        k_cand <<<128,  256, 0, stream>>>(ze, embed, A, Nf, ccnt, cnd, amin);
        k_deep <<<4096, 256, 0, stream>>>(ze, embed, A, Nf, dlist, dcnt, amin);
    } else {
        k_dist_r10<<<1024, 256, 0, stream>>>(ze, embed, A, Nf, amin);
    }
    k_combine <<<32,   256, 0, stream>>>(amin, out_ind);
    k_gather  <<<1024, 256, 0, stream>>>(embed, out + OUT_ZQ, out_ind, part);
    k_final   <<<1,    256, 0, stream>>>(part, out_diff);
}

// Round 15
// 398.137 us; speedup vs baseline: 2.1265x; 1.0687x over previous
//
#include <hip/hip_runtime.h>

#define OUT_ZQ   0
#define OUT_DIFF 2097152
#define OUT_IND  2097153

// ws layout (bytes) — big path total 18,087,936 <= proven 18,489,600
#define WS_AMIN   0        // u64[8192]
#define WS_A      65536    // f32[8192]
#define WS_N      98304    // f32[8192]
#define WS_EMAX   131072   // u32
#define WS_DLIST  131136   // u16[4][8192] = 64 KB
#define WS_DCNT   196672   // i32[4]
#define WS_PART   196688   // f32[1024]
#define WS_CCNT   200784   // i32 (+pad)
#define WS_CND    200848   // u32[98304]
#define WS_BQ     594064   // u64[4][2][8192] = 512 KB  (top-2 keys per split)
#define WS_B3V    1118352  // f32[4][8192]              (3rd-best VALUE per split)
#define WS_ZH3    1310720  // u16[2M] = 4 MB  fragment-major hi(2*z_e)
#define WS_ZL3    5505024  // lo(2*z_e)
#define WS_EH3    9699328  // hi(embed)
#define WS_EL3    13893632 // lo(embed)
#define WS_BIG_END 18087936ULL
#define CAND_CAP  98304

typedef unsigned long long u64t;
typedef __attribute__((ext_vector_type(8))) short bf16x8;
typedef __attribute__((ext_vector_type(4))) float f32x4;

__device__ inline unsigned short bf16rn(float f) {
    unsigned u = __float_as_uint(f);
    return (unsigned short)((u + 0x7fffu + ((u >> 16) & 1u)) >> 16);
}
__device__ inline float bf16tof(unsigned short h) { return __uint_as_float(((unsigned)h) << 16); }
__device__ inline float valf(u64t k) { return __uint_as_float((unsigned)(k >> 32)); }

#define INITKEY ((((u64t)0x7F7FFFFFu) << 32) | 0xFFFFu)   // value = FLT_MAX (no NaN)

// ---------------------------------------------------------------- init
__global__ __launch_bounds__(256) void k_init(u64t* __restrict__ amin,
                                              int* __restrict__ dcnt,
                                              unsigned* __restrict__ e2) {
    const int i = blockIdx.x * 256 + threadIdx.x;
    amin[i] = ~0ULL;
    if (i < 4) dcnt[i] = 0;
    if (i == 4) *e2 = 0u;
}

// ---------------------------------------------------------------- z_e: bit-exact np.einsum replica (v2: weights in regs, b128 broadcast lz)
__global__ __launch_bounds__(256) void k_ze_np(const float* __restrict__ z,
                                               const float* __restrict__ pw,
                                               const float* __restrict__ pb,
                                               float* __restrict__ ze) {
    __shared__ float lz[32][16];
    const int t   = threadIdx.x;
    const int b   = blockIdx.x >> 6;
    const int hw0 = (blockIdx.x & 63) * 16;

    float acc[16];
#pragma unroll
    for (int p = 0; p < 16; ++p) acc[p] = 0.0f;

    for (int cc = 0; cc < 256; cc += 32) {
        float4 wv[8];
        const float4* wsrc = reinterpret_cast<const float4*>(pw + (size_t)t * 256 + cc);
#pragma unroll
        for (int i = 0; i < 8; ++i) wv[i] = wsrc[i];
        float zv[2];
#pragma unroll
        for (int i = 0; i < 2; ++i) {
            const int f = t + i * 256;
            zv[i] = z[(size_t)(b * 256 + cc + (f >> 4)) * 1024 + hw0 + (f & 15)];
        }
        __syncthreads();
#pragma unroll
        for (int i = 0; i < 2; ++i) {
            const int f = t + i * 256;
            lz[f >> 4][f & 15] = zv[i];
        }
        __syncthreads();
#define ZSTEP(CL, WL) {                                                     \
    const float4 q0 = *reinterpret_cast<const float4*>(&lz[CL][0]);         \
    const float4 q1 = *reinterpret_cast<const float4*>(&lz[CL][4]);         \
    const float4 q2 = *reinterpret_cast<const float4*>(&lz[CL][8]);         \
    const float4 q3 = *reinterpret_cast<const float4*>(&lz[CL][12]);        \
    acc[0]  = __fadd_rn(acc[0],  __fmul_rn(q0.x, WL));                      \
    acc[1]  = __fadd_rn(acc[1],  __fmul_rn(q0.y, WL));                      \
    acc[2]  = __fadd_rn(acc[2],  __fmul_rn(q0.z, WL));                      \
    acc[3]  = __fadd_rn(acc[3],  __fmul_rn(q0.w, WL));                      \
    acc[4]  = __fadd_rn(acc[4],  __fmul_rn(q1.x, WL));                      \
    acc[5]  = __fadd_rn(acc[5],  __fmul_rn(q1.y, WL));                      \
    acc[6]  = __fadd_rn(acc[6],  __fmul_rn(q1.z, WL));                      \
    acc[7]  = __fadd_rn(acc[7],  __fmul_rn(q1.w, WL));                      \
    acc[8]  = __fadd_rn(acc[8],  __fmul_rn(q2.x, WL));                      \
    acc[9]  = __fadd_rn(acc[9],  __fmul_rn(q2.y, WL));                      \
    acc[10] = __fadd_rn(acc[10], __fmul_rn(q2.z, WL));                      \
    acc[11] = __fadd_rn(acc[11], __fmul_rn(q2.w, WL));                      \
    acc[12] = __fadd_rn(acc[12], __fmul_rn(q3.x, WL));                      \
    acc[13] = __fadd_rn(acc[13], __fmul_rn(q3.y, WL));                      \
    acc[14] = __fadd_rn(acc[14], __fmul_rn(q3.z, WL));                      \
    acc[15] = __fadd_rn(acc[15], __fmul_rn(q3.w, WL)); }
#pragma unroll
        for (int c8 = 0; c8 < 8; ++c8) {
            const float4 wq = wv[c8];
            ZSTEP(c8 * 4 + 0, wq.x)
            ZSTEP(c8 * 4 + 1, wq.y)
            ZSTEP(c8 * 4 + 2, wq.z)
            ZSTEP(c8 * 4 + 3, wq.w)
        }
#undef ZSTEP
    }
    const float bb = pb[t];
#pragma unroll
    for (int p = 0; p < 16; ++p)
        ze[(size_t)(b * 1024 + hw0 + p) * 256 + t] = __fadd_rn(acc[p], bb);
}

// ---------------------------------------------------------------- np pairwise row-norms
__global__ __launch_bounds__(256) void k_rowstats(const float* __restrict__ ze,
                                                  const float* __restrict__ embed,
                                                  float* __restrict__ A,
                                                  float* __restrict__ Nf,
                                                  unsigned* __restrict__ e2) {
    const int gid = blockIdx.x * 256 + threadIdx.x;
    const float* row = (gid < 8192) ? (ze + (size_t)gid * 256)
                                    : (embed + (size_t)(gid - 8192) * 256);
    float blk[2];
#pragma unroll
    for (int half = 0; half < 2; ++half) {
        const float4* r4 = reinterpret_cast<const float4*>(row + half * 128);
        float r[8];
#pragma unroll
        for (int i = 0; i < 16; ++i) {
            const float4 a = r4[i * 2], b = r4[i * 2 + 1];
            const float s[8] = {__fmul_rn(a.x, a.x), __fmul_rn(a.y, a.y),
                                __fmul_rn(a.z, a.z), __fmul_rn(a.w, a.w),
                                __fmul_rn(b.x, b.x), __fmul_rn(b.y, b.y),
                                __fmul_rn(b.z, b.z), __fmul_rn(b.w, b.w)};
            if (i == 0) {
#pragma unroll
                for (int j = 0; j < 8; ++j) r[j] = s[j];
            } else {
#pragma unroll
                for (int j = 0; j < 8; ++j) r[j] = __fadd_rn(r[j], s[j]);
            }
        }
        blk[half] = __fadd_rn(__fadd_rn(__fadd_rn(r[0], r[1]), __fadd_rn(r[2], r[3])),
                              __fadd_rn(__fadd_rn(r[4], r[5]), __fadd_rn(r[6], r[7])));
    }
    const float res = __fadd_rn(blk[0], blk[1]);
    if (gid < 8192) A[gid] = res;
    else {
        Nf[gid - 8192] = res;
        float mx = res;
        for (int off = 32; off; off >>= 1) mx = fmaxf(mx, __shfl_down(mx, off, 64));
        if ((threadIdx.x & 63) == 0) atomicMax(e2, __float_as_uint(mx));
    }
}

// ---------------------------------------------------------------- bf16 hi/lo precompute in FRAGMENT-MAJOR layout
// z elem (px,c): pt=px>>6 ti=(px>>4)&3 lr=px&15; ci=c>>5 lg=(c>>3)&3; lane=lg*16+lr
//   zh3 idx = ((ci*128+pt)*4+ti)*512 + lane*8 + (c&7)
// e elem (k,c):  ks=k>>11 ksub=(k>>8)&7 w=(k>>6)&3 tj=(k>>4)&3 lr=k&15
//   eh3 idx = (((ks*8+ksub)*8+ci)*16 + w*4 + tj)*512 + lane*8 + (c&7)
__global__ __launch_bounds__(256) void k_cvt(const float* __restrict__ ze,
                                             const float* __restrict__ embed,
                                             unsigned short* __restrict__ zh3,
                                             unsigned short* __restrict__ zl3,
                                             unsigned short* __restrict__ eh3,
                                             unsigned short* __restrict__ el3,
                                             int* __restrict__ ccnt) {
    const int gid = blockIdx.x * 256 + threadIdx.x;
    if (gid == 0) *ccnt = 0;
    const int row = gid >> 5;
    const int c0  = (gid & 31) * 8;
    const bool isz = (row < 8192);
    const float* src = (isz ? ze + (size_t)row * 256 : embed + (size_t)(row - 8192) * 256) + c0;
    const float4 v0 = reinterpret_cast<const float4*>(src)[0];
    const float4 v1 = reinterpret_cast<const float4*>(src)[1];
    float x[8] = {v0.x, v0.y, v0.z, v0.w, v1.x, v1.y, v1.z, v1.w};
    if (isz) {
#pragma unroll
        for (int i = 0; i < 8; ++i) x[i] = __fmul_rn(2.0f, x[i]);   // exact prescale
    }
    unsigned short hv[8], lv[8];
#pragma unroll
    for (int i = 0; i < 8; ++i) {
        hv[i] = bf16rn(x[i]);
        lv[i] = bf16rn(__fsub_rn(x[i], bf16tof(hv[i])));
    }
    const int ci = c0 >> 5, lg = (c0 >> 3) & 3;
    if (isz) {
        const int pt = row >> 6, ti = (row >> 4) & 3, lr = row & 15;
        const int lane = lg * 16 + lr;
        const size_t off = ((size_t)(ci * 128 + pt) * 4 + ti) * 512 + (size_t)lane * 8;
        *reinterpret_cast<ushort4*>(zh3 + off)     = make_ushort4(hv[0], hv[1], hv[2], hv[3]);
        *reinterpret_cast<ushort4*>(zh3 + off + 4) = make_ushort4(hv[4], hv[5], hv[6], hv[7]);
        *reinterpret_cast<ushort4*>(zl3 + off)     = make_ushort4(lv[0], lv[1], lv[2], lv[3]);
        *reinterpret_cast<ushort4*>(zl3 + off + 4) = make_ushort4(lv[4], lv[5], lv[6], lv[7]);
    } else {
        const int k = row - 8192;
        const int ks = k >> 11, ksub = (k >> 8) & 7, w = (k >> 6) & 3, tj = (k >> 4) & 3, lr = k & 15;
        const int lane = lg * 16 + lr;
        const size_t off = (((size_t)((ks * 8 + ksub) * 8 + ci) * 16) + w * 4 + tj) * 512 + (size_t)lane * 8;
        *reinterpret_cast<ushort4*>(eh3 + off)     = make_ushort4(hv[0], hv[1], hv[2], hv[3]);
        *reinterpret_cast<ushort4*>(eh3 + off + 4) = make_ushort4(hv[4], hv[5], hv[6], hv[7]);
        *reinterpret_cast<ushort4*>(el3 + off)     = make_ushort4(lv[0], lv[1], lv[2], lv[3]);
        *reinterpret_cast<ushort4*>(el3 + off + 4) = make_ushort4(lv[4], lv[5], lv[6], lv[7]);
    }
}

// ---------------------------------------------------------------- MFMA screen v3: NO LDS, NO BARRIERS in main loop
// grid 512 = 128 px-tiles(64) x 4 k-splits(2048). Fragments loaded directly (coalesced b128, L2-resident).
// Per (px,split): top-2 packed keys + 3rd-best VALUE (index-free; deep covers the rest).
__global__ __launch_bounds__(256, 2) void k_mfma(const float* __restrict__ A,
                                                 const float* __restrict__ Nf,
                                                 const unsigned short* __restrict__ zh3,
                                                 const unsigned short* __restrict__ zl3,
                                                 const unsigned short* __restrict__ eh3,
                                                 const unsigned short* __restrict__ el3,
                                                 u64t* __restrict__ bq12,
                                                 float* __restrict__ b3v) {
    __shared__ u64t  mrgk[64][4][2];
    __shared__ float mrgv[64][4];
    const int t = threadIdx.x;
    const int ks = blockIdx.x & 3, pt = blockIdx.x >> 2;
    const int pix0 = pt * 64;
    const int w = t >> 6, l = t & 63;
    const int lg = l >> 4, lr = l & 15;

    float a_reg[4][4];
#pragma unroll
    for (int ti = 0; ti < 4; ++ti)
#pragma unroll
        for (int r = 0; r < 4; ++r)
            a_reg[ti][r] = A[pix0 + ti * 16 + lg * 4 + r];

    u64t b1[4][4], b2[4][4];
    float bv[4][4];
#pragma unroll
    for (int ti = 0; ti < 4; ++ti)
#pragma unroll
        for (int r = 0; r < 4; ++r) { b1[ti][r] = INITKEY; b2[ti][r] = INITKEY; bv[ti][r] = 3.402823466e+38f; }

    const size_t zoff0 = (size_t)pt * 2048 + (size_t)l * 8;
    for (int ksub = 0; ksub < 8; ++ksub) {
        f32x4 acc[4][4];
#pragma unroll
        for (int ti = 0; ti < 4; ++ti)
#pragma unroll
            for (int tj = 0; tj < 4; ++tj) acc[ti][tj] = (f32x4)(0.0f);

        const size_t ebase = (size_t)(ks * 8 + ksub) * 65536 + (size_t)w * 2048 + (size_t)l * 8;
#pragma unroll 2
        for (int ci = 0; ci < 8; ++ci) {
            const size_t zo = zoff0 + (size_t)ci * 262144;
            const size_t eo = ebase + (size_t)ci * 8192;
            bf16x8 az[4], alz[4], be[4], ble[4];
#pragma unroll
            for (int ti = 0; ti < 4; ++ti) {
                az[ti]  = *reinterpret_cast<const bf16x8*>(zh3 + zo + (size_t)ti * 512);
                alz[ti] = *reinterpret_cast<const bf16x8*>(zl3 + zo + (size_t)ti * 512);
            }
#pragma unroll
            for (int tj = 0; tj < 4; ++tj) {
                be[tj]  = *reinterpret_cast<const bf16x8*>(eh3 + eo + (size_t)tj * 512);
                ble[tj] = *reinterpret_cast<const bf16x8*>(el3 + eo + (size_t)tj * 512);
            }
#pragma unroll
            for (int tj = 0; tj < 4; ++tj)
#pragma unroll
                for (int ti = 0; ti < 4; ++ti) {
                    acc[ti][tj] = __builtin_amdgcn_mfma_f32_16x16x32_bf16(az[ti],  be[tj],  acc[ti][tj], 0, 0, 0);
                    acc[ti][tj] = __builtin_amdgcn_mfma_f32_16x16x32_bf16(az[ti],  ble[tj], acc[ti][tj], 0, 0, 0);
                    acc[ti][tj] = __builtin_amdgcn_mfma_f32_16x16x32_bf16(alz[ti], be[tj],  acc[ti][tj], 0, 0, 0);
                }
        }
        // epilogue: vhat = fl(fl(A - M~) + N); update (b1,b2 keys, bv value)
#pragma unroll
        for (int tj = 0; tj < 4; ++tj) {
            const int kk = ks * 2048 + ksub * 256 + w * 64 + tj * 16 + lr;
            const float nk = Nf[kk];
#pragma unroll
            for (int ti = 0; ti < 4; ++ti)
#pragma unroll
                for (int r = 0; r < 4; ++r) {
                    const float vv = __fadd_rn(__fsub_rn(a_reg[ti][r], acc[ti][tj][r]), nk);
                    const u64t key = ((u64t)__float_as_uint(vv) << 32) | (unsigned)kk;
                    if (key < b2[ti][r]) {
                        bv[ti][r] = valf(b2[ti][r]);
                        if (key < b1[ti][r]) { b2[ti][r] = b1[ti][r]; b1[ti][r] = key; }
                        else                 { b2[ti][r] = key; }
                    } else {
                        bv[ti][r] = fminf(bv[ti][r], vv);
                    }
                }
        }
    }
    // butterfly merge of (k1,k2,v3) within each 16-lane group
#pragma unroll
    for (int ti = 0; ti < 4; ++ti)
#pragma unroll
        for (int r = 0; r < 4; ++r) {
            u64t k1 = b1[ti][r], k2 = b2[ti][r];
            float v3 = bv[ti][r];
#pragma unroll
            for (int m = 1; m <= 8; m <<= 1) {
                const u64t o1 = __shfl_xor(k1, m, 64);
                const u64t o2 = __shfl_xor(k2, m, 64);
                const float ov = __shfl_xor(v3, m, 64);
                const u64t n1 = (k1 < o1) ? k1 : o1;
                const u64t X  = (k1 < o1) ? o1 : k1;
                const u64t Y  = (k2 < o2) ? k2 : o2;
                const u64t n2 = (X < Y) ? X : Y;
                const u64t t4 = (X < Y) ? Y : X;
                v3 = fminf(fminf(v3, ov), valf(t4));
                k1 = n1; k2 = n2;
            }
            b1[ti][r] = k1; b2[ti][r] = k2; bv[ti][r] = v3;
        }
    if (lr == 0) {
#pragma unroll
        for (int ti = 0; ti < 4; ++ti)
#pragma unroll
            for (int r = 0; r < 4; ++r) {
                const int pxl = ti * 16 + lg * 4 + r;
                mrgk[pxl][w][0] = b1[ti][r];
                mrgk[pxl][w][1] = b2[ti][r];
                mrgv[pxl][w]    = bv[ti][r];
            }
    }
    __syncthreads();
    if (t < 64) {
        u64t K1 = INITKEY, K2 = INITKEY;
        float V3 = 3.402823466e+38f;
#pragma unroll
        for (int w4 = 0; w4 < 4; ++w4) {
            const u64t o1 = mrgk[t][w4][0], o2 = mrgk[t][w4][1];
            const float ov = mrgv[t][w4];
            const u64t n1 = (K1 < o1) ? K1 : o1;
            const u64t X  = (K1 < o1) ? o1 : K1;
            const u64t Y  = (K2 < o2) ? K2 : o2;
            const u64t n2 = (X < Y) ? X : Y;
            const u64t t4 = (X < Y) ? Y : X;
            V3 = fminf(fminf(V3, ov), valf(t4));
            K1 = n1; K2 = n2;
        }
        bq12[((size_t)(ks * 2 + 0)) * 8192 + pix0 + t] = K1;
        bq12[((size_t)(ks * 2 + 1)) * 8192 + pix0 + t] = K2;
        b3v[(size_t)ks * 8192 + pix0 + t] = V3;
    }
}

// ---------------------------------------------------------------- select: candidates + deep flags (3rd-VALUE gated)
__global__ __launch_bounds__(256) void k_sel(const float* __restrict__ A,
                                             const u64t* __restrict__ bq12,
                                             const float* __restrict__ b3v,
                                             unsigned short* __restrict__ dlist,
                                             int* __restrict__ dcnt,
                                             int* __restrict__ ccnt,
                                             unsigned* __restrict__ cnd) {
    const int px = blockIdx.x * 256 + threadIdx.x;
    const int lane = threadIdx.x & 63;
    u64t k1[4], k2[4];
    float v3[4];
#pragma unroll
    for (int s = 0; s < 4; ++s) {
        k1[s] = bq12[((size_t)(s * 2 + 0)) * 8192 + px];
        k2[s] = bq12[((size_t)(s * 2 + 1)) * 8192 + px];
        v3[s] = b3v[(size_t)s * 8192 + px];
    }
    float m = valf(k1[0]);
#pragma unroll
    for (int s = 1; s < 4; ++s) m = fminf(m, valf(k1[s]));
    const float a = A[px];
    const unsigned eb = (__float_as_uint(a + 0.125f) >> 23) & 255u;
    const float up = __uint_as_float((eb - 23u) << 23);
    const float thresh = m + 4.5f * up + 1.0e-5f;

    unsigned cand[8];
    int nc = 0;
#pragma unroll
    for (int s = 0; s < 4; ++s) {
        if (valf(k1[s]) <= thresh) cand[nc++] = ((unsigned)px << 16) | (unsigned)(k1[s] & 0xffffu);
        if (valf(k2[s]) <= thresh) cand[nc++] = ((unsigned)px << 16) | (unsigned)(k2[s] & 0xffffu);
        if (v3[s] <= thresh) {
            const int pos = atomicAdd(&dcnt[s], 1);
            if (pos < 8192) dlist[s * 8192 + pos] = (unsigned short)px;
        }
    }
    int sc = nc;
#pragma unroll
    for (int o = 1; o < 64; o <<= 1) {
        const int n = __shfl_up(sc, o, 64);
        if (lane >= o) sc += n;
    }
    int base = 0;
    if (lane == 63) base = atomicAdd(ccnt, sc);
    base = __shfl(base, 63, 64);
    const int off = base + sc - nc;
    for (int j = 0; j < nc; ++j)
        if (off + j < CAND_CAP) cnd[off + j] = cand[j];
}

// ---------------------------------------------------------------- candidate np-exact rescore
__global__ __launch_bounds__(256) void k_cand(const float* __restrict__ ze,
                                              const float* __restrict__ embed,
                                              const float* __restrict__ A,
                                              const float* __restrict__ Nf,
                                              const int* __restrict__ ccnt,
                                              const unsigned* __restrict__ cnd,
                                              u64t* __restrict__ amin) {
    int cnt = *ccnt; if (cnt > CAND_CAP) cnt = CAND_CAP;
    for (int i = blockIdx.x * 256 + threadIdx.x; i < cnt; i += 32768) {
        const unsigned pk = cnd[i];
        const int px = pk >> 16, k = pk & 0xffffu;
        const float4* zr = reinterpret_cast<const float4*>(ze + (size_t)px * 256);
        const float4* er = reinterpret_cast<const float4*>(embed + (size_t)k * 256);
        float acc = 0.0f;
        for (int c4 = 0; c4 < 64; ++c4) {
            const float4 z4 = zr[c4], e4 = er[c4];
            acc = fmaf(__fmul_rn(2.0f, z4.x), e4.x, acc);
            acc = fmaf(__fmul_rn(2.0f, z4.y), e4.y, acc);
            acc = fmaf(__fmul_rn(2.0f, z4.z), e4.z, acc);
            acc = fmaf(__fmul_rn(2.0f, z4.w), e4.w, acc);
        }
        const float v = __fadd_rn(__fsub_rn(A[px], acc), Nf[k]);
        atomicMin(&amin[px], ((u64t)__float_as_uint(v) << 32) | (unsigned)k);
    }
}

// ---------------------------------------------------------------- deep: exact np rescore of a whole 2048-k split (r12/13-proven)
__global__ __launch_bounds__(256) void k_deep(const float* __restrict__ ze,
                                              const float* __restrict__ embed,
                                              const float* __restrict__ A,
                                              const float* __restrict__ Nf,
                                              const unsigned short* __restrict__ dlist,
                                              const int* __restrict__ dcnt,
                                              u64t* __restrict__ amin) {
    const int s = blockIdx.x >> 10;
    const int bkt = blockIdx.x & 1023;
    int n = dcnt[s]; if (n > 8192) n = 8192;
    const int i0 = bkt * 8;
    if (i0 >= n) return;
    __shared__ int spx[8];
    __shared__ float sA[8];
    __shared__ __align__(16) float lz2[8][264];
    __shared__ __align__(16) float echA[128][36];
    __shared__ __align__(16) float echB[128][36];
    __shared__ u64t redm[8][128];
    const int t = threadIdx.x;
    if (t < 8) {
        const int v = (i0 + t < n) ? (int)dlist[s * 8192 + i0 + t] : -1;
        spx[t] = v;
        sA[t] = (v >= 0) ? A[v] : 0.0f;
    }
    __syncthreads();
    {
        const int row = t >> 5, c0 = (t & 31) * 8;
        float4 v0 = make_float4(0.f, 0.f, 0.f, 0.f), v1 = v0;
        const int px = spx[row];
        if (px >= 0) {
            const float4* zr = reinterpret_cast<const float4*>(ze + (size_t)px * 256 + c0);
            v0 = zr[0]; v1 = zr[1];
        }
        lz2[row][c0 + 0] = __fmul_rn(2.0f, v0.x);
        lz2[row][c0 + 1] = __fmul_rn(2.0f, v0.y);
        lz2[row][c0 + 2] = __fmul_rn(2.0f, v0.z);
        lz2[row][c0 + 3] = __fmul_rn(2.0f, v0.w);
        lz2[row][c0 + 4] = __fmul_rn(2.0f, v1.x);
        lz2[row][c0 + 5] = __fmul_rn(2.0f, v1.y);
        lz2[row][c0 + 6] = __fmul_rn(2.0f, v1.z);
        lz2[row][c0 + 7] = __fmul_rn(2.0f, v1.w);
    }
    __syncthreads();
    const int pxg = t >> 7, kg = t & 127;
    u64t pbest[4];
#pragma unroll
    for (int p = 0; p < 4; ++p) pbest[p] = ~0ULL;
    for (int kc = 0; kc < 8; ++kc) {
        float acc[4][2];
#pragma unroll
        for (int p = 0; p < 4; ++p) { acc[p][0] = 0.0f; acc[p][1] = 0.0f; }
        for (int cc = 0; cc < 8; ++cc) {
            const float4* esrc = reinterpret_cast<const float4*>(
                embed + (size_t)(s * 2048 + kc * 256 + t) * 256 + cc * 32);
            float4 ev[8];
#pragma unroll
            for (int m = 0; m < 8; ++m) ev[m] = esrc[m];
            __syncthreads();
            {
                float* dst = (t & 1) ? &echB[t >> 1][0] : &echA[t >> 1][0];
#pragma unroll
                for (int m = 0; m < 8; ++m) {
                    dst[m * 4 + 0] = ev[m].x; dst[m * 4 + 1] = ev[m].y;
                    dst[m * 4 + 2] = ev[m].z; dst[m * 4 + 3] = ev[m].w;
                }
            }
            __syncthreads();
#pragma unroll
            for (int c4 = 0; c4 < 8; ++c4) {
                const float4 e0 = *reinterpret_cast<const float4*>(&echA[kg][c4 * 4]);
                const float4 e1 = *reinterpret_cast<const float4*>(&echB[kg][c4 * 4]);
#pragma unroll
                for (int p = 0; p < 4; ++p) {
                    const float4 zq = *reinterpret_cast<const float4*>(&lz2[pxg * 4 + p][cc * 32 + c4 * 4]);
                    acc[p][0] = fmaf(zq.x, e0.x, acc[p][0]);
                    acc[p][0] = fmaf(zq.y, e0.y, acc[p][0]);
                    acc[p][0] = fmaf(zq.z, e0.z, acc[p][0]);
                    acc[p][0] = fmaf(zq.w, e0.w, acc[p][0]);
                    acc[p][1] = fmaf(zq.x, e1.x, acc[p][1]);
                    acc[p][1] = fmaf(zq.y, e1.y, acc[p][1]);
                    acc[p][1] = fmaf(zq.z, e1.z, acc[p][1]);
                    acc[p][1] = fmaf(zq.w, e1.w, acc[p][1]);
                }
            }
        }
#pragma unroll
        for (int p = 0; p < 4; ++p) {
#pragma unroll
            for (int j = 0; j < 2; ++j) {
                const int k = s * 2048 + kc * 256 + kg * 2 + j;
                const float v = __fadd_rn(__fsub_rn(sA[pxg * 4 + p], acc[p][j]), Nf[k]);
                const u64t key = ((u64t)__float_as_uint(v) << 32) | (unsigned)k;
                pbest[p] = (key < pbest[p]) ? key : pbest[p];
            }
        }
    }
#pragma unroll
    for (int p = 0; p < 4; ++p) redm[pxg * 4 + p][kg] = pbest[p];
    __syncthreads();
    if (t < 8) {
        u64t bvv = ~0ULL;
        for (int q = 0; q < 128; ++q) {
            const u64t v = redm[t][q];
            bvv = (v < bvv) ? v : bvv;
        }
        if (spx[t] >= 0) atomicMin(&amin[spx[t]], bvv);
    }
}

// ---------------------------------------------------------------- fallback (ws too small): r10 VALU distance kernel
__global__ __launch_bounds__(256, 2) void k_dist_r10(const float* __restrict__ ze,
                                                     const float* __restrict__ embed,
                                                     const float* __restrict__ A,
                                                     const float* __restrict__ Nf,
                                                     u64t* __restrict__ amin) {
    __shared__ __align__(16) char smem[49152];
    float (*le)[128] = reinterpret_cast<float (*)[128]>(smem);
    float (*z2)[256] = reinterpret_cast<float (*)[256]>(smem + 16384);
    u64t* red = reinterpret_cast<u64t*>(smem);

    const int t    = threadIdx.x;
    const int ks   = blockIdx.x & 31;
    const int pt   = blockIdx.x >> 5;
    const int pix0 = pt * 256;
    const int k0   = ks * 256;
    const int tp   = t & 15, tk = t >> 4;
    const int er   = t >> 1, eh2 = (t & 1) * 16;

    float best[16];
    int   bidx[16];
#pragma unroll
    for (int i = 0; i < 16; ++i) { best[i] = 3.402823466e+38f; bidx[i] = 0x7fffffff; }

    float Ai[16];
#pragma unroll
    for (int q = 0; q < 4; ++q)
#pragma unroll
        for (int m = 0; m < 4; ++m)
            Ai[q * 4 + m] = A[pix0 + (q * 16 + tp) * 4 + m];

    for (int kc = 0; kc < 256; kc += 128) {
        float acc[16][8];
#pragma unroll
        for (int i = 0; i < 16; ++i)
#pragma unroll
            for (int j = 0; j < 8; ++j) acc[i][j] = 0.0f;
        const int kbase = k0 + kc + tk * 8;
        for (int cc = 0; cc < 256; cc += 32) {
            float4 se[4], sz[8];
            const float4* esrc = reinterpret_cast<const float4*>(
                embed + (size_t)(k0 + kc + er) * 256 + cc + eh2);
#pragma unroll
            for (int m = 0; m < 4; ++m) se[m] = esrc[m];
            const float4* zsrc = reinterpret_cast<const float4*>(
                ze + (size_t)(pix0 + t) * 256 + cc);
#pragma unroll
            for (int m = 0; m < 8; ++m) sz[m] = zsrc[m];
            __syncthreads();
#pragma unroll
            for (int m = 0; m < 4; ++m) {
                le[eh2 + m * 4 + 0][er] = se[m].x;
                le[eh2 + m * 4 + 1][er] = se[m].y;
                le[eh2 + m * 4 + 2][er] = se[m].z;
                le[eh2 + m * 4 + 3][er] = se[m].w;
            }
#pragma unroll
            for (int m = 0; m < 8; ++m) {
                z2[m * 4 + 0][t] = __fmul_rn(2.0f, sz[m].x);
                z2[m * 4 + 1][t] = __fmul_rn(2.0f, sz[m].y);
                z2[m * 4 + 2][t] = __fmul_rn(2.0f, sz[m].z);
                z2[m * 4 + 3][t] = __fmul_rn(2.0f, sz[m].w);
            }
            __syncthreads();
#pragma unroll 2
            for (int c = 0; c < 32; ++c) {
                const float4 e0 = *reinterpret_cast<const float4*>(&le[c][tk * 8]);
                const float4 e1 = *reinterpret_cast<const float4*>(&le[c][tk * 8 + 4]);
                float4 zq[4];
#pragma unroll
                for (int q = 0; q < 4; ++q)
                    zq[q] = *reinterpret_cast<const float4*>(&z2[c][(q * 16 + tp) * 4]);
#define FMA8(i, zv)                                          \
    acc[i][0] = fmaf(zv, e0.x, acc[i][0]);                   \
    acc[i][1] = fmaf(zv, e0.y, acc[i][1]);                   \
    acc[i][2] = fmaf(zv, e0.z, acc[i][2]);                   \
    acc[i][3] = fmaf(zv, e0.w, acc[i][3]);                   \
    acc[i][4] = fmaf(zv, e1.x, acc[i][4]);                   \
    acc[i][5] = fmaf(zv, e1.y, acc[i][5]);                   \
    acc[i][6] = fmaf(zv, e1.z, acc[i][6]);                   \
    acc[i][7] = fmaf(zv, e1.w, acc[i][7]);
#pragma unroll
                for (int q = 0; q < 4; ++q) {
                    FMA8(q * 4 + 0, zq[q].x)
                    FMA8(q * 4 + 1, zq[q].y)
                    FMA8(q * 4 + 2, zq[q].z)
                    FMA8(q * 4 + 3, zq[q].w)
                }
#undef FMA8
            }
        }
        const float4 n0 = *reinterpret_cast<const float4*>(&Nf[kbase]);
        const float4 n1 = *reinterpret_cast<const float4*>(&Nf[kbase + 4]);
        const float nk[8] = {n0.x, n0.y, n0.z, n0.w, n1.x, n1.y, n1.z, n1.w};
#pragma unroll
        for (int j = 0; j < 8; ++j) {
            const int k = kbase + j;
#pragma unroll
            for (int i = 0; i < 16; ++i) {
                const float v = __fadd_rn(__fsub_rn(Ai[i], acc[i][j]), nk[j]);
                if (v < best[i]) { best[i] = v; bidx[i] = k; }
            }
        }
    }
    __syncthreads();
#pragma unroll
    for (int i = 0; i < 16; ++i) {
        const int px = ((i >> 2) * 16 + tp) * 4 + (i & 3);
        const unsigned u = __float_as_uint(best[i]);
        red[px * 17 + tk] = ((u64t)u << 32) | (unsigned)bidx[i];
    }
    __syncthreads();
    {
        u64t bvv = ~0ULL;
#pragma unroll 4
        for (int q2 = 0; q2 < 16; ++q2) {
            const u64t v = red[t * 17 + q2];
            bvv = (v < bvv) ? v : bvv;
        }
        atomicMin(&amin[pix0 + t], bvv);
    }
}

// ---------------------------------------------------------------- unpack argmin
__global__ __launch_bounds__(256) void k_combine(const u64t* __restrict__ amin,
                                                 float* __restrict__ out_ind) {
    const int nn = blockIdx.x * 256 + threadIdx.x;
    out_ind[nn] = (float)(unsigned)(amin[nn] & 0xffffffffULL);
}

// ---------------------------------------------------------------- gather z_q (overwrite z_e) + partial MSE (f64)
__global__ __launch_bounds__(256) void k_gather(const float* __restrict__ embed,
                                                float* __restrict__ out,
                                                const float* __restrict__ out_ind,
                                                float* __restrict__ part) {
    __shared__ double wsum[4];
    const int t = threadIdx.x;
    const int g = t >> 5, ll = t & 31;
    const int nn = blockIdx.x * 8 + g;
    const int idx = (int)(out_ind[nn] + 0.5f);
    const float4* ev4 = reinterpret_cast<const float4*>(embed + (size_t)idx * 256);
    float4* zp = reinterpret_cast<float4*>(out + (size_t)nn * 256);
    double sm = 0.0;
#pragma unroll
    for (int r = 0; r < 2; ++r) {
        const float4 ev = ev4[ll + r * 32];
        const float4 zv = zp[ll + r * 32];
        const double dx = (double)ev.x - zv.x, dy = (double)ev.y - zv.y;
        const double dz = (double)ev.z - zv.z, dw = (double)ev.w - zv.w;
        sm += dx * dx + dy * dy + dz * dz + dw * dw;
        zp[ll + r * 32] = ev;
    }
    for (int off = 32; off; off >>= 1) sm += __shfl_down(sm, off, 64);
    const int wid = t >> 6, lane = t & 63;
    if (lane == 0) wsum[wid] = sm;
    __syncthreads();
    if (t == 0) part[blockIdx.x] = (float)(wsum[0] + wsum[1] + wsum[2] + wsum[3]);
}

// ---------------------------------------------------------------- final diff reduction (f64)
__global__ __launch_bounds__(256) void k_final(const float* __restrict__ part,
                                               float* __restrict__ out_diff) {
    __shared__ double wsum[4];
    double sm = 0.0;
#pragma unroll
    for (int i = 0; i < 4; ++i) sm += (double)part[threadIdx.x + i * 256];
    for (int off = 32; off; off >>= 1) sm += __shfl_down(sm, off, 64);
    const int wid = threadIdx.x >> 6, lane = threadIdx.x & 63;
    if (lane == 0) wsum[wid] = sm;
    __syncthreads();
    if (threadIdx.x == 0)
        out_diff[0] = (float)(2.0 * (wsum[0] + wsum[1] + wsum[2] + wsum[3]) / 2097152.0);
}

extern "C" void kernel_launch(void* const* d_in, const int* in_sizes, int n_in,
                              void* d_out, int out_size, void* d_ws, size_t ws_size,
                              hipStream_t stream) {
    const float* z     = (const float*)d_in[0];
    const float* pw    = (const float*)d_in[1];
    const float* pb    = (const float*)d_in[2];
    const float* embed = (const float*)d_in[3];
    float* out = (float*)d_out;
    char*  ws  = (char*)d_ws;

    u64t*           amin  = (u64t*)(ws + WS_AMIN);
    float*          A     = (float*)(ws + WS_A);
    float*          Nf    = (float*)(ws + WS_N);
    unsigned*       e2    = (unsigned*)(ws + WS_EMAX);
    unsigned short* dlist = (unsigned short*)(ws + WS_DLIST);
    int*            dcnt  = (int*)(ws + WS_DCNT);
    float*          part  = (float*)(ws + WS_PART);

    float* ze       = out + OUT_ZQ;      // z_e lives in z_q slot, overwritten by gather
    float* out_diff = out + OUT_DIFF;
    float* out_ind  = out + OUT_IND;

    const bool big = (ws_size >= WS_BIG_END);

    k_init    <<<32,   256, 0, stream>>>(amin, dcnt, e2);
    k_ze_np   <<<512,  256, 0, stream>>>(z, pw, pb, ze);
    k_rowstats<<<64,   256, 0, stream>>>(ze, embed, A, Nf, e2);
    if (big) {
        int*            ccnt = (int*)(ws + WS_CCNT);
        unsigned*       cnd  = (unsigned*)(ws + WS_CND);
        u64t*           bq12 = (u64t*)(ws + WS_BQ);
        float*          b3v  = (float*)(ws + WS_B3V);
        unsigned short* zh3  = (unsigned short*)(ws + WS_ZH3);
        unsigned short* zl3  = (unsigned short*)(ws + WS_ZL3);
        unsigned short* eh3  = (unsigned short*)(ws + WS_EH3);
        unsigned short* el3  = (unsigned short*)(ws + WS_EL3);
        k_cvt  <<<2048, 256, 0, stream>>>(ze, embed, zh3, zl3, eh3, el3, ccnt);
        k_mfma <<<512,  256, 0, stream>>>(A, Nf, zh3, zl3, eh3, el3, bq12, b3v);
        k_sel  <<<32,   256, 0, stream>>>(A, bq12, b3v, dlist, dcnt, ccnt, cnd);
        k_cand <<<128,  256, 0, stream>>>(ze, embed, A, Nf, ccnt, cnd, amin);
        k_deep <<<4096, 256, 0, stream>>>(ze, embed, A, Nf, dlist, dcnt, amin);
    } else {
        k_dist_r10<<<1024, 256, 0, stream>>>(ze, embed, A, Nf, amin);
    }
    k_combine <<<32,   256, 0, stream>>>(amin, out_ind);
    k_gather  <<<1024, 256, 0, stream>>>(embed, out + OUT_ZQ, out_ind, part);
    k_final   <<<1,    256, 0, stream>>>(part, out_diff);
}

// Round 16
// 231.972 us; speedup vs baseline: 3.6497x; 1.7163x over previous
//
#include <hip/hip_runtime.h>

#define OUT_ZQ   0
#define OUT_DIFF 2097152
#define OUT_IND  2097153

// ws layout (bytes) — big path total 18,087,936 <= proven 18,489,600
#define WS_AMIN   0        // u64[8192]
#define WS_A      65536    // f32[8192]
#define WS_N      98304    // f32[8192]
#define WS_EMAX   131072   // u32
#define WS_DLIST  131136   // u16[4][8192] = 64 KB
#define WS_DCNT   196672   // i32[4]
#define WS_PART   196688   // f32[1024]
#define WS_CCNT   200784   // i32 (+pad)
#define WS_CND    200848   // u32[98304]
#define WS_BQ     594064   // u64[4][2][8192] = 512 KB  (top-2 keys per split)
#define WS_B3V    1118352  // f32[4][8192]              (3rd-best VALUE per split)
#define WS_ZH3    1310720  // u16[2M] = 4 MB  fragment-major hi(2*z_e)
#define WS_ZL3    5505024  // lo(2*z_e)
#define WS_EH3    9699328  // hi(embed)
#define WS_EL3    13893632 // lo(embed)
#define WS_BIG_END 18087936ULL
#define CAND_CAP  98304

typedef unsigned long long u64t;
typedef __attribute__((ext_vector_type(8))) short bf16x8;
typedef __attribute__((ext_vector_type(4))) float f32x4;

__device__ inline unsigned short bf16rn(float f) {
    unsigned u = __float_as_uint(f);
    return (unsigned short)((u + 0x7fffu + ((u >> 16) & 1u)) >> 16);
}
__device__ inline float bf16tof(unsigned short h) { return __uint_as_float(((unsigned)h) << 16); }
__device__ inline float valf(u64t k) { return __uint_as_float((unsigned)(k >> 32)); }

#define INITKEY ((((u64t)0x7F7FFFFFu) << 32) | 0xFFFFu)   // value = FLT_MAX (no NaN)

// ---------------------------------------------------------------- init
__global__ __launch_bounds__(256) void k_init(u64t* __restrict__ amin,
                                              int* __restrict__ dcnt,
                                              unsigned* __restrict__ e2) {
    const int i = blockIdx.x * 256 + threadIdx.x;
    amin[i] = ~0ULL;
    if (i < 4) dcnt[i] = 0;
    if (i == 4) *e2 = 0u;
}

// ---------------------------------------------------------------- z_e: bit-exact np.einsum replica (v2)
__global__ __launch_bounds__(256) void k_ze_np(const float* __restrict__ z,
                                               const float* __restrict__ pw,
                                               const float* __restrict__ pb,
                                               float* __restrict__ ze) {
    __shared__ float lz[32][16];
    const int t   = threadIdx.x;
    const int b   = blockIdx.x >> 6;
    const int hw0 = (blockIdx.x & 63) * 16;

    float acc[16];
#pragma unroll
    for (int p = 0; p < 16; ++p) acc[p] = 0.0f;

    for (int cc = 0; cc < 256; cc += 32) {
        float4 wv[8];
        const float4* wsrc = reinterpret_cast<const float4*>(pw + (size_t)t * 256 + cc);
#pragma unroll
        for (int i = 0; i < 8; ++i) wv[i] = wsrc[i];
        float zv[2];
#pragma unroll
        for (int i = 0; i < 2; ++i) {
            const int f = t + i * 256;
            zv[i] = z[(size_t)(b * 256 + cc + (f >> 4)) * 1024 + hw0 + (f & 15)];
        }
        __syncthreads();
#pragma unroll
        for (int i = 0; i < 2; ++i) {
            const int f = t + i * 256;
            lz[f >> 4][f & 15] = zv[i];
        }
        __syncthreads();
#define ZSTEP(CL, WL) {                                                     \
    const float4 q0 = *reinterpret_cast<const float4*>(&lz[CL][0]);         \
    const float4 q1 = *reinterpret_cast<const float4*>(&lz[CL][4]);         \
    const float4 q2 = *reinterpret_cast<const float4*>(&lz[CL][8]);         \
    const float4 q3 = *reinterpret_cast<const float4*>(&lz[CL][12]);        \
    acc[0]  = __fadd_rn(acc[0],  __fmul_rn(q0.x, WL));                      \
    acc[1]  = __fadd_rn(acc[1],  __fmul_rn(q0.y, WL));                      \
    acc[2]  = __fadd_rn(acc[2],  __fmul_rn(q0.z, WL));                      \
    acc[3]  = __fadd_rn(acc[3],  __fmul_rn(q0.w, WL));                      \
    acc[4]  = __fadd_rn(acc[4],  __fmul_rn(q1.x, WL));                      \
    acc[5]  = __fadd_rn(acc[5],  __fmul_rn(q1.y, WL));                      \
    acc[6]  = __fadd_rn(acc[6],  __fmul_rn(q1.z, WL));                      \
    acc[7]  = __fadd_rn(acc[7],  __fmul_rn(q1.w, WL));                      \
    acc[8]  = __fadd_rn(acc[8],  __fmul_rn(q2.x, WL));                      \
    acc[9]  = __fadd_rn(acc[9],  __fmul_rn(q2.y, WL));                      \
    acc[10] = __fadd_rn(acc[10], __fmul_rn(q2.z, WL));                      \
    acc[11] = __fadd_rn(acc[11], __fmul_rn(q2.w, WL));                      \
    acc[12] = __fadd_rn(acc[12], __fmul_rn(q3.x, WL));                      \
    acc[13] = __fadd_rn(acc[13], __fmul_rn(q3.y, WL));                      \
    acc[14] = __fadd_rn(acc[14], __fmul_rn(q3.z, WL));                      \
    acc[15] = __fadd_rn(acc[15], __fmul_rn(q3.w, WL)); }
#pragma unroll
        for (int c8 = 0; c8 < 8; ++c8) {
            const float4 wq = wv[c8];
            ZSTEP(c8 * 4 + 0, wq.x)
            ZSTEP(c8 * 4 + 1, wq.y)
            ZSTEP(c8 * 4 + 2, wq.z)
            ZSTEP(c8 * 4 + 3, wq.w)
        }
#undef ZSTEP
    }
    const float bb = pb[t];
#pragma unroll
    for (int p = 0; p < 16; ++p)
        ze[(size_t)(b * 1024 + hw0 + p) * 256 + t] = __fadd_rn(acc[p], bb);
}

// ---------------------------------------------------------------- np pairwise row-norms
__global__ __launch_bounds__(256) void k_rowstats(const float* __restrict__ ze,
                                                  const float* __restrict__ embed,
                                                  float* __restrict__ A,
                                                  float* __restrict__ Nf,
                                                  unsigned* __restrict__ e2) {
    const int gid = blockIdx.x * 256 + threadIdx.x;
    const float* row = (gid < 8192) ? (ze + (size_t)gid * 256)
                                    : (embed + (size_t)(gid - 8192) * 256);
    float blk[2];
#pragma unroll
    for (int half = 0; half < 2; ++half) {
        const float4* r4 = reinterpret_cast<const float4*>(row + half * 128);
        float r[8];
#pragma unroll
        for (int i = 0; i < 16; ++i) {
            const float4 a = r4[i * 2], b = r4[i * 2 + 1];
            const float s[8] = {__fmul_rn(a.x, a.x), __fmul_rn(a.y, a.y),
                                __fmul_rn(a.z, a.z), __fmul_rn(a.w, a.w),
                                __fmul_rn(b.x, b.x), __fmul_rn(b.y, b.y),
                                __fmul_rn(b.z, b.z), __fmul_rn(b.w, b.w)};
            if (i == 0) {
#pragma unroll
                for (int j = 0; j < 8; ++j) r[j] = s[j];
            } else {
#pragma unroll
                for (int j = 0; j < 8; ++j) r[j] = __fadd_rn(r[j], s[j]);
            }
        }
        blk[half] = __fadd_rn(__fadd_rn(__fadd_rn(r[0], r[1]), __fadd_rn(r[2], r[3])),
                              __fadd_rn(__fadd_rn(r[4], r[5]), __fadd_rn(r[6], r[7])));
    }
    const float res = __fadd_rn(blk[0], blk[1]);
    if (gid < 8192) A[gid] = res;
    else {
        Nf[gid - 8192] = res;
        float mx = res;
        for (int off = 32; off; off >>= 1) mx = fmaxf(mx, __shfl_down(mx, off, 64));
        if ((threadIdx.x & 63) == 0) atomicMax(e2, __float_as_uint(mx));
    }
}

// ---------------------------------------------------------------- bf16 hi/lo precompute in FRAGMENT-MAJOR layout
__global__ __launch_bounds__(256) void k_cvt(const float* __restrict__ ze,
                                             const float* __restrict__ embed,
                                             unsigned short* __restrict__ zh3,
                                             unsigned short* __restrict__ zl3,
                                             unsigned short* __restrict__ eh3,
                                             unsigned short* __restrict__ el3,
                                             int* __restrict__ ccnt) {
    const int gid = blockIdx.x * 256 + threadIdx.x;
    if (gid == 0) *ccnt = 0;
    const int row = gid >> 5;
    const int c0  = (gid & 31) * 8;
    const bool isz = (row < 8192);
    const float* src = (isz ? ze + (size_t)row * 256 : embed + (size_t)(row - 8192) * 256) + c0;
    const float4 v0 = reinterpret_cast<const float4*>(src)[0];
    const float4 v1 = reinterpret_cast<const float4*>(src)[1];
    float x[8] = {v0.x, v0.y, v0.z, v0.w, v1.x, v1.y, v1.z, v1.w};
    if (isz) {
#pragma unroll
        for (int i = 0; i < 8; ++i) x[i] = __fmul_rn(2.0f, x[i]);   // exact prescale
    }
    unsigned short hv[8], lv[8];
#pragma unroll
    for (int i = 0; i < 8; ++i) {
        hv[i] = bf16rn(x[i]);
        lv[i] = bf16rn(__fsub_rn(x[i], bf16tof(hv[i])));
    }
    const int ci = c0 >> 5, lg = (c0 >> 3) & 3;
    if (isz) {
        const int pt = row >> 6, ti = (row >> 4) & 3, lr = row & 15;
        const int lane = lg * 16 + lr;
        const size_t off = ((size_t)(ci * 128 + pt) * 4 + ti) * 512 + (size_t)lane * 8;
        *reinterpret_cast<ushort4*>(zh3 + off)     = make_ushort4(hv[0], hv[1], hv[2], hv[3]);
        *reinterpret_cast<ushort4*>(zh3 + off + 4) = make_ushort4(hv[4], hv[5], hv[6], hv[7]);
        *reinterpret_cast<ushort4*>(zl3 + off)     = make_ushort4(lv[0], lv[1], lv[2], lv[3]);
        *reinterpret_cast<ushort4*>(zl3 + off + 4) = make_ushort4(lv[4], lv[5], lv[6], lv[7]);
    } else {
        const int k = row - 8192;
        const int ks = k >> 11, ksub = (k >> 8) & 7, w = (k >> 6) & 3, tj = (k >> 4) & 3, lr = k & 15;
        const int lane = lg * 16 + lr;
        const size_t off = (((size_t)((ks * 8 + ksub) * 8 + ci) * 16) + w * 4 + tj) * 512 + (size_t)lane * 8;
        *reinterpret_cast<ushort4*>(eh3 + off)     = make_ushort4(hv[0], hv[1], hv[2], hv[3]);
        *reinterpret_cast<ushort4*>(eh3 + off + 4) = make_ushort4(hv[4], hv[5], hv[6], hv[7]);
        *reinterpret_cast<ushort4*>(el3 + off)     = make_ushort4(lv[0], lv[1], lv[2], lv[3]);
        *reinterpret_cast<ushort4*>(el3 + off + 4) = make_ushort4(lv[4], lv[5], lv[6], lv[7]);
    }
}

// ---------------------------------------------------------------- MFMA screen v3: no LDS/barriers in main loop (r15-proven)
__global__ __launch_bounds__(256, 2) void k_mfma(const float* __restrict__ A,
                                                 const float* __restrict__ Nf,
                                                 const unsigned short* __restrict__ zh3,
                                                 const unsigned short* __restrict__ zl3,
                                                 const unsigned short* __restrict__ eh3,
                                                 const unsigned short* __restrict__ el3,
                                                 u64t* __restrict__ bq12,
                                                 float* __restrict__ b3v) {
    __shared__ u64t  mrgk[64][4][2];
    __shared__ float mrgv[64][4];
    const int t = threadIdx.x;
    const int ks = blockIdx.x & 3, pt = blockIdx.x >> 2;
    const int pix0 = pt * 64;
    const int w = t >> 6, l = t & 63;
    const int lg = l >> 4, lr = l & 15;

    float a_reg[4][4];
#pragma unroll
    for (int ti = 0; ti < 4; ++ti)
#pragma unroll
        for (int r = 0; r < 4; ++r)
            a_reg[ti][r] = A[pix0 + ti * 16 + lg * 4 + r];

    u64t b1[4][4], b2[4][4];
    float bv[4][4];
#pragma unroll
    for (int ti = 0; ti < 4; ++ti)
#pragma unroll
        for (int r = 0; r < 4; ++r) { b1[ti][r] = INITKEY; b2[ti][r] = INITKEY; bv[ti][r] = 3.402823466e+38f; }

    const size_t zoff0 = (size_t)pt * 2048 + (size_t)l * 8;
    for (int ksub = 0; ksub < 8; ++ksub) {
        f32x4 acc[4][4];
#pragma unroll
        for (int ti = 0; ti < 4; ++ti)
#pragma unroll
            for (int tj = 0; tj < 4; ++tj) acc[ti][tj] = (f32x4)(0.0f);

        const size_t ebase = (size_t)(ks * 8 + ksub) * 65536 + (size_t)w * 2048 + (size_t)l * 8;
#pragma unroll 2
        for (int ci = 0; ci < 8; ++ci) {
            const size_t zo = zoff0 + (size_t)ci * 262144;
            const size_t eo = ebase + (size_t)ci * 8192;
            bf16x8 az[4], alz[4], be[4], ble[4];
#pragma unroll
            for (int ti = 0; ti < 4; ++ti) {
                az[ti]  = *reinterpret_cast<const bf16x8*>(zh3 + zo + (size_t)ti * 512);
                alz[ti] = *reinterpret_cast<const bf16x8*>(zl3 + zo + (size_t)ti * 512);
            }
#pragma unroll
            for (int tj = 0; tj < 4; ++tj) {
                be[tj]  = *reinterpret_cast<const bf16x8*>(eh3 + eo + (size_t)tj * 512);
                ble[tj] = *reinterpret_cast<const bf16x8*>(el3 + eo + (size_t)tj * 512);
            }
#pragma unroll
            for (int tj = 0; tj < 4; ++tj)
#pragma unroll
                for (int ti = 0; ti < 4; ++ti) {
                    acc[ti][tj] = __builtin_amdgcn_mfma_f32_16x16x32_bf16(az[ti],  be[tj],  acc[ti][tj], 0, 0, 0);
                    acc[ti][tj] = __builtin_amdgcn_mfma_f32_16x16x32_bf16(az[ti],  ble[tj], acc[ti][tj], 0, 0, 0);
                    acc[ti][tj] = __builtin_amdgcn_mfma_f32_16x16x32_bf16(alz[ti], be[tj],  acc[ti][tj], 0, 0, 0);
                }
        }
#pragma unroll
        for (int tj = 0; tj < 4; ++tj) {
            const int kk = ks * 2048 + ksub * 256 + w * 64 + tj * 16 + lr;
            const float nk = Nf[kk];
#pragma unroll
            for (int ti = 0; ti < 4; ++ti)
#pragma unroll
                for (int r = 0; r < 4; ++r) {
                    const float vv = __fadd_rn(__fsub_rn(a_reg[ti][r], acc[ti][tj][r]), nk);
                    const u64t key = ((u64t)__float_as_uint(vv) << 32) | (unsigned)kk;
                    if (key < b2[ti][r]) {
                        bv[ti][r] = valf(b2[ti][r]);
                        if (key < b1[ti][r]) { b2[ti][r] = b1[ti][r]; b1[ti][r] = key; }
                        else                 { b2[ti][r] = key; }
                    } else {
                        bv[ti][r] = fminf(bv[ti][r], vv);
                    }
                }
        }
    }
#pragma unroll
    for (int ti = 0; ti < 4; ++ti)
#pragma unroll
        for (int r = 0; r < 4; ++r) {
            u64t k1 = b1[ti][r], k2 = b2[ti][r];
            float v3 = bv[ti][r];
#pragma unroll
            for (int m = 1; m <= 8; m <<= 1) {
                const u64t o1 = __shfl_xor(k1, m, 64);
                const u64t o2 = __shfl_xor(k2, m, 64);
                const float ov = __shfl_xor(v3, m, 64);
                const u64t n1 = (k1 < o1) ? k1 : o1;
                const u64t X  = (k1 < o1) ? o1 : k1;
                const u64t Y  = (k2 < o2) ? k2 : o2;
                const u64t n2 = (X < Y) ? X : Y;
                const u64t t4 = (X < Y) ? Y : X;
                v3 = fminf(fminf(v3, ov), valf(t4));
                k1 = n1; k2 = n2;
            }
            b1[ti][r] = k1; b2[ti][r] = k2; bv[ti][r] = v3;
        }
    if (lr == 0) {
#pragma unroll
        for (int ti = 0; ti < 4; ++ti)
#pragma unroll
            for (int r = 0; r < 4; ++r) {
                const int pxl = ti * 16 + lg * 4 + r;
                mrgk[pxl][w][0] = b1[ti][r];
                mrgk[pxl][w][1] = b2[ti][r];
                mrgv[pxl][w]    = bv[ti][r];
            }
    }
    __syncthreads();
    if (t < 64) {
        u64t K1 = INITKEY, K2 = INITKEY;
        float V3 = 3.402823466e+38f;
#pragma unroll
        for (int w4 = 0; w4 < 4; ++w4) {
            const u64t o1 = mrgk[t][w4][0], o2 = mrgk[t][w4][1];
            const float ov = mrgv[t][w4];
            const u64t n1 = (K1 < o1) ? K1 : o1;
            const u64t X  = (K1 < o1) ? o1 : K1;
            const u64t Y  = (K2 < o2) ? K2 : o2;
            const u64t n2 = (X < Y) ? X : Y;
            const u64t t4 = (X < Y) ? Y : X;
            V3 = fminf(fminf(V3, ov), valf(t4));
            K1 = n1; K2 = n2;
        }
        bq12[((size_t)(ks * 2 + 0)) * 8192 + pix0 + t] = K1;
        bq12[((size_t)(ks * 2 + 1)) * 8192 + pix0 + t] = K2;
        b3v[(size_t)ks * 8192 + pix0 + t] = V3;
    }
}

// ---------------------------------------------------------------- select: candidates + deep flags (3rd-VALUE gated)
__global__ __launch_bounds__(256) void k_sel(const float* __restrict__ A,
                                             const u64t* __restrict__ bq12,
                                             const float* __restrict__ b3v,
                                             unsigned short* __restrict__ dlist,
                                             int* __restrict__ dcnt,
                                             int* __restrict__ ccnt,
                                             unsigned* __restrict__ cnd) {
    const int px = blockIdx.x * 256 + threadIdx.x;
    const int lane = threadIdx.x & 63;
    u64t k1[4], k2[4];
    float v3[4];
#pragma unroll
    for (int s = 0; s < 4; ++s) {
        k1[s] = bq12[((size_t)(s * 2 + 0)) * 8192 + px];
        k2[s] = bq12[((size_t)(s * 2 + 1)) * 8192 + px];
        v3[s] = b3v[(size_t)s * 8192 + px];
    }
    float m = valf(k1[0]);
#pragma unroll
    for (int s = 1; s < 4; ++s) m = fminf(m, valf(k1[s]));
    const float a = A[px];
    const unsigned eb = (__float_as_uint(a + 0.125f) >> 23) & 255u;
    const float up = __uint_as_float((eb - 23u) << 23);
    const float thresh = m + 4.5f * up + 1.0e-5f;

    unsigned cand[8];
    int nc = 0;
#pragma unroll
    for (int s = 0; s < 4; ++s) {
        if (valf(k1[s]) <= thresh) cand[nc++] = ((unsigned)px << 16) | (unsigned)(k1[s] & 0xffffu);
        if (valf(k2[s]) <= thresh) cand[nc++] = ((unsigned)px << 16) | (unsigned)(k2[s] & 0xffffu);
        if (v3[s] <= thresh) {
            const int pos = atomicAdd(&dcnt[s], 1);
            if (pos < 8192) dlist[s * 8192 + pos] = (unsigned short)px;
        }
    }
    int sc = nc;
#pragma unroll
    for (int o = 1; o < 64; o <<= 1) {
        const int n = __shfl_up(sc, o, 64);
        if (lane >= o) sc += n;
    }
    int base = 0;
    if (lane == 63) base = atomicAdd(ccnt, sc);
    base = __shfl(base, 63, 64);
    const int off = base + sc - nc;
    for (int j = 0; j < nc; ++j)
        if (off + j < CAND_CAP) cnd[off + j] = cand[j];
}

// ---------------------------------------------------------------- candidate np-exact rescore
__global__ __launch_bounds__(256) void k_cand(const float* __restrict__ ze,
                                              const float* __restrict__ embed,
                                              const float* __restrict__ A,
                                              const float* __restrict__ Nf,
                                              const int* __restrict__ ccnt,
                                              const unsigned* __restrict__ cnd,
                                              u64t* __restrict__ amin) {
    int cnt = *ccnt; if (cnt > CAND_CAP) cnt = CAND_CAP;
    for (int i = blockIdx.x * 256 + threadIdx.x; i < cnt; i += 32768) {
        const unsigned pk = cnd[i];
        const int px = pk >> 16, k = pk & 0xffffu;
        const float4* zr = reinterpret_cast<const float4*>(ze + (size_t)px * 256);
        const float4* er = reinterpret_cast<const float4*>(embed + (size_t)k * 256);
        float acc = 0.0f;
        for (int c4 = 0; c4 < 64; ++c4) {
            const float4 z4 = zr[c4], e4 = er[c4];
            acc = fmaf(__fmul_rn(2.0f, z4.x), e4.x, acc);
            acc = fmaf(__fmul_rn(2.0f, z4.y), e4.y, acc);
            acc = fmaf(__fmul_rn(2.0f, z4.z), e4.z, acc);
            acc = fmaf(__fmul_rn(2.0f, z4.w), e4.w, acc);
        }
        const float v = __fadd_rn(__fsub_rn(A[px], acc), Nf[k]);
        atomicMin(&amin[px], ((u64t)__float_as_uint(v) << 32) | (unsigned)k);
    }
}

// ---------------------------------------------------------------- deep v3: one block per (flagged px, 256-k slice)
// Per block: stage 2*z_e[px] in LDS; thread t owns k = base+t, runs the np-exact
// sequential fmaf chain (identical to k_cand); wave u64-min reduce -> 1 atomicMin/block.
__global__ __launch_bounds__(256) void k_deep(const float* __restrict__ ze,
                                              const float* __restrict__ embed,
                                              const float* __restrict__ A,
                                              const float* __restrict__ Nf,
                                              const unsigned short* __restrict__ dlist,
                                              const int* __restrict__ dcnt,
                                              u64t* __restrict__ amin) {
    __shared__ float lz2[256];
    __shared__ float sa[1];
    __shared__ u64t lw4[4];
    const int t = threadIdx.x;
    int n0 = dcnt[0], n1 = dcnt[1], n2 = dcnt[2], n3 = dcnt[3];
    n0 = (n0 > 8192) ? 8192 : n0;  n1 = (n1 > 8192) ? 8192 : n1;
    n2 = (n2 > 8192) ? 8192 : n2;  n3 = (n3 > 8192) ? 8192 : n3;
    const int tot = (n0 + n1 + n2 + n3) * 8;

    for (int it = blockIdx.x; it < tot; it += gridDim.x) {
        const int q = it >> 3, slice = it & 7;
        int s, pxi;
        if (q < n0)                { s = 0; pxi = q; }
        else if (q < n0 + n1)      { s = 1; pxi = q - n0; }
        else if (q < n0 + n1 + n2) { s = 2; pxi = q - n0 - n1; }
        else                       { s = 3; pxi = q - n0 - n1 - n2; }
        const int px = dlist[s * 8192 + pxi];

        __syncthreads();   // protect lz2/lw4 from previous iteration's readers
        lz2[t] = __fmul_rn(2.0f, ze[(size_t)px * 256 + t]);   // exact prescale
        if (t == 0) sa[0] = A[px];
        __syncthreads();

        const int k = s * 2048 + slice * 256 + t;
        const float4* er = reinterpret_cast<const float4*>(embed + (size_t)k * 256);
        float acc = 0.0f;
#pragma unroll 8
        for (int c4 = 0; c4 < 64; ++c4) {
            const float4 e4 = er[c4];
            acc = fmaf(lz2[c4 * 4 + 0], e4.x, acc);
            acc = fmaf(lz2[c4 * 4 + 1], e4.y, acc);
            acc = fmaf(lz2[c4 * 4 + 2], e4.z, acc);
            acc = fmaf(lz2[c4 * 4 + 3], e4.w, acc);
        }
        const float v = __fadd_rn(__fsub_rn(sa[0], acc), Nf[k]);
        u64t key = ((u64t)__float_as_uint(v) << 32) | (unsigned)k;
#pragma unroll
        for (int m = 1; m <= 32; m <<= 1) {
            const u64t o = __shfl_xor(key, m, 64);
            key = (o < key) ? o : key;
        }
        if ((t & 63) == 0) lw4[t >> 6] = key;
        __syncthreads();
        if (t == 0) {
            u64t bk = lw4[0];
            bk = (lw4[1] < bk) ? lw4[1] : bk;
            bk = (lw4[2] < bk) ? lw4[2] : bk;
            bk = (lw4[3] < bk) ? lw4[3] : bk;
            atomicMin(&amin[px], bk);
        }
    }
}

// ---------------------------------------------------------------- fallback (ws too small): r10 VALU distance kernel
__global__ __launch_bounds__(256, 2) void k_dist_r10(const float* __restrict__ ze,
                                                     const float* __restrict__ embed,
                                                     const float* __restrict__ A,
                                                     const float* __restrict__ Nf,
                                                     u64t* __restrict__ amin) {
    __shared__ __align__(16) char smem[49152];
    float (*le)[128] = reinterpret_cast<float (*)[128]>(smem);
    float (*z2)[256] = reinterpret_cast<float (*)[256]>(smem + 16384);
    u64t* red = reinterpret_cast<u64t*>(smem);

    const int t    = threadIdx.x;
    const int ks   = blockIdx.x & 31;
    const int pt   = blockIdx.x >> 5;
    const int pix0 = pt * 256;
    const int k0   = ks * 256;
    const int tp   = t & 15, tk = t >> 4;
    const int er   = t >> 1, eh2 = (t & 1) * 16;

    float best[16];
    int   bidx[16];
#pragma unroll
    for (int i = 0; i < 16; ++i) { best[i] = 3.402823466e+38f; bidx[i] = 0x7fffffff; }

    float Ai[16];
#pragma unroll
    for (int q = 0; q < 4; ++q)
#pragma unroll
        for (int m = 0; m < 4; ++m)
            Ai[q * 4 + m] = A[pix0 + (q * 16 + tp) * 4 + m];

    for (int kc = 0; kc < 256; kc += 128) {
        float acc[16][8];
#pragma unroll
        for (int i = 0; i < 16; ++i)
#pragma unroll
            for (int j = 0; j < 8; ++j) acc[i][j] = 0.0f;
        const int kbase = k0 + kc + tk * 8;
        for (int cc = 0; cc < 256; cc += 32) {
            float4 se[4], sz[8];
            const float4* esrc = reinterpret_cast<const float4*>(
                embed + (size_t)(k0 + kc + er) * 256 + cc + eh2);
#pragma unroll
            for (int m = 0; m < 4; ++m) se[m] = esrc[m];
            const float4* zsrc = reinterpret_cast<const float4*>(
                ze + (size_t)(pix0 + t) * 256 + cc);
#pragma unroll
            for (int m = 0; m < 8; ++m) sz[m] = zsrc[m];
            __syncthreads();
#pragma unroll
            for (int m = 0; m < 4; ++m) {
                le[eh2 + m * 4 + 0][er] = se[m].x;
                le[eh2 + m * 4 + 1][er] = se[m].y;
                le[eh2 + m * 4 + 2][er] = se[m].z;
                le[eh2 + m * 4 + 3][er] = se[m].w;
            }
#pragma unroll
            for (int m = 0; m < 8; ++m) {
                z2[m * 4 + 0][t] = __fmul_rn(2.0f, sz[m].x);
                z2[m * 4 + 1][t] = __fmul_rn(2.0f, sz[m].y);
                z2[m * 4 + 2][t] = __fmul_rn(2.0f, sz[m].z);
                z2[m * 4 + 3][t] = __fmul_rn(2.0f, sz[m].w);
            }
            __syncthreads();
#pragma unroll 2
            for (int c = 0; c < 32; ++c) {
                const float4 e0 = *reinterpret_cast<const float4*>(&le[c][tk * 8]);
                const float4 e1 = *reinterpret_cast<const float4*>(&le[c][tk * 8 + 4]);
                float4 zq[4];
#pragma unroll
                for (int q = 0; q < 4; ++q)
                    zq[q] = *reinterpret_cast<const float4*>(&z2[c][(q * 16 + tp) * 4]);
#define FMA8(i, zv)                                          \
    acc[i][0] = fmaf(zv, e0.x, acc[i][0]);                   \
    acc[i][1] = fmaf(zv, e0.y, acc[i][1]);                   \
    acc[i][2] = fmaf(zv, e0.z, acc[i][2]);                   \
    acc[i][3] = fmaf(zv, e0.w, acc[i][3]);                   \
    acc[i][4] = fmaf(zv, e1.x, acc[i][4]);                   \
    acc[i][5] = fmaf(zv, e1.y, acc[i][5]);                   \
    acc[i][6] = fmaf(zv, e1.z, acc[i][6]);                   \
    acc[i][7] = fmaf(zv, e1.w, acc[i][7]);
#pragma unroll
                for (int q = 0; q < 4; ++q) {
                    FMA8(q * 4 + 0, zq[q].x)
                    FMA8(q * 4 + 1, zq[q].y)
                    FMA8(q * 4 + 2, zq[q].z)
                    FMA8(q * 4 + 3, zq[q].w)
                }
#undef FMA8
            }
        }
        const float4 n0 = *reinterpret_cast<const float4*>(&Nf[kbase]);
        const float4 n1 = *reinterpret_cast<const float4*>(&Nf[kbase + 4]);
        const float nk[8] = {n0.x, n0.y, n0.z, n0.w, n1.x, n1.y, n1.z, n1.w};
#pragma unroll
        for (int j = 0; j < 8; ++j) {
            const int k = kbase + j;
#pragma unroll
            for (int i = 0; i < 16; ++i) {
                const float v = __fadd_rn(__fsub_rn(Ai[i], acc[i][j]), nk[j]);
                if (v < best[i]) { best[i] = v; bidx[i] = k; }
            }
        }
    }
    __syncthreads();
#pragma unroll
    for (int i = 0; i < 16; ++i) {
        const int px = ((i >> 2) * 16 + tp) * 4 + (i & 3);
        const unsigned u = __float_as_uint(best[i]);
        red[px * 17 + tk] = ((u64t)u << 32) | (unsigned)bidx[i];
    }
    __syncthreads();
    {
        u64t bvv = ~0ULL;
#pragma unroll 4
        for (int q2 = 0; q2 < 16; ++q2) {
            const u64t v = red[t * 17 + q2];
            bvv = (v < bvv) ? v : bvv;
        }
        atomicMin(&amin[pix0 + t], bvv);
    }
}

// ---------------------------------------------------------------- unpack argmin
__global__ __launch_bounds__(256) void k_combine(const u64t* __restrict__ amin,
                                                 float* __restrict__ out_ind) {
    const int nn = blockIdx.x * 256 + threadIdx.x;
    out_ind[nn] = (float)(unsigned)(amin[nn] & 0xffffffffULL);
}

// ---------------------------------------------------------------- gather z_q (overwrite z_e) + partial MSE (f64)
__global__ __launch_bounds__(256) void k_gather(const float* __restrict__ embed,
                                                float* __restrict__ out,
                                                const float* __restrict__ out_ind,
                                                float* __restrict__ part) {
    __shared__ double wsum[4];
    const int t = threadIdx.x;
    const int g = t >> 5, ll = t & 31;
    const int nn = blockIdx.x * 8 + g;
    const int idx = (int)(out_ind[nn] + 0.5f);
    const float4* ev4 = reinterpret_cast<const float4*>(embed + (size_t)idx * 256);
    float4* zp = reinterpret_cast<float4*>(out + (size_t)nn * 256);
    double sm = 0.0;
#pragma unroll
    for (int r = 0; r < 2; ++r) {
        const float4 ev = ev4[ll + r * 32];
        const float4 zv = zp[ll + r * 32];
        const double dx = (double)ev.x - zv.x, dy = (double)ev.y - zv.y;
        const double dz = (double)ev.z - zv.z, dw = (double)ev.w - zv.w;
        sm += dx * dx + dy * dy + dz * dz + dw * dw;
        zp[ll + r * 32] = ev;
    }
    for (int off = 32; off; off >>= 1) sm += __shfl_down(sm, off, 64);
    const int wid = t >> 6, lane = t & 63;
    if (lane == 0) wsum[wid] = sm;
    __syncthreads();
    if (t == 0) part[blockIdx.x] = (float)(wsum[0] + wsum[1] + wsum[2] + wsum[3]);
}

// ---------------------------------------------------------------- final diff reduction (f64)
__global__ __launch_bounds__(256) void k_final(const float* __restrict__ part,
                                               float* __restrict__ out_diff) {
    __shared__ double wsum[4];
    double sm = 0.0;
#pragma unroll
    for (int i = 0; i < 4; ++i) sm += (double)part[threadIdx.x + i * 256];
    for (int off = 32; off; off >>= 1) sm += __shfl_down(sm, off, 64);
    const int wid = threadIdx.x >> 6, lane = threadIdx.x & 63;
    if (lane == 0) wsum[wid] = sm;
    __syncthreads();
    if (threadIdx.x == 0)
        out_diff[0] = (float)(2.0 * (wsum[0] + wsum[1] + wsum[2] + wsum[3]) / 2097152.0);
}

extern "C" void kernel_launch(void* const* d_in, const int* in_sizes, int n_in,
                              void* d_out, int out_size, void* d_ws, size_t ws_size,
                              hipStream_t stream) {
    const float* z     = (const float*)d_in[0];
    const float* pw    = (const float*)d_in[1];
    const float* pb    = (const float*)d_in[2];
    const float* embed = (const float*)d_in[3];
    float* out = (float*)d_out;
    char*  ws  = (char*)d_ws;

    u64t*           amin  = (u64t*)(ws + WS_AMIN);
    float*          A     = (float*)(ws + WS_A);
    float*          Nf    = (float*)(ws + WS_N);
    unsigned*       e2    = (unsigned*)(ws + WS_EMAX);
    unsigned short* dlist = (unsigned short*)(ws + WS_DLIST);
    int*            dcnt  = (int*)(ws + WS_DCNT);
    float*          part  = (float*)(ws + WS_PART);

    float* ze       = out + OUT_ZQ;      // z_e lives in z_q slot, overwritten by gather
    float* out_diff = out + OUT_DIFF;
    float* out_ind  = out + OUT_IND;

    const bool big = (ws_size >= WS_BIG_END);

    k_init    <<<32,   256, 0, stream>>>(amin, dcnt, e2);
    k_ze_np   <<<512,  256, 0, stream>>>(z, pw, pb, ze);
    k_rowstats<<<64,   256, 0, stream>>>(ze, embed, A, Nf, e2);
    if (big) {
        int*            ccnt = (int*)(ws + WS_CCNT);
        unsigned*       cnd  = (unsigned*)(ws + WS_CND);
        u64t*           bq12 = (u64t*)(ws + WS_BQ);
        float*          b3v  = (float*)(ws + WS_B3V);
        unsigned short* zh3  = (unsigned short*)(ws + WS_ZH3);
        unsigned short* zl3  = (unsigned short*)(ws + WS_ZL3);
        unsigned short* eh3  = (unsigned short*)(ws + WS_EH3);
        unsigned short* el3  = (unsigned short*)(ws + WS_EL3);
        k_cvt  <<<2048, 256, 0, stream>>>(ze, embed, zh3, zl3, eh3, el3, ccnt);
        k_mfma <<<512,  256, 0, stream>>>(A, Nf, zh3, zl3, eh3, el3, bq12, b3v);
        k_sel  <<<32,   256, 0, stream>>>(A, bq12, b3v, dlist, dcnt, ccnt, cnd);
        k_cand <<<128,  256, 0, stream>>>(ze, embed, A, Nf, ccnt, cnd, amin);
        k_deep <<<2048, 256, 0, stream>>>(ze, embed, A, Nf, dlist, dcnt, amin);
    } else {
        k_dist_r10<<<1024, 256, 0, stream>>>(ze, embed, A, Nf, amin);
    }
    k_combine <<<32,   256, 0, stream>>>(amin, out_ind);
    k_gather  <<<1024, 256, 0, stream>>>(embed, out + OUT_ZQ, out_ind, part);
    k_final   <<<1,    256, 0, stream>>>(part, out_diff);
}